// Round 5
// baseline (623.346 us; speedup 1.0000x reference)
//
#include <hip/hip_runtime.h>
#include <cstdint>
#include <cstddef>

#define Hc   128
#define INc  256
#define ZD   (INc + Hc)   // 384
#define Kc   8
#define ZP   392          // z row pad (ushorts): 784B/row
#define HP   136          // precompute/update staging row pad (ushorts)
#define ZP2  264          // node z row pad
#define EPH  136          // bf16 epilogue arrays pad (ushorts/row)

typedef unsigned short ushortT;
typedef __attribute__((ext_vector_type(8))) short bf16x8;
typedef __attribute__((ext_vector_type(4))) float f32x4;
typedef __attribute__((ext_vector_type(4))) unsigned short us4;
typedef __attribute__((ext_vector_type(8))) unsigned short us8;

// fast sigmoid: no clamps needed — exp(-x)->inf => rcp->0 ; exp(-x)->0 => 1
__device__ __forceinline__ float fsig(float x) {
  return __builtin_amdgcn_rcpf(1.f + __expf(-x));
}
// fast tanh: upper clamp only (avoid inf/inf); e->0 gives -1 exactly
__device__ __forceinline__ float ftanh(float x) {
  float e = __expf(2.f * fminf(x, 15.f));
  return (e - 1.f) * __builtin_amdgcn_rcpf(e + 1.f);
}
__device__ __forceinline__ ushortT f2bf(float f) {
  unsigned u = __builtin_bit_cast(unsigned, f);
  unsigned r = (u + 0x7fffu + ((u >> 16) & 1u)) >> 16;
  return (ushortT)r;
}
__device__ __forceinline__ us4 f2bf4(float4 v) {
  us4 o; o[0] = f2bf(v.x); o[1] = f2bf(v.y); o[2] = f2bf(v.z); o[3] = f2bf(v.w);
  return o;
}
__device__ __forceinline__ float bf2f(ushortT u) {
  return __builtin_bit_cast(float, (unsigned)u << 16);
}

// ---------------- utility kernels ----------------
__global__ void zero_f4(float4* __restrict__ p, long n4) {
  long i = (long)blockIdx.x * blockDim.x + threadIdx.x;
  long stride = (long)gridDim.x * blockDim.x;
  float4 z; z.x = z.y = z.z = z.w = 0.f;
  for (; i < n4; i += stride) p[i] = z;
}
__global__ void mark_init(int* __restrict__ mark, int M) {
  int i = blockIdx.x * blockDim.x + threadIdx.x;
  if (i < M) mark[i] = -1;
}
__global__ void mark_set(int* __restrict__ mark, const int* __restrict__ submess, int S) {
  int i = blockIdx.x * blockDim.x + threadIdx.x;
  if (i < S) mark[submess[i]] = i;
}

// ---------------- weight repack into B-fragment order (verified R2-R4) ----------
#define GATE_FRAGS (4*8*12*64)
#define WN_FRAGS   (8*8*64)
__global__ void repack_weights(const float* __restrict__ Wi, const float* __restrict__ Wo,
                               const float* __restrict__ Wu, const float* __restrict__ Wf,
                               const float* __restrict__ Wn, ushortT* __restrict__ pack) {
  int idx = blockIdx.x * blockDim.x + threadIdx.x;
  if (idx < GATE_FRAGS) {
    int lane = idx & 63;
    int kt = (idx >> 6) % 12;
    int gc = idx / (64 * 12);
    int c = gc & 7, g = gc >> 3;
    const float* W = (g == 0) ? Wi : (g == 1) ? Wo : (g == 2) ? Wu : Wf;
    int k0 = kt * 32 + (lane >> 4) * 8;
    int col = c * 16 + (lane & 15);
    ushortT* dst = pack + (size_t)idx * 8;
    #pragma unroll
    for (int j = 0; j < 8; ++j) dst[j] = f2bf(W[(size_t)(k0 + j) * Hc + col]);
  } else if (idx < GATE_FRAGS + WN_FRAGS) {
    int i2 = idx - GATE_FRAGS;
    int lane = i2 & 63;
    int kt = (i2 >> 6) & 7;
    int c = i2 >> 9;
    int k0 = kt * 32 + (lane >> 4) * 8;
    int col = c * 16 + (lane & 15);
    ushortT* dst = pack + (size_t)GATE_FRAGS * 8 + (size_t)i2 * 8;
    #pragma unroll
    for (int j = 0; j < 8; ++j) dst[j] = f2bf(Wn[(size_t)(k0 + j) * Hc + col]);
  }
}

// Wf2 B-fragment (gate pack, g=3, kt=8..11 == Wf rows 256..383)
__device__ __forceinline__ const bf16x8* wf2_frag(const ushortT* pack, int cw, int kf, int lane) {
  return (const bf16x8*)&pack[(size_t)(((3 * 8 + cw) * 12 + (8 + kf)) * 64 + lane) * 8];
}

// ---------------- precompute: passthrough + masked bf16 shadows + Hf = h@Wf2 ----
__global__ __launch_bounds__(256) void precompute(
    const float* __restrict__ h_in, const float* __restrict__ c_in,
    const int* __restrict__ mark, const ushortT* __restrict__ pack,
    float* __restrict__ h_out, float* __restrict__ c_out,
    ushortT* __restrict__ H16, ushortT* __restrict__ C16, ushortT* __restrict__ Hf16,
    int M)
{
  __shared__ __align__(16) ushortT zh[16 * HP];
  __shared__ int mskL[16];
  const int t = threadIdx.x;
  const int row0 = blockIdx.x * 16;

  if (t < 16) mskL[t] = (row0 + t < M) ? (mark[row0 + t] >= 0 ? 1 : 0) : 1;
  __syncthreads();
  {
    int r = t >> 4, cp = t & 15;
    int j = row0 + r;
    bool ok = (j < M);
    int msk = mskL[r];
    float4 a0, a1, b0, b1;
    a0.x=a0.y=a0.z=a0.w=0.f; a1=a0; b0=a0; b1=a0;
    if (ok) {
      const float4* h4 = (const float4*)(h_in + (size_t)j * Hc);
      const float4* c4 = (const float4*)(c_in + (size_t)j * Hc);
      a0 = h4[cp]; a1 = h4[cp + 16]; b0 = c4[cp]; b1 = c4[cp + 16];
      ((float4*)(h_out + (size_t)j * Hc))[cp] = a0;
      ((float4*)(h_out + (size_t)j * Hc))[cp + 16] = a1;
      ((float4*)(c_out + (size_t)j * Hc))[cp] = b0;
      ((float4*)(c_out + (size_t)j * Hc))[cp + 16] = b1;
    }
    us4 zz; zz[0]=zz[1]=zz[2]=zz[3]=0;
    us4 ha0 = msk ? zz : f2bf4(a0), ha1 = msk ? zz : f2bf4(a1);
    us4 ca0 = msk ? zz : f2bf4(b0), ca1 = msk ? zz : f2bf4(b1);
    if (ok) {
      *(us4*)&H16[(size_t)j * Hc + cp * 4] = ha0;
      *(us4*)&H16[(size_t)j * Hc + 64 + cp * 4] = ha1;
      *(us4*)&C16[(size_t)j * Hc + cp * 4] = ca0;
      *(us4*)&C16[(size_t)j * Hc + 64 + cp * 4] = ca1;
    }
    *(us4*)&zh[r * HP + cp * 4] = ha0;
    *(us4*)&zh[r * HP + 64 + cp * 4] = ha1;
  }
  __syncthreads();

  const int w = t >> 6, lane = t & 63, lg = lane >> 4, cl = lane & 15;
  f32x4 acc0 = (f32x4){0.f,0.f,0.f,0.f}, acc1 = acc0;
  const ushortT* zr = &zh[cl * HP + lg * 8];
  #pragma unroll
  for (int kf = 0; kf < 4; ++kf) {
    bf16x8 a = *(const bf16x8*)&zr[kf * 32];
    acc0 = __builtin_amdgcn_mfma_f32_16x16x32_bf16(a, *wf2_frag(pack, w*2+0, kf, lane), acc0, 0, 0, 0);
    acc1 = __builtin_amdgcn_mfma_f32_16x16x32_bf16(a, *wf2_frag(pack, w*2+1, kf, lane), acc1, 0, 0, 0);
  }
  #pragma unroll
  for (int half = 0; half < 2; ++half) {
    int col = (w * 2 + half) * 16 + cl;
    f32x4 a_ = half ? acc1 : acc0;
    #pragma unroll
    for (int reg = 0; reg < 4; ++reg) {
      int j = row0 + lg * 4 + reg;
      if (j < M) Hf16[(size_t)j * Hc + col] = f2bf(a_[reg]);
    }
  }
}

// ---------------- update shadows at sub rows from iter-0 output ----------------
__global__ __launch_bounds__(256) void update_sub(
    const float* __restrict__ h_out, const float* __restrict__ c_out,
    const int* __restrict__ submess, const ushortT* __restrict__ pack,
    ushortT* __restrict__ H16, ushortT* __restrict__ C16, ushortT* __restrict__ Hf16,
    int S)
{
  __shared__ __align__(16) ushortT zh[16 * HP];
  __shared__ int msL[16];
  const int t = threadIdx.x;
  const int row0 = blockIdx.x * 16;

  if (t < 16) msL[t] = (row0 + t < S) ? submess[row0 + t] : -1;
  __syncthreads();
  {
    int r = t >> 4, cp = t & 15;
    int ms = msL[r];
    float4 a0, a1, b0, b1;
    a0.x=a0.y=a0.z=a0.w=0.f; a1=a0; b0=a0; b1=a0;
    if (ms >= 0) {
      const float4* h4 = (const float4*)(h_out + (size_t)ms * Hc);
      const float4* c4 = (const float4*)(c_out + (size_t)ms * Hc);
      a0 = h4[cp]; a1 = h4[cp + 16]; b0 = c4[cp]; b1 = c4[cp + 16];
    }
    us4 ha0 = f2bf4(a0), ha1 = f2bf4(a1);
    if (ms >= 0) {
      *(us4*)&H16[(size_t)ms * Hc + cp * 4] = ha0;
      *(us4*)&H16[(size_t)ms * Hc + 64 + cp * 4] = ha1;
      *(us4*)&C16[(size_t)ms * Hc + cp * 4] = f2bf4(b0);
      *(us4*)&C16[(size_t)ms * Hc + 64 + cp * 4] = f2bf4(b1);
    }
    *(us4*)&zh[r * HP + cp * 4] = ha0;
    *(us4*)&zh[r * HP + 64 + cp * 4] = ha1;
  }
  __syncthreads();

  const int w = t >> 6, lane = t & 63, lg = lane >> 4, cl = lane & 15;
  f32x4 acc0 = (f32x4){0.f,0.f,0.f,0.f}, acc1 = acc0;
  const ushortT* zr = &zh[cl * HP + lg * 8];
  #pragma unroll
  for (int kf = 0; kf < 4; ++kf) {
    bf16x8 a = *(const bf16x8*)&zr[kf * 32];
    acc0 = __builtin_amdgcn_mfma_f32_16x16x32_bf16(a, *wf2_frag(pack, w*2+0, kf, lane), acc0, 0, 0, 0);
    acc1 = __builtin_amdgcn_mfma_f32_16x16x32_bf16(a, *wf2_frag(pack, w*2+1, kf, lane), acc1, 0, 0, 0);
  }
  #pragma unroll
  for (int half = 0; half < 2; ++half) {
    int col = (w * 2 + half) * 16 + cl;
    f32x4 a_ = half ? acc1 : acc0;
    #pragma unroll
    for (int reg = 0; reg < 4; ++reg) {
      int ms = msL[lg * 4 + reg];
      if (ms >= 0) Hf16[(size_t)ms * Hc + col] = f2bf(a_[reg]);
    }
  }
}

// ---- LSTM step: occupancy-tuned (VGPR<=64, LDS 13.6KB), bf16 epi roundtrip ----
__global__ __launch_bounds__(256, 8) void lstm_step4(
    const float* __restrict__ fmess, const int* __restrict__ submess,
    const int* __restrict__ bgraph,
    const ushortT* __restrict__ H16, const ushortT* __restrict__ C16,
    const ushortT* __restrict__ Hf16,
    const ushortT* __restrict__ pack,
    const float* __restrict__ bi, const float* __restrict__ bo,
    const float* __restrict__ bu, const float* __restrict__ bfb,
    float* __restrict__ dstH, float* __restrict__ dstC, int S)
{
  // union: zs (bf16 [16][ZP] = 12544B) | bf16 epi arrays cst/osg/fxl [16][EPH]
  __shared__ __align__(16) unsigned char pool[3 * 16 * EPH * 2];   // 13056B
  __shared__ int nbj[16][Kc];
  __shared__ int msrow[16];

  ushortT* zs  = (ushortT*)pool;
  ushortT* cst = (ushortT*)pool;            // [16][EPH]
  ushortT* osg = cst + 16 * EPH;
  ushortT* fxl = osg + 16 * EPH;

  const int t = threadIdx.x;
  const int row0 = blockIdx.x * 16;

  if (t < 16) msrow[t] = (row0 + t < S) ? submess[row0 + t] : -1;
  __syncthreads();

  // ---- stage x (bf16) + neighbor ids ----
  {
    int r = t >> 4, cp = t & 15;
    int ms = msrow[r];
    const float4* xr = (ms >= 0) ? (const float4*)(fmess + (size_t)ms * INc) : nullptr;
    #pragma unroll
    for (int q = 0; q < 4; ++q) {
      int slot = cp + q * 16;
      float4 v;
      if (xr) v = xr[slot]; else { v.x = v.y = v.z = v.w = 0.f; }
      *(us4*)&zs[r * ZP + slot * 4] = f2bf4(v);
    }
  }
  if (t < 128) {
    int r = t >> 3, k = t & 7;
    int ms = msrow[r];
    nbj[r][k] = (ms >= 0) ? bgraph[(size_t)ms * Kc + k] : 0;
  }
  __syncthreads();

  // ---- h_sum from bf16 shadow ----
  {
    int r = t >> 4, cp = t & 15;
    float sum[8] = {0.f,0.f,0.f,0.f,0.f,0.f,0.f,0.f};
    #pragma unroll
    for (int k = 0; k < Kc; ++k) {
      int j = nbj[r][k];
      us8 v = *(const us8*)&H16[(size_t)j * Hc + cp * 8];
      #pragma unroll
      for (int e = 0; e < 8; ++e) sum[e] += bf2f(v[e]);
    }
    us4 o0, o1;
    #pragma unroll
    for (int e = 0; e < 4; ++e) { o0[e] = f2bf(sum[e]); o1[e] = f2bf(sum[4 + e]); }
    *(us4*)&zs[r * ZP + INc + cp * 8] = o0;
    *(us4*)&zs[r * ZP + INc + cp * 8 + 4] = o1;
  }
  __syncthreads();

  const int w = t >> 6, lane = t & 63, lg = lane >> 4, cl = lane & 15;

  // ---- gate K-loop: 88 MFMAs/wave ----
  f32x4 acc[8];
  #pragma unroll
  for (int i = 0; i < 8; ++i) acc[i] = (f32x4){0.f, 0.f, 0.f, 0.f};

  const ushortT* zrow = &zs[cl * ZP + lg * 8];
  const ushortT* bp = pack + (size_t)lane * 8;
  #pragma unroll
  for (int kt = 0; kt < 12; ++kt) {
    bf16x8 a = *(const bf16x8*)&zrow[kt * 32];
    #pragma unroll
    for (int tix = 0; tix < 8; ++tix) {
      int g = tix >> 1;
      if (g == 3 && kt >= 8) continue;
      int cw = w * 2 + (tix & 1);
      bf16x8 b = *(const bf16x8*)(bp + ((size_t)((g * 8 + cw) * 12 + kt)) * 512);
      acc[tix] = __builtin_amdgcn_mfma_f32_16x16x32_bf16(a, b, acc[tix], 0, 0, 0);
    }
  }
  __syncthreads();   // all A-frag reads of zs done; pool may be overwritten

  // ---- write epi arrays (bf16, biases folded) ----
  #pragma unroll
  for (int half = 0; half < 2; ++half) {
    int col = (w * 2 + half) * 16 + cl;
    float biv = bi[col], bov = bo[col], buv = bu[col], bfv = bfb[col];
    f32x4 ia = acc[0 + half], oa = acc[2 + half], ua = acc[4 + half], fa = acc[6 + half];
    #pragma unroll
    for (int reg = 0; reg < 4; ++reg) {
      int row = lg * 4 + reg;
      cst[row * EPH + col] = f2bf(fsig(ia[reg] + biv) * ftanh(ua[reg] + buv));
      osg[row * EPH + col] = f2bf(fsig(oa[reg] + bov));
      fxl[row * EPH + col] = f2bf(fa[reg] + bfv);
    }
  }
  __syncthreads();

  // ---- finish: (row, 8-col chunk); vectorized 16B gathers + stores ----
  {
    int r = t >> 4, cc = t & 15;
    int ms = msrow[r];
    float fx[8], cacc[8];
    {
      us8 fx8 = *(const us8*)&fxl[r * EPH + cc * 8];
      us8 ci8 = *(const us8*)&cst[r * EPH + cc * 8];
      #pragma unroll
      for (int e = 0; e < 8; ++e) { fx[e] = bf2f(fx8[e]); cacc[e] = bf2f(ci8[e]); }
    }
    #pragma unroll
    for (int k = 0; k < Kc; ++k) {
      int j = nbj[r][k];
      us8 hf8 = *(const us8*)&Hf16[(size_t)j * Hc + cc * 8];
      us8 cn8 = *(const us8*)&C16[(size_t)j * Hc + cc * 8];
      #pragma unroll
      for (int e = 0; e < 8; ++e)
        cacc[e] = fmaf(fsig(fx[e] + bf2f(hf8[e])), bf2f(cn8[e]), cacc[e]);
    }
    if (ms >= 0) {
      us8 ov8 = *(const us8*)&osg[r * EPH + cc * 8];
      float hv[8];
      #pragma unroll
      for (int e = 0; e < 8; ++e) hv[e] = bf2f(ov8[e]) * ftanh(cacc[e]);
      float* dh = dstH + (size_t)ms * Hc + cc * 8;
      float* dc = dstC + (size_t)ms * Hc + cc * 8;
      *(float4*)&dh[0] = *(float4*)&hv[0];
      *(float4*)&dh[4] = *(float4*)&hv[4];
      *(float4*)&dc[0] = *(float4*)&cacc[0];
      *(float4*)&dc[4] = *(float4*)&cacc[4];
    }
  }
}

// ---------------- node readout (MFMA, unchanged) ----------------
__global__ __launch_bounds__(256) void node_readout_mfma(
    const float* __restrict__ fnode, const int* __restrict__ agraph,
    const int* __restrict__ subnode, const float* __restrict__ hfull,
    const ushortT* __restrict__ packWn, const float* __restrict__ bn,
    float* __restrict__ node_buf, int Nsub)
{
  __shared__ __align__(16) ushortT z2[16 * ZP2];
  __shared__ int orow[16];
  __shared__ const float* aptr[16][Kc];

  const int t = threadIdx.x;
  const int row0 = blockIdx.x * 16;

  if (t < 16) orow[t] = (row0 + t < Nsub) ? subnode[row0 + t] : -1;
  if (t >= 64 && t < 64 + 128) {
    int i = t - 64, r = i >> 3, k = i & 7;
    int v = row0 + r;
    aptr[r][k] = (v < Nsub) ? hfull + (size_t)agraph[(size_t)v * Kc + k] * Hc : nullptr;
  }
  {
    int r = t >> 4, cp = t & 15;
    int v = row0 + r;
    const float4* fr = (v < Nsub) ? (const float4*)(fnode + (size_t)v * Hc) : nullptr;
    float4 v0, v1; v0.x = v0.y = v0.z = v0.w = 0.f; v1 = v0;
    if (fr) { v0 = fr[cp]; v1 = fr[cp + 16]; }
    *(us4*)&z2[r * ZP2 + cp * 4] = f2bf4(v0);
    *(us4*)&z2[r * ZP2 + 64 + cp * 4] = f2bf4(v1);
  }
  __syncthreads();
  {
    int r = t >> 4, cp = t & 15;
    float4 s0, s1; s0.x = s0.y = s0.z = s0.w = 0.f; s1 = s0;
    #pragma unroll
    for (int k = 0; k < Kc; ++k) {
      const float* p = aptr[r][k];
      if (p) {
        float4 v0 = ((const float4*)p)[cp], v1 = ((const float4*)p)[cp + 16];
        s0.x += v0.x; s0.y += v0.y; s0.z += v0.z; s0.w += v0.w;
        s1.x += v1.x; s1.y += v1.y; s1.z += v1.z; s1.w += v1.w;
      }
    }
    *(us4*)&z2[r * ZP2 + Hc + cp * 4] = f2bf4(s0);
    *(us4*)&z2[r * ZP2 + Hc + 64 + cp * 4] = f2bf4(s1);
  }
  __syncthreads();

  const int w = t >> 6, lane = t & 63;
  const int lg = lane >> 4, cl = lane & 15;

  f32x4 acc0 = (f32x4){0.f,0.f,0.f,0.f};
  f32x4 acc1 = (f32x4){0.f,0.f,0.f,0.f};
  const ushortT* zr = &z2[cl * ZP2 + lg * 8];
  #pragma unroll
  for (int kt = 0; kt < 8; ++kt) {
    bf16x8 a = *(const bf16x8*)&zr[kt * 32];
    bf16x8 b0 = *(const bf16x8*)&packWn[(size_t)(((w * 2 + 0) * 8 + kt) * 64 + lane) * 8];
    bf16x8 b1 = *(const bf16x8*)&packWn[(size_t)(((w * 2 + 1) * 8 + kt) * 64 + lane) * 8];
    acc0 = __builtin_amdgcn_mfma_f32_16x16x32_bf16(a, b0, acc0, 0, 0, 0);
    acc1 = __builtin_amdgcn_mfma_f32_16x16x32_bf16(a, b1, acc1, 0, 0, 0);
  }
  #pragma unroll
  for (int half = 0; half < 2; ++half) {
    int col = (w * 2 + half) * 16 + cl;
    float bnv = bn[col];
    f32x4 a_ = half ? acc1 : acc0;
    #pragma unroll
    for (int reg = 0; reg < 4; ++reg) {
      int row = lg * 4 + reg;
      int o = orow[row];
      if (o >= 0) node_buf[(size_t)o * Hc + col] = fmaxf(a_[reg] + bnv, 0.f);
    }
  }
}

// ---------------- launch ----------------
extern "C" void kernel_launch(void* const* d_in, const int* in_sizes, int n_in,
                              void* d_out, int out_size, void* d_ws, size_t ws_size,
                              hipStream_t stream) {
  const float* fnode   = (const float*)d_in[0];
  const float* fmess   = (const float*)d_in[1];
  const int*   agraph  = (const int*)d_in[2];
  const int*   bgraph  = (const int*)d_in[3];
  const float* h_in    = (const float*)d_in[4];
  const float* c_in    = (const float*)d_in[5];
  const int*   submess = (const int*)d_in[6];
  const int*   subnode = (const int*)d_in[7];
  const float* Wi = (const float*)d_in[9];
  const float* bi = (const float*)d_in[10];
  const float* Wo = (const float*)d_in[11];
  const float* bo = (const float*)d_in[12];
  const float* Wf = (const float*)d_in[13];
  const float* bf_ = (const float*)d_in[14];
  const float* Wu = (const float*)d_in[15];
  const float* bu = (const float*)d_in[16];
  const float* Wn = (const float*)d_in[17];
  const float* bn = (const float*)d_in[18];

  const int S    = in_sizes[6];
  const int Nsub = in_sizes[2] / Kc;
  const int M    = in_sizes[4] / Hc;
  const int num_nodes = out_size / Hc - 2 * M;

  float* node_buf = (float*)d_out;
  float* h_out = node_buf + (size_t)num_nodes * Hc;
  float* c_out = h_out + (size_t)M * Hc;

  // ws layout: mark[M] | pack | Hf16[M*128] bf16 | C16[M*128] bf16
  // H16[M*128] bf16 lives in the node_buf region (zeroed only after iter1).
  int* mark = (int*)d_ws;
  size_t off = (((size_t)M * sizeof(int)) + 255) & ~(size_t)255;
  ushortT* pack = (ushortT*)((char*)d_ws + off);
  off += (((size_t)(GATE_FRAGS + WN_FRAGS) * 8 * sizeof(ushortT)) + 255) & ~(size_t)255;
  ushortT* Hf16 = (ushortT*)((char*)d_ws + off);
  off += (((size_t)M * Hc * sizeof(ushortT)) + 255) & ~(size_t)255;
  ushortT* C16 = (ushortT*)((char*)d_ws + off);
  ushortT* H16 = (ushortT*)node_buf;   // 30.7MB <= num_nodes*Hc*4 = 33.5MB
  ushortT* packWn = pack + (size_t)GATE_FRAGS * 8;

  // 1. mark + weight repack
  hipLaunchKernelGGL(mark_init, dim3((M + 255) / 256), dim3(256), 0, stream, mark, M);
  hipLaunchKernelGGL(mark_set,  dim3((S + 255) / 256), dim3(256), 0, stream, mark, submess, S);
  hipLaunchKernelGGL(repack_weights, dim3((GATE_FRAGS + WN_FRAGS + 255) / 256), dim3(256), 0, stream,
                     Wi, Wo, Wu, Wf, Wn, pack);

  // 2. precompute: h/c passthrough + masked bf16 shadows + Hf = masked h @ Wf2
  hipLaunchKernelGGL(precompute, dim3((M + 15) / 16), dim3(256), 0, stream,
                     h_in, c_in, mark, pack, h_out, c_out, H16, C16, Hf16, M);

  const int lblocks = (S + 15) / 16;
  // 3. iter 0
  hipLaunchKernelGGL(lstm_step4, dim3(lblocks), dim3(256), 0, stream,
      fmess, submess, bgraph, H16, C16, Hf16, pack,
      bi, bo, bu, bf_, h_out, c_out, S);
  // 4. refresh shadows at sub rows
  hipLaunchKernelGGL(update_sub, dim3(lblocks), dim3(256), 0, stream,
      h_out, c_out, submess, pack, H16, C16, Hf16, S);
  // 5. iter 1
  hipLaunchKernelGGL(lstm_step4, dim3(lblocks), dim3(256), 0, stream,
      fmess, submess, bgraph, H16, C16, Hf16, pack,
      bi, bo, bu, bf_, h_out, c_out, S);

  // 6. zero node_buf (erases H16 shadow), then node readout
  long nn4 = (long)num_nodes * Hc / 4;
  long zb = (nn4 + 255) / 256; if (zb > 8192) zb = 8192;
  hipLaunchKernelGGL(zero_f4, dim3((int)zb), dim3(256), 0, stream, (float4*)node_buf, nn4);

  const int nblocks = (Nsub + 15) / 16;
  hipLaunchKernelGGL(node_readout_mfma, dim3(nblocks), dim3(256), 0, stream,
      fnode, agraph, subnode, h_out, packWn, bn, node_buf, S);
}

// Round 6
// 377.835 us; speedup vs baseline: 1.6498x; 1.6498x over previous
//
#include <hip/hip_runtime.h>
#include <cstdint>
#include <cstddef>

#define Hc   128
#define INc  256
#define Kc   8
#define HP   136          // precompute/update staging row pad (ushorts)
#define HSP  136          // lstm h_sum staging row pad (ushorts)
#define EPH  136          // lstm gate-partial arrays row pad (ushorts)
#define ZP2  264          // node/x staging row pad (ushorts)

typedef unsigned short ushortT;
typedef __attribute__((ext_vector_type(8))) short bf16x8;
typedef __attribute__((ext_vector_type(4))) float f32x4;
typedef __attribute__((ext_vector_type(4))) unsigned short us4;
typedef __attribute__((ext_vector_type(8))) unsigned short us8;

// fast sigmoid: exp(-x)->inf => rcp->0 ; exp(-x)->0 => 1 (no clamps needed)
__device__ __forceinline__ float fsig(float x) {
  return __builtin_amdgcn_rcpf(1.f + __expf(-x));
}
// fast tanh: upper clamp only (avoid inf/inf); e->0 gives -1 exactly
__device__ __forceinline__ float ftanh(float x) {
  float e = __expf(2.f * fminf(x, 15.f));
  return (e - 1.f) * __builtin_amdgcn_rcpf(e + 1.f);
}
__device__ __forceinline__ ushortT f2bf(float f) {
  unsigned u = __builtin_bit_cast(unsigned, f);
  unsigned r = (u + 0x7fffu + ((u >> 16) & 1u)) >> 16;
  return (ushortT)r;
}
__device__ __forceinline__ us4 f2bf4(float4 v) {
  us4 o; o[0] = f2bf(v.x); o[1] = f2bf(v.y); o[2] = f2bf(v.z); o[3] = f2bf(v.w);
  return o;
}
__device__ __forceinline__ float bf2f(ushortT u) {
  return __builtin_bit_cast(float, (unsigned)u << 16);
}

// ---------------- utility kernels ----------------
__global__ void zero_f4(float4* __restrict__ p, long n4) {
  long i = (long)blockIdx.x * blockDim.x + threadIdx.x;
  long stride = (long)gridDim.x * blockDim.x;
  float4 z; z.x = z.y = z.z = z.w = 0.f;
  for (; i < n4; i += stride) p[i] = z;
}
__global__ void mark_init(int* __restrict__ mark, int M) {
  int i = blockIdx.x * blockDim.x + threadIdx.x;
  if (i < M) mark[i] = -1;
}
__global__ void mark_set(int* __restrict__ mark, const int* __restrict__ submess, int S) {
  int i = blockIdx.x * blockDim.x + threadIdx.x;
  if (i < S) mark[submess[i]] = i;
}

// ---------------- weight repack into B-fragment order (verified R2-R5) ----------
// gates: idx = ((g*8 + c)*12 + kt)*64 + lane ; elem j:
//        W_g[kt*32 + (lane>>4)*8 + j][c*16 + (lane&15)]  (kt 0..11 spans K=384)
#define GATE_FRAGS (4*8*12*64)
#define WN_FRAGS   (8*8*64)
__global__ void repack_weights(const float* __restrict__ Wi, const float* __restrict__ Wo,
                               const float* __restrict__ Wu, const float* __restrict__ Wf,
                               const float* __restrict__ Wn, ushortT* __restrict__ pack) {
  int idx = blockIdx.x * blockDim.x + threadIdx.x;
  if (idx < GATE_FRAGS) {
    int lane = idx & 63;
    int kt = (idx >> 6) % 12;
    int gc = idx / (64 * 12);
    int c = gc & 7, g = gc >> 3;
    const float* W = (g == 0) ? Wi : (g == 1) ? Wo : (g == 2) ? Wu : Wf;
    int k0 = kt * 32 + (lane >> 4) * 8;
    int col = c * 16 + (lane & 15);
    ushortT* dst = pack + (size_t)idx * 8;
    #pragma unroll
    for (int j = 0; j < 8; ++j) dst[j] = f2bf(W[(size_t)(k0 + j) * Hc + col]);
  } else if (idx < GATE_FRAGS + WN_FRAGS) {
    int i2 = idx - GATE_FRAGS;
    int lane = i2 & 63;
    int kt = (i2 >> 6) & 7;
    int c = i2 >> 9;
    int k0 = kt * 32 + (lane >> 4) * 8;
    int col = c * 16 + (lane & 15);
    ushortT* dst = pack + (size_t)GATE_FRAGS * 8 + (size_t)i2 * 8;
    #pragma unroll
    for (int j = 0; j < 8; ++j) dst[j] = f2bf(Wn[(size_t)(k0 + j) * Hc + col]);
  }
}

// W*2 B-fragment (h-part rows 256..383 of gate g => kt slots 8..11)
__device__ __forceinline__ const bf16x8* wh_frag(const ushortT* pack, int g, int cw, int kf, int lane) {
  return (const bf16x8*)&pack[(size_t)(((g * 8 + cw) * 12 + (8 + kf)) * 64 + lane) * 8];
}

// ---------------- precompute: passthrough + masked bf16 shadows + Hf = h@Wf2 ----
__global__ __launch_bounds__(256) void precompute(
    const float* __restrict__ h_in, const float* __restrict__ c_in,
    const int* __restrict__ mark, const ushortT* __restrict__ pack,
    float* __restrict__ h_out, float* __restrict__ c_out,
    ushortT* __restrict__ H16, ushortT* __restrict__ C16, ushortT* __restrict__ Hf16,
    int M)
{
  __shared__ __align__(16) ushortT zh[16 * HP];
  __shared__ int mskL[16];
  const int t = threadIdx.x;
  const int row0 = blockIdx.x * 16;

  if (t < 16) mskL[t] = (row0 + t < M) ? (mark[row0 + t] >= 0 ? 1 : 0) : 1;
  __syncthreads();
  {
    int r = t >> 4, cp = t & 15;
    int j = row0 + r;
    bool ok = (j < M);
    int msk = mskL[r];
    float4 a0, a1, b0, b1;
    a0.x=a0.y=a0.z=a0.w=0.f; a1=a0; b0=a0; b1=a0;
    if (ok) {
      const float4* h4 = (const float4*)(h_in + (size_t)j * Hc);
      const float4* c4 = (const float4*)(c_in + (size_t)j * Hc);
      a0 = h4[cp]; a1 = h4[cp + 16]; b0 = c4[cp]; b1 = c4[cp + 16];
      ((float4*)(h_out + (size_t)j * Hc))[cp] = a0;
      ((float4*)(h_out + (size_t)j * Hc))[cp + 16] = a1;
      ((float4*)(c_out + (size_t)j * Hc))[cp] = b0;
      ((float4*)(c_out + (size_t)j * Hc))[cp + 16] = b1;
    }
    us4 zz; zz[0]=zz[1]=zz[2]=zz[3]=0;
    us4 ha0 = msk ? zz : f2bf4(a0), ha1 = msk ? zz : f2bf4(a1);
    us4 ca0 = msk ? zz : f2bf4(b0), ca1 = msk ? zz : f2bf4(b1);
    if (ok) {
      *(us4*)&H16[(size_t)j * Hc + cp * 4] = ha0;
      *(us4*)&H16[(size_t)j * Hc + 64 + cp * 4] = ha1;
      *(us4*)&C16[(size_t)j * Hc + cp * 4] = ca0;
      *(us4*)&C16[(size_t)j * Hc + 64 + cp * 4] = ca1;
    }
    *(us4*)&zh[r * HP + cp * 4] = ha0;
    *(us4*)&zh[r * HP + 64 + cp * 4] = ha1;
  }
  __syncthreads();

  const int w = t >> 6, lane = t & 63, lg = lane >> 4, cl = lane & 15;
  f32x4 acc0 = (f32x4){0.f,0.f,0.f,0.f}, acc1 = acc0;
  const ushortT* zr = &zh[cl * HP + lg * 8];
  #pragma unroll
  for (int kf = 0; kf < 4; ++kf) {
    bf16x8 a = *(const bf16x8*)&zr[kf * 32];
    acc0 = __builtin_amdgcn_mfma_f32_16x16x32_bf16(a, *wh_frag(pack, 3, w*2+0, kf, lane), acc0, 0, 0, 0);
    acc1 = __builtin_amdgcn_mfma_f32_16x16x32_bf16(a, *wh_frag(pack, 3, w*2+1, kf, lane), acc1, 0, 0, 0);
  }
  #pragma unroll
  for (int half = 0; half < 2; ++half) {
    int col = (w * 2 + half) * 16 + cl;
    f32x4 a_ = half ? acc1 : acc0;
    #pragma unroll
    for (int reg = 0; reg < 4; ++reg) {
      int j = row0 + lg * 4 + reg;
      if (j < M) Hf16[(size_t)j * Hc + col] = f2bf(a_[reg]);
    }
  }
}

// ---------------- Xg = x @ W*[0:256] + b*  (iteration-invariant gate x-parts) ----
// Xg layout: [spos][g*128 + col] bf16, g in {i,o,u,f}
__global__ __launch_bounds__(256) void xg_gemm(
    const float* __restrict__ fmess, const int* __restrict__ submess,
    const ushortT* __restrict__ pack,
    const float* __restrict__ bi, const float* __restrict__ bo,
    const float* __restrict__ bu, const float* __restrict__ bfb,
    ushortT* __restrict__ Xg, int S)
{
  __shared__ __align__(16) ushortT xs[16 * ZP2];
  __shared__ int msr[16];
  const int t = threadIdx.x;
  const int row0 = blockIdx.x * 16;

  if (t < 16) msr[t] = (row0 + t < S) ? submess[row0 + t] : -1;
  __syncthreads();
  {
    int r = t >> 4, cp = t & 15;
    int ms = msr[r];
    const float4* xr = (ms >= 0) ? (const float4*)(fmess + (size_t)ms * INc) : nullptr;
    #pragma unroll
    for (int q = 0; q < 4; ++q) {
      int slot = cp + q * 16;
      float4 v;
      if (xr) v = xr[slot]; else { v.x = v.y = v.z = v.w = 0.f; }
      *(us4*)&xs[r * ZP2 + slot * 4] = f2bf4(v);
    }
  }
  __syncthreads();

  const int w = t >> 6, lane = t & 63, lg = lane >> 4, cl = lane & 15;
  // wave w computes gate w over all 8 col-tiles, K = 256 (kt 0..7)
  f32x4 acc[8];
  #pragma unroll
  for (int i = 0; i < 8; ++i) acc[i] = (f32x4){0.f, 0.f, 0.f, 0.f};
  const ushortT* zr = &xs[cl * ZP2 + lg * 8];
  #pragma unroll
  for (int kt = 0; kt < 8; ++kt) {
    bf16x8 a = *(const bf16x8*)&zr[kt * 32];
    #pragma unroll
    for (int c = 0; c < 8; ++c) {
      bf16x8 b = *(const bf16x8*)&pack[(size_t)(((w * 8 + c) * 12 + kt) * 64 + lane) * 8];
      acc[c] = __builtin_amdgcn_mfma_f32_16x16x32_bf16(a, b, acc[c], 0, 0, 0);
    }
  }
  const float* bias = (w == 0) ? bi : (w == 1) ? bo : (w == 2) ? bu : bfb;
  #pragma unroll
  for (int c = 0; c < 8; ++c) {
    int col = c * 16 + cl;
    float bv = bias[col];
    #pragma unroll
    for (int reg = 0; reg < 4; ++reg) {
      int s = row0 + lg * 4 + reg;
      if (s < S) Xg[(size_t)s * 512 + w * 128 + col] = f2bf(acc[c][reg] + bv);
    }
  }
}

// ---------------- update shadows at sub rows from iter-0 output ----------------
__global__ __launch_bounds__(256) void update_sub(
    const float* __restrict__ h_out, const float* __restrict__ c_out,
    const int* __restrict__ submess, const ushortT* __restrict__ pack,
    ushortT* __restrict__ H16, ushortT* __restrict__ C16, ushortT* __restrict__ Hf16,
    int S)
{
  __shared__ __align__(16) ushortT zh[16 * HP];
  __shared__ int msL[16];
  const int t = threadIdx.x;
  const int row0 = blockIdx.x * 16;

  if (t < 16) msL[t] = (row0 + t < S) ? submess[row0 + t] : -1;
  __syncthreads();
  {
    int r = t >> 4, cp = t & 15;
    int ms = msL[r];
    float4 a0, a1, b0, b1;
    a0.x=a0.y=a0.z=a0.w=0.f; a1=a0; b0=a0; b1=a0;
    if (ms >= 0) {
      const float4* h4 = (const float4*)(h_out + (size_t)ms * Hc);
      const float4* c4 = (const float4*)(c_out + (size_t)ms * Hc);
      a0 = h4[cp]; a1 = h4[cp + 16]; b0 = c4[cp]; b1 = c4[cp + 16];
    }
    us4 ha0 = f2bf4(a0), ha1 = f2bf4(a1);
    if (ms >= 0) {
      *(us4*)&H16[(size_t)ms * Hc + cp * 4] = ha0;
      *(us4*)&H16[(size_t)ms * Hc + 64 + cp * 4] = ha1;
      *(us4*)&C16[(size_t)ms * Hc + cp * 4] = f2bf4(b0);
      *(us4*)&C16[(size_t)ms * Hc + 64 + cp * 4] = f2bf4(b1);
    }
    *(us4*)&zh[r * HP + cp * 4] = ha0;
    *(us4*)&zh[r * HP + 64 + cp * 4] = ha1;
  }
  __syncthreads();

  const int w = t >> 6, lane = t & 63, lg = lane >> 4, cl = lane & 15;
  f32x4 acc0 = (f32x4){0.f,0.f,0.f,0.f}, acc1 = acc0;
  const ushortT* zr = &zh[cl * HP + lg * 8];
  #pragma unroll
  for (int kf = 0; kf < 4; ++kf) {
    bf16x8 a = *(const bf16x8*)&zr[kf * 32];
    acc0 = __builtin_amdgcn_mfma_f32_16x16x32_bf16(a, *wh_frag(pack, 3, w*2+0, kf, lane), acc0, 0, 0, 0);
    acc1 = __builtin_amdgcn_mfma_f32_16x16x32_bf16(a, *wh_frag(pack, 3, w*2+1, kf, lane), acc1, 0, 0, 0);
  }
  #pragma unroll
  for (int half = 0; half < 2; ++half) {
    int col = (w * 2 + half) * 16 + cl;
    f32x4 a_ = half ? acc1 : acc0;
    #pragma unroll
    for (int reg = 0; reg < 4; ++reg) {
      int ms = msL[lg * 4 + reg];
      if (ms >= 0) Hf16[(size_t)ms * Hc + col] = f2bf(a_[reg]);
    }
  }
}

// ---- LSTM step: h-part gate MFMAs (24/wave) + Xg + gather epilogue ----
__global__ __launch_bounds__(256) void lstm_step5(
    const int* __restrict__ submess, const int* __restrict__ bgraph,
    const ushortT* __restrict__ H16, const ushortT* __restrict__ C16,
    const ushortT* __restrict__ Hf16, const ushortT* __restrict__ Xg,
    const ushortT* __restrict__ pack,
    float* __restrict__ dstH, float* __restrict__ dstC, int S)
{
  __shared__ __align__(16) ushortT zs[16 * HSP];    // h_sum staging (bf16)
  __shared__ __align__(16) ushortT pih[16 * EPH];   // gate h-part partials (bf16)
  __shared__ __align__(16) ushortT poh[16 * EPH];
  __shared__ __align__(16) ushortT puh[16 * EPH];
  __shared__ int nbj[16][Kc];
  __shared__ int msrow[16];

  const int t = threadIdx.x;
  const int row0 = blockIdx.x * 16;

  if (t < 128) {
    int r = t >> 3, k = t & 7;
    int s = row0 + r;
    int ms = (s < S) ? submess[s] : -1;
    if (k == 0) msrow[r] = ms;
    nbj[r][k] = (ms >= 0) ? bgraph[(size_t)ms * Kc + k] : 0;
  }
  __syncthreads();

  // ---- h_sum gather (bf16 shadow, branch-free) -> zs ----
  {
    int r = t >> 4, cp = t & 15;
    float sum[8] = {0.f,0.f,0.f,0.f,0.f,0.f,0.f,0.f};
    #pragma unroll
    for (int k = 0; k < Kc; ++k) {
      int j = nbj[r][k];
      us8 v = *(const us8*)&H16[(size_t)j * Hc + cp * 8];
      #pragma unroll
      for (int e = 0; e < 8; ++e) sum[e] += bf2f(v[e]);
    }
    us4 o0, o1;
    #pragma unroll
    for (int e = 0; e < 4; ++e) { o0[e] = f2bf(sum[e]); o1[e] = f2bf(sum[4 + e]); }
    *(us4*)&zs[r * HSP + cp * 8] = o0;
    *(us4*)&zs[r * HSP + cp * 8 + 4] = o1;
  }
  __syncthreads();

  const int w = t >> 6, lane = t & 63, lg = lane >> 4, cl = lane & 15;

  // ---- gate h-part K-loop: 3 gates x 2 col-tiles x 4 kt = 24 MFMAs/wave ----
  f32x4 acc[6];
  #pragma unroll
  for (int i = 0; i < 6; ++i) acc[i] = (f32x4){0.f, 0.f, 0.f, 0.f};
  const ushortT* zrow = &zs[cl * HSP + lg * 8];
  #pragma unroll
  for (int kf = 0; kf < 4; ++kf) {
    bf16x8 a = *(const bf16x8*)&zrow[kf * 32];
    #pragma unroll
    for (int g = 0; g < 3; ++g)
      #pragma unroll
      for (int half = 0; half < 2; ++half)
        acc[g * 2 + half] = __builtin_amdgcn_mfma_f32_16x16x32_bf16(
            a, *wh_frag(pack, g, w * 2 + half, kf, lane), acc[g * 2 + half], 0, 0, 0);
  }

  // ---- write partials (disjoint LDS; no barrier needed vs zs reads) ----
  #pragma unroll
  for (int half = 0; half < 2; ++half) {
    int col = (w * 2 + half) * 16 + cl;
    #pragma unroll
    for (int reg = 0; reg < 4; ++reg) {
      int row = lg * 4 + reg;
      pih[row * EPH + col] = f2bf(acc[0 + half][reg]);
      poh[row * EPH + col] = f2bf(acc[2 + half][reg]);
      puh[row * EPH + col] = f2bf(acc[4 + half][reg]);
    }
  }
  __syncthreads();

  // ---- epilogue: (row, 8-col chunk); Xg + partials + vectorized gathers ----
  {
    int r = t >> 4, cc = t & 15;
    int ms = msrow[r];
    const ushortT* xgr = Xg + (size_t)(row0 + r) * 512 + cc * 8;
    us8 xi8 = *(const us8*)&xgr[0];
    us8 xo8 = *(const us8*)&xgr[128];
    us8 xu8 = *(const us8*)&xgr[256];
    us8 xf8 = *(const us8*)&xgr[384];
    us8 pi8 = *(const us8*)&pih[r * EPH + cc * 8];
    us8 po8 = *(const us8*)&poh[r * EPH + cc * 8];
    us8 pu8 = *(const us8*)&puh[r * EPH + cc * 8];
    float fx[8], ovv[8], cacc[8];
    #pragma unroll
    for (int e = 0; e < 8; ++e) {
      float iv = fsig(bf2f(xi8[e]) + bf2f(pi8[e]));
      float uv = ftanh(bf2f(xu8[e]) + bf2f(pu8[e]));
      ovv[e] = fsig(bf2f(xo8[e]) + bf2f(po8[e]));
      fx[e] = bf2f(xf8[e]);
      cacc[e] = iv * uv;
    }
    #pragma unroll
    for (int k = 0; k < Kc; ++k) {
      int j = nbj[r][k];
      us8 hf8 = *(const us8*)&Hf16[(size_t)j * Hc + cc * 8];
      us8 cn8 = *(const us8*)&C16[(size_t)j * Hc + cc * 8];
      #pragma unroll
      for (int e = 0; e < 8; ++e)
        cacc[e] = fmaf(fsig(fx[e] + bf2f(hf8[e])), bf2f(cn8[e]), cacc[e]);
    }
    if (ms >= 0) {
      float hv[8];
      #pragma unroll
      for (int e = 0; e < 8; ++e) hv[e] = ovv[e] * ftanh(cacc[e]);
      float* dh = dstH + (size_t)ms * Hc + cc * 8;
      float* dc = dstC + (size_t)ms * Hc + cc * 8;
      *(float4*)&dh[0] = *(float4*)&hv[0];
      *(float4*)&dh[4] = *(float4*)&hv[4];
      *(float4*)&dc[0] = *(float4*)&cacc[0];
      *(float4*)&dc[4] = *(float4*)&cacc[4];
    }
  }
}

// ---------------- node readout (MFMA, unchanged) ----------------
__global__ __launch_bounds__(256) void node_readout_mfma(
    const float* __restrict__ fnode, const int* __restrict__ agraph,
    const int* __restrict__ subnode, const float* __restrict__ hfull,
    const ushortT* __restrict__ packWn, const float* __restrict__ bn,
    float* __restrict__ node_buf, int Nsub)
{
  __shared__ __align__(16) ushortT z2[16 * ZP2];
  __shared__ int orow[16];
  __shared__ const float* aptr[16][Kc];

  const int t = threadIdx.x;
  const int row0 = blockIdx.x * 16;

  if (t < 16) orow[t] = (row0 + t < Nsub) ? subnode[row0 + t] : -1;
  if (t >= 64 && t < 64 + 128) {
    int i = t - 64, r = i >> 3, k = i & 7;
    int v = row0 + r;
    aptr[r][k] = (v < Nsub) ? hfull + (size_t)agraph[(size_t)v * Kc + k] * Hc : nullptr;
  }
  {
    int r = t >> 4, cp = t & 15;
    int v = row0 + r;
    const float4* fr = (v < Nsub) ? (const float4*)(fnode + (size_t)v * Hc) : nullptr;
    float4 v0, v1; v0.x = v0.y = v0.z = v0.w = 0.f; v1 = v0;
    if (fr) { v0 = fr[cp]; v1 = fr[cp + 16]; }
    *(us4*)&z2[r * ZP2 + cp * 4] = f2bf4(v0);
    *(us4*)&z2[r * ZP2 + 64 + cp * 4] = f2bf4(v1);
  }
  __syncthreads();
  {
    int r = t >> 4, cp = t & 15;
    float4 s0, s1; s0.x = s0.y = s0.z = s0.w = 0.f; s1 = s0;
    #pragma unroll
    for (int k = 0; k < Kc; ++k) {
      const float* p = aptr[r][k];
      if (p) {
        float4 v0 = ((const float4*)p)[cp], v1 = ((const float4*)p)[cp + 16];
        s0.x += v0.x; s0.y += v0.y; s0.z += v0.z; s0.w += v0.w;
        s1.x += v1.x; s1.y += v1.y; s1.z += v1.z; s1.w += v1.w;
      }
    }
    *(us4*)&z2[r * ZP2 + Hc + cp * 4] = f2bf4(s0);
    *(us4*)&z2[r * ZP2 + Hc + 64 + cp * 4] = f2bf4(s1);
  }
  __syncthreads();

  const int w = t >> 6, lane = t & 63;
  const int lg = lane >> 4, cl = lane & 15;

  f32x4 acc0 = (f32x4){0.f,0.f,0.f,0.f};
  f32x4 acc1 = (f32x4){0.f,0.f,0.f,0.f};
  const ushortT* zr = &z2[cl * ZP2 + lg * 8];
  #pragma unroll
  for (int kt = 0; kt < 8; ++kt) {
    bf16x8 a = *(const bf16x8*)&zr[kt * 32];
    bf16x8 b0 = *(const bf16x8*)&packWn[(size_t)(((w * 2 + 0) * 8 + kt) * 64 + lane) * 8];
    bf16x8 b1 = *(const bf16x8*)&packWn[(size_t)(((w * 2 + 1) * 8 + kt) * 64 + lane) * 8];
    acc0 = __builtin_amdgcn_mfma_f32_16x16x32_bf16(a, b0, acc0, 0, 0, 0);
    acc1 = __builtin_amdgcn_mfma_f32_16x16x32_bf16(a, b1, acc1, 0, 0, 0);
  }
  #pragma unroll
  for (int half = 0; half < 2; ++half) {
    int col = (w * 2 + half) * 16 + cl;
    float bnv = bn[col];
    f32x4 a_ = half ? acc1 : acc0;
    #pragma unroll
    for (int reg = 0; reg < 4; ++reg) {
      int row = lg * 4 + reg;
      int o = orow[row];
      if (o >= 0) node_buf[(size_t)o * Hc + col] = fmaxf(a_[reg] + bnv, 0.f);
    }
  }
}

// ---------------- launch ----------------
extern "C" void kernel_launch(void* const* d_in, const int* in_sizes, int n_in,
                              void* d_out, int out_size, void* d_ws, size_t ws_size,
                              hipStream_t stream) {
  const float* fnode   = (const float*)d_in[0];
  const float* fmess   = (const float*)d_in[1];
  const int*   agraph  = (const int*)d_in[2];
  const int*   bgraph  = (const int*)d_in[3];
  const float* h_in    = (const float*)d_in[4];
  const float* c_in    = (const float*)d_in[5];
  const int*   submess = (const int*)d_in[6];
  const int*   subnode = (const int*)d_in[7];
  const float* Wi = (const float*)d_in[9];
  const float* bi = (const float*)d_in[10];
  const float* Wo = (const float*)d_in[11];
  const float* bo = (const float*)d_in[12];
  const float* Wf = (const float*)d_in[13];
  const float* bf_ = (const float*)d_in[14];
  const float* Wu = (const float*)d_in[15];
  const float* bu = (const float*)d_in[16];
  const float* Wn = (const float*)d_in[17];
  const float* bn = (const float*)d_in[18];

  const int S    = in_sizes[6];
  const int Nsub = in_sizes[2] / Kc;
  const int M    = in_sizes[4] / Hc;
  const int num_nodes = out_size / Hc - 2 * M;

  float* node_buf = (float*)d_out;
  float* h_out = node_buf + (size_t)num_nodes * Hc;
  float* c_out = h_out + (size_t)M * Hc;

  const int lblocks = (S + 15) / 16;

  // ws layout: mark[M] | pack | Hf16[M*128] | C16[M*128] | Xg[lblocks*16*512] (all bf16)
  // H16[M*128] bf16 lives in the node_buf region (zeroed only after iter1).
  int* mark = (int*)d_ws;
  size_t off = (((size_t)M * sizeof(int)) + 255) & ~(size_t)255;
  ushortT* pack = (ushortT*)((char*)d_ws + off);
  off += (((size_t)(GATE_FRAGS + WN_FRAGS) * 8 * sizeof(ushortT)) + 255) & ~(size_t)255;
  ushortT* Hf16 = (ushortT*)((char*)d_ws + off);
  off += (((size_t)M * Hc * sizeof(ushortT)) + 255) & ~(size_t)255;
  ushortT* C16 = (ushortT*)((char*)d_ws + off);
  off += (((size_t)M * Hc * sizeof(ushortT)) + 255) & ~(size_t)255;
  ushortT* Xg = (ushortT*)((char*)d_ws + off);
  ushortT* H16 = (ushortT*)node_buf;   // 30.7MB <= num_nodes*Hc*4 = 33.5MB
  ushortT* packWn = pack + (size_t)GATE_FRAGS * 8;

  // 1. mark + weight repack
  hipLaunchKernelGGL(mark_init, dim3((M + 255) / 256), dim3(256), 0, stream, mark, M);
  hipLaunchKernelGGL(mark_set,  dim3((S + 255) / 256), dim3(256), 0, stream, mark, submess, S);
  hipLaunchKernelGGL(repack_weights, dim3((GATE_FRAGS + WN_FRAGS + 255) / 256), dim3(256), 0, stream,
                     Wi, Wo, Wu, Wf, Wn, pack);

  // 2. precompute: h/c passthrough + masked bf16 shadows + Hf = masked h @ Wf2
  hipLaunchKernelGGL(precompute, dim3((M + 15) / 16), dim3(256), 0, stream,
                     h_in, c_in, mark, pack, h_out, c_out, H16, C16, Hf16, M);

  // 3. Xg = x @ W*[0:256] + b* (once; reused by both iterations)
  hipLaunchKernelGGL(xg_gemm, dim3(lblocks), dim3(256), 0, stream,
                     fmess, submess, pack, bi, bo, bu, bf_, Xg, S);

  // 4. iter 0
  hipLaunchKernelGGL(lstm_step5, dim3(lblocks), dim3(256), 0, stream,
      submess, bgraph, H16, C16, Hf16, Xg, pack, h_out, c_out, S);
  // 5. refresh shadows at sub rows
  hipLaunchKernelGGL(update_sub, dim3(lblocks), dim3(256), 0, stream,
      h_out, c_out, submess, pack, H16, C16, Hf16, S);
  // 6. iter 1
  hipLaunchKernelGGL(lstm_step5, dim3(lblocks), dim3(256), 0, stream,
      submess, bgraph, H16, C16, Hf16, Xg, pack, h_out, c_out, S);

  // 7. zero node_buf (erases H16 shadow), then node readout
  long nn4 = (long)num_nodes * Hc / 4;
  long zb = (nn4 + 255) / 256; if (zb > 8192) zb = 8192;
  hipLaunchKernelGGL(zero_f4, dim3((int)zb), dim3(256), 0, stream, (float4*)node_buf, nn4);

  const int nblocks = (Nsub + 15) / 16;
  hipLaunchKernelGGL(node_readout_mfma, dim3(nblocks), dim3(256), 0, stream,
      fnode, agraph, subnode, h_out, packWn, bn, node_buf, S);
}

// Round 7
// 356.783 us; speedup vs baseline: 1.7471x; 1.0590x over previous
//
#include <hip/hip_runtime.h>
#include <cstdint>
#include <cstddef>

#define Hc   128
#define INc  256
#define Kc   8
#define HP   136          // precompute staging row pad (ushorts)
#define HSP  136          // lstm h_sum/h_new staging row pad (ushorts)
#define EPH  136          // lstm gate-partial arrays row pad (ushorts)
#define ZP2  264          // node/x staging row pad (ushorts)

typedef unsigned short ushortT;
typedef __attribute__((ext_vector_type(8))) short bf16x8;
typedef __attribute__((ext_vector_type(4))) float f32x4;
typedef __attribute__((ext_vector_type(4))) unsigned short us4;
typedef __attribute__((ext_vector_type(8))) unsigned short us8;

// fast sigmoid: exp(-x)->inf => rcp->0 ; exp(-x)->0 => 1 (no clamps needed)
__device__ __forceinline__ float fsig(float x) {
  return __builtin_amdgcn_rcpf(1.f + __expf(-x));
}
// fast tanh: upper clamp only (avoid inf/inf); e->0 gives -1 exactly
__device__ __forceinline__ float ftanh(float x) {
  float e = __expf(2.f * fminf(x, 15.f));
  return (e - 1.f) * __builtin_amdgcn_rcpf(e + 1.f);
}
__device__ __forceinline__ ushortT f2bf(float f) {
  unsigned u = __builtin_bit_cast(unsigned, f);
  unsigned r = (u + 0x7fffu + ((u >> 16) & 1u)) >> 16;
  return (ushortT)r;
}
__device__ __forceinline__ us4 f2bf4(float4 v) {
  us4 o; o[0] = f2bf(v.x); o[1] = f2bf(v.y); o[2] = f2bf(v.z); o[3] = f2bf(v.w);
  return o;
}
__device__ __forceinline__ float bf2f(ushortT u) {
  return __builtin_bit_cast(float, (unsigned)u << 16);
}

// ---------------- utility kernels ----------------
__global__ void zero_f4(float4* __restrict__ p, long n4) {
  long i = (long)blockIdx.x * blockDim.x + threadIdx.x;
  long stride = (long)gridDim.x * blockDim.x;
  float4 z; z.x = z.y = z.z = z.w = 0.f;
  for (; i < n4; i += stride) p[i] = z;
}
__global__ void mark_init(int* __restrict__ mark, int M) {
  int i = blockIdx.x * blockDim.x + threadIdx.x;
  if (i < M) mark[i] = -1;
}
__global__ void mark_set(int* __restrict__ mark, const int* __restrict__ submess, int S) {
  int i = blockIdx.x * blockDim.x + threadIdx.x;
  if (i < S) mark[submess[i]] = i;
}

// ---------------- weight repack into B-fragment order (verified R2-R6) ----------
// gates: idx = ((g*8 + c)*12 + kt)*64 + lane ; elem j:
//        W_g[kt*32 + (lane>>4)*8 + j][c*16 + (lane&15)]  (kt 0..11 spans K=384)
#define GATE_FRAGS (4*8*12*64)
#define WN_FRAGS   (8*8*64)
__global__ void repack_weights(const float* __restrict__ Wi, const float* __restrict__ Wo,
                               const float* __restrict__ Wu, const float* __restrict__ Wf,
                               const float* __restrict__ Wn, ushortT* __restrict__ pack) {
  int idx = blockIdx.x * blockDim.x + threadIdx.x;
  if (idx < GATE_FRAGS) {
    int lane = idx & 63;
    int kt = (idx >> 6) % 12;
    int gc = idx / (64 * 12);
    int c = gc & 7, g = gc >> 3;
    const float* W = (g == 0) ? Wi : (g == 1) ? Wo : (g == 2) ? Wu : Wf;
    int k0 = kt * 32 + (lane >> 4) * 8;
    int col = c * 16 + (lane & 15);
    ushortT* dst = pack + (size_t)idx * 8;
    #pragma unroll
    for (int j = 0; j < 8; ++j) dst[j] = f2bf(W[(size_t)(k0 + j) * Hc + col]);
  } else if (idx < GATE_FRAGS + WN_FRAGS) {
    int i2 = idx - GATE_FRAGS;
    int lane = i2 & 63;
    int kt = (i2 >> 6) & 7;
    int c = i2 >> 9;
    int k0 = kt * 32 + (lane >> 4) * 8;
    int col = c * 16 + (lane & 15);
    ushortT* dst = pack + (size_t)GATE_FRAGS * 8 + (size_t)i2 * 8;
    #pragma unroll
    for (int j = 0; j < 8; ++j) dst[j] = f2bf(Wn[(size_t)(k0 + j) * Hc + col]);
  }
}

// W*2 B-fragment (h-part rows 256..383 of gate g => kt slots 8..11)
__device__ __forceinline__ const bf16x8* wh_frag(const ushortT* pack, int g, int cw, int kf, int lane) {
  return (const bf16x8*)&pack[(size_t)(((g * 8 + cw) * 12 + (8 + kf)) * 64 + lane) * 8];
}

// ---------------- precompute: non-sub passthrough + masked shadows + Hf --------
// shadows are the EXTENDED arrays; this kernel fills rows [0, M).
__global__ __launch_bounds__(256) void precompute(
    const float* __restrict__ h_in, const float* __restrict__ c_in,
    const int* __restrict__ mark, const ushortT* __restrict__ pack,
    float* __restrict__ h_out, float* __restrict__ c_out,
    ushortT* H16, ushortT* C16, ushortT* Hf16,
    int M)
{
  __shared__ __align__(16) ushortT zh[16 * HP];
  __shared__ int mskL[16];
  const int t = threadIdx.x;
  const int row0 = blockIdx.x * 16;

  if (t < 16) mskL[t] = (row0 + t < M) ? (mark[row0 + t] >= 0 ? 1 : 0) : 1;
  __syncthreads();
  {
    int r = t >> 4, cp = t & 15;
    int j = row0 + r;
    bool ok = (j < M);
    int msk = mskL[r];
    float4 a0, a1, b0, b1;
    a0.x=a0.y=a0.z=a0.w=0.f; a1=a0; b0=a0; b1=a0;
    if (ok) {
      const float4* h4 = (const float4*)(h_in + (size_t)j * Hc);
      const float4* c4 = (const float4*)(c_in + (size_t)j * Hc);
      a0 = h4[cp]; a1 = h4[cp + 16]; b0 = c4[cp]; b1 = c4[cp + 16];
      if (!msk) {   // sub rows of h_out/c_out are written by iter1 — skip dead stores
        ((float4*)(h_out + (size_t)j * Hc))[cp] = a0;
        ((float4*)(h_out + (size_t)j * Hc))[cp + 16] = a1;
        ((float4*)(c_out + (size_t)j * Hc))[cp] = b0;
        ((float4*)(c_out + (size_t)j * Hc))[cp + 16] = b1;
      }
    }
    us4 zz; zz[0]=zz[1]=zz[2]=zz[3]=0;
    us4 ha0 = msk ? zz : f2bf4(a0), ha1 = msk ? zz : f2bf4(a1);
    us4 ca0 = msk ? zz : f2bf4(b0), ca1 = msk ? zz : f2bf4(b1);
    if (ok) {
      *(us4*)&H16[(size_t)j * Hc + cp * 4] = ha0;
      *(us4*)&H16[(size_t)j * Hc + 64 + cp * 4] = ha1;
      *(us4*)&C16[(size_t)j * Hc + cp * 4] = ca0;
      *(us4*)&C16[(size_t)j * Hc + 64 + cp * 4] = ca1;
    }
    *(us4*)&zh[r * HP + cp * 4] = ha0;
    *(us4*)&zh[r * HP + 64 + cp * 4] = ha1;
  }
  __syncthreads();

  const int w = t >> 6, lane = t & 63, lg = lane >> 4, cl = lane & 15;
  f32x4 acc0 = (f32x4){0.f,0.f,0.f,0.f}, acc1 = acc0;
  const ushortT* zr = &zh[cl * HP + lg * 8];
  #pragma unroll
  for (int kf = 0; kf < 4; ++kf) {
    bf16x8 a = *(const bf16x8*)&zr[kf * 32];
    acc0 = __builtin_amdgcn_mfma_f32_16x16x32_bf16(a, *wh_frag(pack, 3, w*2+0, kf, lane), acc0, 0, 0, 0);
    acc1 = __builtin_amdgcn_mfma_f32_16x16x32_bf16(a, *wh_frag(pack, 3, w*2+1, kf, lane), acc1, 0, 0, 0);
  }
  #pragma unroll
  for (int half = 0; half < 2; ++half) {
    int col = (w * 2 + half) * 16 + cl;
    f32x4 a_ = half ? acc1 : acc0;
    #pragma unroll
    for (int reg = 0; reg < 4; ++reg) {
      int j = row0 + lg * 4 + reg;
      if (j < M) Hf16[(size_t)j * Hc + col] = f2bf(a_[reg]);
    }
  }
}

// ---------------- Xg = x @ W*[0:256] + b*  (iteration-invariant gate x-parts) ----
// Xg layout: [spos][g*128 + col] bf16, g in {i,o,u,f}
__global__ __launch_bounds__(256) void xg_gemm(
    const float* __restrict__ fmess, const int* __restrict__ submess,
    const ushortT* __restrict__ pack,
    const float* __restrict__ bi, const float* __restrict__ bo,
    const float* __restrict__ bu, const float* __restrict__ bfb,
    ushortT* __restrict__ Xg, int S)
{
  __shared__ __align__(16) ushortT xs[16 * ZP2];
  __shared__ int msr[16];
  const int t = threadIdx.x;
  const int row0 = blockIdx.x * 16;

  if (t < 16) msr[t] = (row0 + t < S) ? submess[row0 + t] : -1;
  __syncthreads();
  {
    int r = t >> 4, cp = t & 15;
    int ms = msr[r];
    const float4* xr = (ms >= 0) ? (const float4*)(fmess + (size_t)ms * INc) : nullptr;
    #pragma unroll
    for (int q = 0; q < 4; ++q) {
      int slot = cp + q * 16;
      float4 v;
      if (xr) v = xr[slot]; else { v.x = v.y = v.z = v.w = 0.f; }
      *(us4*)&xs[r * ZP2 + slot * 4] = f2bf4(v);
    }
  }
  __syncthreads();

  const int w = t >> 6, lane = t & 63, lg = lane >> 4, cl = lane & 15;
  // wave w computes gate w over all 8 col-tiles, K = 256 (kt 0..7)
  f32x4 acc[8];
  #pragma unroll
  for (int i = 0; i < 8; ++i) acc[i] = (f32x4){0.f, 0.f, 0.f, 0.f};
  const ushortT* zr = &xs[cl * ZP2 + lg * 8];
  #pragma unroll
  for (int kt = 0; kt < 8; ++kt) {
    bf16x8 a = *(const bf16x8*)&zr[kt * 32];
    #pragma unroll
    for (int c = 0; c < 8; ++c) {
      bf16x8 b = *(const bf16x8*)&pack[(size_t)(((w * 8 + c) * 12 + kt) * 64 + lane) * 8];
      acc[c] = __builtin_amdgcn_mfma_f32_16x16x32_bf16(a, b, acc[c], 0, 0, 0);
    }
  }
  const float* bias = (w == 0) ? bi : (w == 1) ? bo : (w == 2) ? bu : bfb;
  #pragma unroll
  for (int c = 0; c < 8; ++c) {
    int col = c * 16 + cl;
    float bv = bias[col];
    #pragma unroll
    for (int reg = 0; reg < 4; ++reg) {
      int s = row0 + lg * 4 + reg;
      if (s < S) Xg[(size_t)s * 512 + w * 128 + col] = f2bf(acc[c][reg] + bv);
    }
  }
}

// ---- LSTM step over extended shadows ----
// MODE 0 (iter0): reads shadow rows [0,M); writes h/c/Hf shadows at rows M+spos.
// MODE 1 (iter1): neighbor ids translated j -> M+mark[j] for sub rows;
//                 writes final f32 h_out/c_out at submess rows.
template<int MODE>
__global__ __launch_bounds__(256) void lstm_step6(
    const int* __restrict__ submess, const int* __restrict__ bgraph,
    const int* __restrict__ mark,
    ushortT* H16x, ushortT* C16x, ushortT* Hf16x,
    const ushortT* __restrict__ Xg, const ushortT* __restrict__ pack,
    float* __restrict__ dstH, float* __restrict__ dstC, int S, int M)
{
  __shared__ __align__(16) ushortT zs[16 * HSP];    // h_sum staging; reused for h_new (MODE 0)
  __shared__ __align__(16) ushortT pih[16 * EPH];   // gate h-part partials (bf16)
  __shared__ __align__(16) ushortT poh[16 * EPH];
  __shared__ __align__(16) ushortT puh[16 * EPH];
  __shared__ int nbj[16][Kc];
  __shared__ int msrow[16];

  const int t = threadIdx.x;
  const int row0 = blockIdx.x * 16;

  if (t < 128) {
    int r = t >> 3, k = t & 7;
    int s = row0 + r;
    int ms = (s < S) ? submess[s] : -1;
    if (k == 0) msrow[r] = ms;
    int j = (ms >= 0) ? bgraph[(size_t)ms * Kc + k] : 0;
    if (MODE == 1 && ms >= 0) {
      int m = mark[j];
      if (m >= 0) j = M + m;    // redirect sub neighbors to updated compact rows
    }
    nbj[r][k] = j;
  }
  __syncthreads();

  // ---- h_sum gather (branch-free) -> zs ----
  {
    int r = t >> 4, cp = t & 15;
    float sum[8] = {0.f,0.f,0.f,0.f,0.f,0.f,0.f,0.f};
    #pragma unroll
    for (int k = 0; k < Kc; ++k) {
      int j = nbj[r][k];
      us8 v = *(const us8*)&H16x[(size_t)j * Hc + cp * 8];
      #pragma unroll
      for (int e = 0; e < 8; ++e) sum[e] += bf2f(v[e]);
    }
    us4 o0, o1;
    #pragma unroll
    for (int e = 0; e < 4; ++e) { o0[e] = f2bf(sum[e]); o1[e] = f2bf(sum[4 + e]); }
    *(us4*)&zs[r * HSP + cp * 8] = o0;
    *(us4*)&zs[r * HSP + cp * 8 + 4] = o1;
  }
  __syncthreads();

  const int w = t >> 6, lane = t & 63, lg = lane >> 4, cl = lane & 15;

  // ---- gate h-part K-loop: 3 gates x 2 col-tiles x 4 kt = 24 MFMAs/wave ----
  f32x4 acc[6];
  #pragma unroll
  for (int i = 0; i < 6; ++i) acc[i] = (f32x4){0.f, 0.f, 0.f, 0.f};
  const ushortT* zrow = &zs[cl * HSP + lg * 8];
  #pragma unroll
  for (int kf = 0; kf < 4; ++kf) {
    bf16x8 a = *(const bf16x8*)&zrow[kf * 32];
    #pragma unroll
    for (int g = 0; g < 3; ++g)
      #pragma unroll
      for (int half = 0; half < 2; ++half)
        acc[g * 2 + half] = __builtin_amdgcn_mfma_f32_16x16x32_bf16(
            a, *wh_frag(pack, g, w * 2 + half, kf, lane), acc[g * 2 + half], 0, 0, 0);
  }

  // ---- write partials (disjoint LDS arrays) ----
  #pragma unroll
  for (int half = 0; half < 2; ++half) {
    int col = (w * 2 + half) * 16 + cl;
    #pragma unroll
    for (int reg = 0; reg < 4; ++reg) {
      int row = lg * 4 + reg;
      pih[row * EPH + col] = f2bf(acc[0 + half][reg]);
      poh[row * EPH + col] = f2bf(acc[2 + half][reg]);
      puh[row * EPH + col] = f2bf(acc[4 + half][reg]);
    }
  }
  __syncthreads();   // also covers last zs a-frag reads before MODE-0 zs overwrite

  // ---- epilogue: (row, 8-col chunk); Xg + partials + vectorized gathers ----
  {
    int r = t >> 4, cc = t & 15;
    int ms = msrow[r];
    const ushortT* xgr = Xg + (size_t)(row0 + r) * 512 + cc * 8;
    us8 xi8 = *(const us8*)&xgr[0];
    us8 xo8 = *(const us8*)&xgr[128];
    us8 xu8 = *(const us8*)&xgr[256];
    us8 xf8 = *(const us8*)&xgr[384];
    us8 pi8 = *(const us8*)&pih[r * EPH + cc * 8];
    us8 po8 = *(const us8*)&poh[r * EPH + cc * 8];
    us8 pu8 = *(const us8*)&puh[r * EPH + cc * 8];
    float fx[8], ovv[8], cacc[8];
    #pragma unroll
    for (int e = 0; e < 8; ++e) {
      float iv = fsig(bf2f(xi8[e]) + bf2f(pi8[e]));
      float uv = ftanh(bf2f(xu8[e]) + bf2f(pu8[e]));
      ovv[e] = fsig(bf2f(xo8[e]) + bf2f(po8[e]));
      fx[e] = bf2f(xf8[e]);
      cacc[e] = iv * uv;
    }
    #pragma unroll
    for (int k = 0; k < Kc; ++k) {
      int j = nbj[r][k];
      us8 hf8 = *(const us8*)&Hf16x[(size_t)j * Hc + cc * 8];
      us8 cn8 = *(const us8*)&C16x[(size_t)j * Hc + cc * 8];
      #pragma unroll
      for (int e = 0; e < 8; ++e)
        cacc[e] = fmaf(fsig(fx[e] + bf2f(hf8[e])), bf2f(cn8[e]), cacc[e]);
    }
    float hv[8];
    #pragma unroll
    for (int e = 0; e < 8; ++e) hv[e] = ovv[e] * ftanh(cacc[e]);

    if (MODE == 0) {
      int spos = row0 + r;
      us8 h8, c8;
      #pragma unroll
      for (int e = 0; e < 8; ++e) {
        h8[e] = (spos < S) ? f2bf(hv[e]) : (ushortT)0;
        c8[e] = f2bf(cacc[e]);
      }
      if (spos < S) {
        *(us8*)&H16x[(size_t)(M + spos) * Hc + cc * 8] = h8;
        *(us8*)&C16x[(size_t)(M + spos) * Hc + cc * 8] = c8;
      }
      // stage h_new (bf16) for the Hf MFMA phase
      *(us4*)&zs[r * HSP + cc * 8]     = (us4){h8[0], h8[1], h8[2], h8[3]};
      *(us4*)&zs[r * HSP + cc * 8 + 4] = (us4){h8[4], h8[5], h8[6], h8[7]};
    } else {
      if (ms >= 0) {
        float* dh = dstH + (size_t)ms * Hc + cc * 8;
        float* dc = dstC + (size_t)ms * Hc + cc * 8;
        *(float4*)&dh[0] = *(float4*)&hv[0];
        *(float4*)&dh[4] = *(float4*)&hv[4];
        *(float4*)&dc[0] = *(float4*)&cacc[0];
        *(float4*)&dc[4] = *(float4*)&cacc[4];
      }
    }
  }

  if (MODE == 0) {
    // ---- Hf_new = h_new @ Wf2, scatter into rows M+spos ----
    __syncthreads();
    f32x4 a0 = (f32x4){0.f,0.f,0.f,0.f}, a1 = a0;
    const ushortT* zr2 = &zs[cl * HSP + lg * 8];
    #pragma unroll
    for (int kf = 0; kf < 4; ++kf) {
      bf16x8 a = *(const bf16x8*)&zr2[kf * 32];
      a0 = __builtin_amdgcn_mfma_f32_16x16x32_bf16(a, *wh_frag(pack, 3, w*2+0, kf, lane), a0, 0, 0, 0);
      a1 = __builtin_amdgcn_mfma_f32_16x16x32_bf16(a, *wh_frag(pack, 3, w*2+1, kf, lane), a1, 0, 0, 0);
    }
    #pragma unroll
    for (int half = 0; half < 2; ++half) {
      int col = (w * 2 + half) * 16 + cl;
      f32x4 a_ = half ? a1 : a0;
      #pragma unroll
      for (int reg = 0; reg < 4; ++reg) {
        int sp = row0 + lg * 4 + reg;
        if (sp < S) Hf16x[(size_t)(M + sp) * Hc + col] = f2bf(a_[reg]);
      }
    }
  }
}

// ---------------- node readout (MFMA, unchanged) ----------------
__global__ __launch_bounds__(256) void node_readout_mfma(
    const float* __restrict__ fnode, const int* __restrict__ agraph,
    const int* __restrict__ subnode, const float* __restrict__ hfull,
    const ushortT* __restrict__ packWn, const float* __restrict__ bn,
    float* __restrict__ node_buf, int Nsub)
{
  __shared__ __align__(16) ushortT z2[16 * ZP2];
  __shared__ int orow[16];
  __shared__ const float* aptr[16][Kc];

  const int t = threadIdx.x;
  const int row0 = blockIdx.x * 16;

  if (t < 16) orow[t] = (row0 + t < Nsub) ? subnode[row0 + t] : -1;
  if (t >= 64 && t < 64 + 128) {
    int i = t - 64, r = i >> 3, k = i & 7;
    int v = row0 + r;
    aptr[r][k] = (v < Nsub) ? hfull + (size_t)agraph[(size_t)v * Kc + k] * Hc : nullptr;
  }
  {
    int r = t >> 4, cp = t & 15;
    int v = row0 + r;
    const float4* fr = (v < Nsub) ? (const float4*)(fnode + (size_t)v * Hc) : nullptr;
    float4 v0, v1; v0.x = v0.y = v0.z = v0.w = 0.f; v1 = v0;
    if (fr) { v0 = fr[cp]; v1 = fr[cp + 16]; }
    *(us4*)&z2[r * ZP2 + cp * 4] = f2bf4(v0);
    *(us4*)&z2[r * ZP2 + 64 + cp * 4] = f2bf4(v1);
  }
  __syncthreads();
  {
    int r = t >> 4, cp = t & 15;
    float4 s0, s1; s0.x = s0.y = s0.z = s0.w = 0.f; s1 = s0;
    #pragma unroll
    for (int k = 0; k < Kc; ++k) {
      const float* p = aptr[r][k];
      if (p) {
        float4 v0 = ((const float4*)p)[cp], v1 = ((const float4*)p)[cp + 16];
        s0.x += v0.x; s0.y += v0.y; s0.z += v0.z; s0.w += v0.w;
        s1.x += v1.x; s1.y += v1.y; s1.z += v1.z; s1.w += v1.w;
      }
    }
    *(us4*)&z2[r * ZP2 + Hc + cp * 4] = f2bf4(s0);
    *(us4*)&z2[r * ZP2 + Hc + 64 + cp * 4] = f2bf4(s1);
  }
  __syncthreads();

  const int w = t >> 6, lane = t & 63;
  const int lg = lane >> 4, cl = lane & 15;

  f32x4 acc0 = (f32x4){0.f,0.f,0.f,0.f};
  f32x4 acc1 = (f32x4){0.f,0.f,0.f,0.f};
  const ushortT* zr = &z2[cl * ZP2 + lg * 8];
  #pragma unroll
  for (int kt = 0; kt < 8; ++kt) {
    bf16x8 a = *(const bf16x8*)&zr[kt * 32];
    bf16x8 b0 = *(const bf16x8*)&packWn[(size_t)(((w * 2 + 0) * 8 + kt) * 64 + lane) * 8];
    bf16x8 b1 = *(const bf16x8*)&packWn[(size_t)(((w * 2 + 1) * 8 + kt) * 64 + lane) * 8];
    acc0 = __builtin_amdgcn_mfma_f32_16x16x32_bf16(a, b0, acc0, 0, 0, 0);
    acc1 = __builtin_amdgcn_mfma_f32_16x16x32_bf16(a, b1, acc1, 0, 0, 0);
  }
  #pragma unroll
  for (int half = 0; half < 2; ++half) {
    int col = (w * 2 + half) * 16 + cl;
    float bnv = bn[col];
    f32x4 a_ = half ? acc1 : acc0;
    #pragma unroll
    for (int reg = 0; reg < 4; ++reg) {
      int row = lg * 4 + reg;
      int o = orow[row];
      if (o >= 0) node_buf[(size_t)o * Hc + col] = fmaxf(a_[reg] + bnv, 0.f);
    }
  }
}

// ---------------- launch ----------------
extern "C" void kernel_launch(void* const* d_in, const int* in_sizes, int n_in,
                              void* d_out, int out_size, void* d_ws, size_t ws_size,
                              hipStream_t stream) {
  const float* fnode   = (const float*)d_in[0];
  const float* fmess   = (const float*)d_in[1];
  const int*   agraph  = (const int*)d_in[2];
  const int*   bgraph  = (const int*)d_in[3];
  const float* h_in    = (const float*)d_in[4];
  const float* c_in    = (const float*)d_in[5];
  const int*   submess = (const int*)d_in[6];
  const int*   subnode = (const int*)d_in[7];
  const float* Wi = (const float*)d_in[9];
  const float* bi = (const float*)d_in[10];
  const float* Wo = (const float*)d_in[11];
  const float* bo = (const float*)d_in[12];
  const float* Wf = (const float*)d_in[13];
  const float* bf_ = (const float*)d_in[14];
  const float* Wu = (const float*)d_in[15];
  const float* bu = (const float*)d_in[16];
  const float* Wn = (const float*)d_in[17];
  const float* bn = (const float*)d_in[18];

  const int S    = in_sizes[6];
  const int Nsub = in_sizes[2] / Kc;
  const int M    = in_sizes[4] / Hc;
  const int num_nodes = out_size / Hc - 2 * M;

  float* node_buf = (float*)d_out;
  float* h_out = node_buf + (size_t)num_nodes * Hc;
  float* c_out = h_out + (size_t)M * Hc;

  const int lblocks = (S + 15) / 16;

  // ws layout: mark[M] | pack | Hf16x[(M+S)*128] | C16x[(M+S)*128] | H16x[(M+S)*128]
  //            | Xg[lblocks*16*512]   (all shadow arrays bf16, extended by S rows)
  int* mark = (int*)d_ws;
  size_t off = (((size_t)M * sizeof(int)) + 255) & ~(size_t)255;
  ushortT* pack = (ushortT*)((char*)d_ws + off);
  off += (((size_t)(GATE_FRAGS + WN_FRAGS) * 8 * sizeof(ushortT)) + 255) & ~(size_t)255;
  size_t shadow_bytes = (((size_t)(M + S) * Hc * sizeof(ushortT)) + 255) & ~(size_t)255;
  ushortT* Hf16x = (ushortT*)((char*)d_ws + off); off += shadow_bytes;
  ushortT* C16x  = (ushortT*)((char*)d_ws + off); off += shadow_bytes;
  ushortT* H16x  = (ushortT*)((char*)d_ws + off); off += shadow_bytes;
  ushortT* Xg    = (ushortT*)((char*)d_ws + off);
  ushortT* packWn = pack + (size_t)GATE_FRAGS * 8;

  // 1. mark + weight repack
  hipLaunchKernelGGL(mark_init, dim3((M + 255) / 256), dim3(256), 0, stream, mark, M);
  hipLaunchKernelGGL(mark_set,  dim3((S + 255) / 256), dim3(256), 0, stream, mark, submess, S);
  hipLaunchKernelGGL(repack_weights, dim3((GATE_FRAGS + WN_FRAGS + 255) / 256), dim3(256), 0, stream,
                     Wi, Wo, Wu, Wf, Wn, pack);

  // 2. precompute: non-sub passthrough + masked shadows rows [0,M) + Hf
  hipLaunchKernelGGL(precompute, dim3((M + 15) / 16), dim3(256), 0, stream,
                     h_in, c_in, mark, pack, h_out, c_out, H16x, C16x, Hf16x, M);

  // 3. Xg = x @ W*[0:256] + b* (once; reused by both iterations)
  hipLaunchKernelGGL(xg_gemm, dim3(lblocks), dim3(256), 0, stream,
                     fmess, submess, pack, bi, bo, bu, bf_, Xg, S);

  // 4. iter 0: reads rows [0,M), writes shadow rows [M, M+S) — disjoint, race-free
  hipLaunchKernelGGL(lstm_step6<0>, dim3(lblocks), dim3(256), 0, stream,
      submess, bgraph, mark, H16x, C16x, Hf16x, Xg, pack, h_out, c_out, S, M);
  // 5. iter 1: translated neighbor ids; writes final f32 sub rows
  hipLaunchKernelGGL(lstm_step6<1>, dim3(lblocks), dim3(256), 0, stream,
      submess, bgraph, mark, H16x, C16x, Hf16x, Xg, pack, h_out, c_out, S, M);

  // 6. zero node_buf, then node readout
  long nn4 = (long)num_nodes * Hc / 4;
  long zb = (nn4 + 255) / 256; if (zb > 8192) zb = 8192;
  hipLaunchKernelGGL(zero_f4, dim3((int)zb), dim3(256), 0, stream, (float4*)node_buf, nn4);

  const int nblocks = (Nsub + 15) / 16;
  hipLaunchKernelGGL(node_readout_mfma, dim3(nblocks), dim3(256), 0, stream,
      fnode, agraph, subnode, h_out, packWn, bn, node_buf, S);
}

// Round 9
// 353.591 us; speedup vs baseline: 1.7629x; 1.0090x over previous
//
#include <hip/hip_runtime.h>
#include <cstdint>
#include <cstddef>

#define Hc   128
#define INc  256
#define Kc   8
#define HP   136          // hf_rows staging row pad (ushorts)
#define HSP  136          // lstm h_sum staging row pad (ushorts)
#define EPH  136          // lstm gate-partial arrays row pad (ushorts)
#define ZP2  264          // node/x staging row pad (ushorts)

typedef unsigned short ushortT;
typedef __attribute__((ext_vector_type(8))) short bf16x8;
typedef __attribute__((ext_vector_type(4))) float f32x4;
typedef __attribute__((ext_vector_type(4))) unsigned short us4;
typedef __attribute__((ext_vector_type(8))) unsigned short us8;

// fast sigmoid: exp(-x)->inf => rcp->0 ; exp(-x)->0 => 1 (no clamps needed)
__device__ __forceinline__ float fsig(float x) {
  return __builtin_amdgcn_rcpf(1.f + __expf(-x));
}
// fast tanh: upper clamp only (avoid inf/inf); e->0 gives -1 exactly
__device__ __forceinline__ float ftanh(float x) {
  float e = __expf(2.f * fminf(x, 15.f));
  return (e - 1.f) * __builtin_amdgcn_rcpf(e + 1.f);
}
__device__ __forceinline__ ushortT f2bf(float f) {
  unsigned u = __builtin_bit_cast(unsigned, f);
  unsigned r = (u + 0x7fffu + ((u >> 16) & 1u)) >> 16;
  return (ushortT)r;
}
__device__ __forceinline__ us4 f2bf4(float4 v) {
  us4 o; o[0] = f2bf(v.x); o[1] = f2bf(v.y); o[2] = f2bf(v.z); o[3] = f2bf(v.w);
  return o;
}
__device__ __forceinline__ float bf2f(ushortT u) {
  return __builtin_bit_cast(float, (unsigned)u << 16);
}

// ---------------- utility kernels ----------------
__global__ void zero_f4(float4* __restrict__ p, long n4) {
  long i = (long)blockIdx.x * blockDim.x + threadIdx.x;
  long stride = (long)gridDim.x * blockDim.x;
  float4 z; z.x = z.y = z.z = z.w = 0.f;
  for (; i < n4; i += stride) p[i] = z;
}
__global__ void mark_init(int* __restrict__ mark, int M) {
  int i = blockIdx.x * blockDim.x + threadIdx.x;
  if (i < M) mark[i] = -1;
}
__global__ void mark_set(int* __restrict__ mark, const int* __restrict__ submess, int S) {
  int i = blockIdx.x * blockDim.x + threadIdx.x;
  if (i < S) mark[submess[i]] = i;
}

// ---------------- weight repack into B-fragment order (verified R2-R7) ----------
// gates: idx = ((g*8 + c)*12 + kt)*64 + lane ; elem j:
//        W_g[kt*32 + (lane>>4)*8 + j][c*16 + (lane&15)]  (kt 0..11 spans K=384)
#define GATE_FRAGS (4*8*12*64)
#define WN_FRAGS   (8*8*64)
__global__ void repack_weights(const float* __restrict__ Wi, const float* __restrict__ Wo,
                               const float* __restrict__ Wu, const float* __restrict__ Wf,
                               const float* __restrict__ Wn, ushortT* __restrict__ pack) {
  int idx = blockIdx.x * blockDim.x + threadIdx.x;
  if (idx < GATE_FRAGS) {
    int lane = idx & 63;
    int kt = (idx >> 6) % 12;
    int gc = idx / (64 * 12);
    int c = gc & 7, g = gc >> 3;
    const float* W = (g == 0) ? Wi : (g == 1) ? Wo : (g == 2) ? Wu : Wf;
    int k0 = kt * 32 + (lane >> 4) * 8;
    int col = c * 16 + (lane & 15);
    ushortT* dst = pack + (size_t)idx * 8;
    #pragma unroll
    for (int j = 0; j < 8; ++j) dst[j] = f2bf(W[(size_t)(k0 + j) * Hc + col]);
  } else if (idx < GATE_FRAGS + WN_FRAGS) {
    int i2 = idx - GATE_FRAGS;
    int lane = i2 & 63;
    int kt = (i2 >> 6) & 7;
    int c = i2 >> 9;
    int k0 = kt * 32 + (lane >> 4) * 8;
    int col = c * 16 + (lane & 15);
    ushortT* dst = pack + (size_t)GATE_FRAGS * 8 + (size_t)i2 * 8;
    #pragma unroll
    for (int j = 0; j < 8; ++j) dst[j] = f2bf(Wn[(size_t)(k0 + j) * Hc + col]);
  }
}

// W*2 B-fragment (h-part rows 256..383 of gate g => kt slots 8..11)
__device__ __forceinline__ const bf16x8* wh_frag(const ushortT* pack, int g, int cw, int kf, int lane) {
  return (const bf16x8*)&pack[(size_t)(((g * 8 + cw) * 12 + (8 + kf)) * 64 + lane) * 8];
}

// ---------------- stage: pure streaming passthrough + masked bf16 shadows ------
// rows [0,M): h_out/c_out passthrough at non-sub rows; shadows masked (0 at sub).
// Also zeroes the dummy row M+S of all three shadow arrays.
__global__ __launch_bounds__(256) void stage_hc(
    const float* __restrict__ h_in, const float* __restrict__ c_in,
    const int* __restrict__ mark,
    float* __restrict__ h_out, float* __restrict__ c_out,
    ushortT* __restrict__ H16x, ushortT* __restrict__ C16x, ushortT* __restrict__ Hf16x,
    int M, int S)
{
  if (blockIdx.x == 0 && threadIdx.x < 48) {
    int a = threadIdx.x, arr = a >> 4, cp = a & 15;
    ushortT* dst = (arr == 0) ? H16x : (arr == 1) ? C16x : Hf16x;
    us8 z;
    #pragma unroll
    for (int e = 0; e < 8; ++e) z[e] = 0;
    *(us8*)&dst[(size_t)(M + S) * Hc + cp * 8] = z;
  }
  long total = (long)M * 16;
  for (long idx = (long)blockIdx.x * blockDim.x + threadIdx.x; idx < total;
       idx += (long)gridDim.x * blockDim.x) {
    long j = idx >> 4;
    int cp = (int)(idx & 15);
    bool sub = (mark[j] >= 0);
    const float4* h4 = (const float4*)(h_in + (size_t)j * Hc);
    const float4* c4 = (const float4*)(c_in + (size_t)j * Hc);
    float4 a0 = h4[cp * 2], a1 = h4[cp * 2 + 1];
    float4 b0 = c4[cp * 2], b1 = c4[cp * 2 + 1];
    if (!sub) {
      ((float4*)(h_out + (size_t)j * Hc))[cp * 2] = a0;
      ((float4*)(h_out + (size_t)j * Hc))[cp * 2 + 1] = a1;
      ((float4*)(c_out + (size_t)j * Hc))[cp * 2] = b0;
      ((float4*)(c_out + (size_t)j * Hc))[cp * 2 + 1] = b1;
    }
    us4 zz; zz[0] = zz[1] = zz[2] = zz[3] = 0;
    *(us4*)&H16x[(size_t)j * Hc + cp * 8]     = sub ? zz : f2bf4(a0);
    *(us4*)&H16x[(size_t)j * Hc + cp * 8 + 4] = sub ? zz : f2bf4(a1);
    *(us4*)&C16x[(size_t)j * Hc + cp * 8]     = sub ? zz : f2bf4(b0);
    *(us4*)&C16x[(size_t)j * Hc + cp * 8 + 4] = sub ? zz : f2bf4(b1);
  }
}

// ---------------- Hf rows: Hf16x[base+r] = H16x[base+r] @ Wf2 (compact, coalesced)
__global__ __launch_bounds__(256) void hf_rows(
    const ushortT* __restrict__ H16x, const ushortT* __restrict__ pack,
    ushortT* __restrict__ Hf16x, int base, int count)
{
  __shared__ __align__(16) ushortT zh[16 * HP];
  const int t = threadIdx.x;
  const int row0 = blockIdx.x * 16;
  {
    int r = t >> 4, cp = t & 15;
    int rr = row0 + r;
    us8 v;
    #pragma unroll
    for (int e = 0; e < 8; ++e) v[e] = 0;
    if (rr < count) v = *(const us8*)&H16x[(size_t)(base + rr) * Hc + cp * 8];
    *(us8*)&zh[r * HP + cp * 8] = v;
  }
  __syncthreads();

  const int w = t >> 6, lane = t & 63, lg = lane >> 4, cl = lane & 15;
  f32x4 acc0 = (f32x4){0.f,0.f,0.f,0.f}, acc1 = acc0;
  const ushortT* zr = &zh[cl * HP + lg * 8];
  #pragma unroll
  for (int kf = 0; kf < 4; ++kf) {
    bf16x8 a = *(const bf16x8*)&zr[kf * 32];
    acc0 = __builtin_amdgcn_mfma_f32_16x16x32_bf16(a, *wh_frag(pack, 3, w*2+0, kf, lane), acc0, 0, 0, 0);
    acc1 = __builtin_amdgcn_mfma_f32_16x16x32_bf16(a, *wh_frag(pack, 3, w*2+1, kf, lane), acc1, 0, 0, 0);
  }
  #pragma unroll
  for (int half = 0; half < 2; ++half) {
    int col = (w * 2 + half) * 16 + cl;
    f32x4 a_ = half ? acc1 : acc0;
    #pragma unroll
    for (int reg = 0; reg < 4; ++reg) {
      int rr = row0 + lg * 4 + reg;
      if (rr < count) Hf16x[(size_t)(base + rr) * Hc + col] = f2bf(a_[reg]);
    }
  }
}

// ---------------- Xg = x @ W*[0:256] + b*  (iteration-invariant gate x-parts) ----
__global__ __launch_bounds__(256) void xg_gemm(
    const float* __restrict__ fmess, const int* __restrict__ submess,
    const ushortT* __restrict__ pack,
    const float* __restrict__ bi, const float* __restrict__ bo,
    const float* __restrict__ bu, const float* __restrict__ bfb,
    ushortT* __restrict__ Xg, int S)
{
  __shared__ __align__(16) ushortT xs[16 * ZP2];
  __shared__ int msr[16];
  const int t = threadIdx.x;
  const int row0 = blockIdx.x * 16;

  if (t < 16) msr[t] = (row0 + t < S) ? submess[row0 + t] : -1;
  __syncthreads();
  {
    int r = t >> 4, cp = t & 15;
    int ms = msr[r];
    const float4* xr = (ms >= 0) ? (const float4*)(fmess + (size_t)ms * INc) : nullptr;
    #pragma unroll
    for (int q = 0; q < 4; ++q) {
      int slot = cp + q * 16;
      float4 v;
      if (xr) v = xr[slot]; else { v.x = v.y = v.z = v.w = 0.f; }
      *(us4*)&xs[r * ZP2 + slot * 4] = f2bf4(v);
    }
  }
  __syncthreads();

  const int w = t >> 6, lane = t & 63, lg = lane >> 4, cl = lane & 15;
  f32x4 acc[8];
  #pragma unroll
  for (int i = 0; i < 8; ++i) acc[i] = (f32x4){0.f, 0.f, 0.f, 0.f};
  const ushortT* zr = &xs[cl * ZP2 + lg * 8];
  #pragma unroll
  for (int kt = 0; kt < 8; ++kt) {
    bf16x8 a = *(const bf16x8*)&zr[kt * 32];
    #pragma unroll
    for (int c = 0; c < 8; ++c) {
      bf16x8 b = *(const bf16x8*)&pack[(size_t)(((w * 8 + c) * 12 + kt) * 64 + lane) * 8];
      acc[c] = __builtin_amdgcn_mfma_f32_16x16x32_bf16(a, b, acc[c], 0, 0, 0);
    }
  }
  const float* bias = (w == 0) ? bi : (w == 1) ? bo : (w == 2) ? bu : bfb;
  #pragma unroll
  for (int c = 0; c < 8; ++c) {
    int col = c * 16 + cl;
    float bv = bias[col];
    #pragma unroll
    for (int reg = 0; reg < 4; ++reg) {
      int s = row0 + lg * 4 + reg;
      if (s < S) Xg[(size_t)s * 512 + w * 128 + col] = f2bf(acc[c][reg] + bv);
    }
  }
}

// ---- LSTM step over extended shadows, with non-sub partial reuse ----
// MODE 0: neighbors = raw ids into masked rows [0,M). Saves hsumNS (bf16) and
//         cpartNS (bf16, pure non-sub forget partial); writes h/c shadows M+spos.
// MODE 1: neighbors redirected: sub j -> M+mark[j], non-sub j -> DUMMY (zero row).
//         Adds saved partials; writes final f32 h_out/c_out.
template<int MODE>
__global__ __launch_bounds__(256) void lstm_step7(
    const int* __restrict__ submess, const int* __restrict__ bgraph,
    const int* __restrict__ mark,
    ushortT* H16x, ushortT* C16x, const ushortT* __restrict__ Hf16x,
    const ushortT* __restrict__ Xg, const ushortT* __restrict__ pack,
    ushortT* hsumNS, ushortT* cpartNS,
    float* __restrict__ dstH, float* __restrict__ dstC, int S, int M)
{
  __shared__ __align__(16) ushortT zs[16 * HSP];
  __shared__ __align__(16) ushortT pih[16 * EPH];
  __shared__ __align__(16) ushortT poh[16 * EPH];
  __shared__ __align__(16) ushortT puh[16 * EPH];
  __shared__ int nbj[16][Kc];
  __shared__ int msrow[16];

  const int t = threadIdx.x;
  const int row0 = blockIdx.x * 16;
  const int DUMMY = M + S;

  if (t < 128) {
    int r = t >> 3, k = t & 7;
    int s = row0 + r;
    int ms = (s < S) ? submess[s] : -1;
    if (k == 0) msrow[r] = ms;
    int j = DUMMY;
    if (ms >= 0) {
      int jj = bgraph[(size_t)ms * Kc + k];
      if (MODE == 0) j = jj;
      else { int m = mark[jj]; if (m >= 0) j = M + m; }
    }
    nbj[r][k] = j;
  }
  __syncthreads();

  // ---- h_sum gather -> zs  (MODE 1: seeded with saved non-sub partial) ----
  {
    int r = t >> 4, cp = t & 15;
    float sum[8] = {0.f,0.f,0.f,0.f,0.f,0.f,0.f,0.f};
    if (MODE == 1) {
      int spos = row0 + r;
      if (spos < S) {
        us8 hs = *(const us8*)&hsumNS[(size_t)spos * Hc + cp * 8];
        #pragma unroll
        for (int e = 0; e < 8; ++e) sum[e] = bf2f(hs[e]);
      }
    }
    #pragma unroll
    for (int k = 0; k < Kc; ++k) {
      int j = nbj[r][k];
      us8 v = *(const us8*)&H16x[(size_t)j * Hc + cp * 8];
      #pragma unroll
      for (int e = 0; e < 8; ++e) sum[e] += bf2f(v[e]);
    }
    us4 o0, o1;
    #pragma unroll
    for (int e = 0; e < 4; ++e) { o0[e] = f2bf(sum[e]); o1[e] = f2bf(sum[4 + e]); }
    *(us4*)&zs[r * HSP + cp * 8] = o0;
    *(us4*)&zs[r * HSP + cp * 8 + 4] = o1;
  }
  __syncthreads();

  const int w = t >> 6, lane = t & 63, lg = lane >> 4, cl = lane & 15;

  // ---- gate h-part K-loop: 24 MFMAs/wave ----
  f32x4 acc[6];
  #pragma unroll
  for (int i = 0; i < 6; ++i) acc[i] = (f32x4){0.f, 0.f, 0.f, 0.f};
  const ushortT* zrow = &zs[cl * HSP + lg * 8];
  #pragma unroll
  for (int kf = 0; kf < 4; ++kf) {
    bf16x8 a = *(const bf16x8*)&zrow[kf * 32];
    #pragma unroll
    for (int g = 0; g < 3; ++g)
      #pragma unroll
      for (int half = 0; half < 2; ++half)
        acc[g * 2 + half] = __builtin_amdgcn_mfma_f32_16x16x32_bf16(
            a, *wh_frag(pack, g, w * 2 + half, kf, lane), acc[g * 2 + half], 0, 0, 0);
  }

  // ---- write partials (disjoint LDS arrays; zs untouched) ----
  #pragma unroll
  for (int half = 0; half < 2; ++half) {
    int col = (w * 2 + half) * 16 + cl;
    #pragma unroll
    for (int reg = 0; reg < 4; ++reg) {
      int row = lg * 4 + reg;
      pih[row * EPH + col] = f2bf(acc[0 + half][reg]);
      poh[row * EPH + col] = f2bf(acc[2 + half][reg]);
      puh[row * EPH + col] = f2bf(acc[4 + half][reg]);
    }
  }
  __syncthreads();

  // ---- epilogue: (row, 8-col chunk) ----
  {
    int r = t >> 4, cc = t & 15;
    int ms = msrow[r];
    int spos = row0 + r;
    const ushortT* xgr = Xg + (size_t)spos * 512 + cc * 8;
    us8 xi8 = *(const us8*)&xgr[0];
    us8 xo8 = *(const us8*)&xgr[128];
    us8 xu8 = *(const us8*)&xgr[256];
    us8 xf8 = *(const us8*)&xgr[384];
    us8 pi8 = *(const us8*)&pih[r * EPH + cc * 8];
    us8 po8 = *(const us8*)&poh[r * EPH + cc * 8];
    us8 pu8 = *(const us8*)&puh[r * EPH + cc * 8];
    float fx[8], ovv[8], iu[8], cn[8];
    #pragma unroll
    for (int e = 0; e < 8; ++e) {
      float iv = fsig(bf2f(xi8[e]) + bf2f(pi8[e]));
      float uv = ftanh(bf2f(xu8[e]) + bf2f(pu8[e]));
      ovv[e] = fsig(bf2f(xo8[e]) + bf2f(po8[e]));
      fx[e] = bf2f(xf8[e]);
      iu[e] = iv * uv;
      cn[e] = 0.f;
    }
    #pragma unroll
    for (int k = 0; k < Kc; ++k) {
      int j = nbj[r][k];
      us8 hf8 = *(const us8*)&Hf16x[(size_t)j * Hc + cc * 8];
      us8 cn8 = *(const us8*)&C16x[(size_t)j * Hc + cc * 8];
      #pragma unroll
      for (int e = 0; e < 8; ++e)
        cn[e] = fmaf(fsig(fx[e] + bf2f(hf8[e])), bf2f(cn8[e]), cn[e]);
    }
    float cacc[8];
    if (MODE == 1 && spos < S) {
      us8 cp8 = *(const us8*)&cpartNS[(size_t)spos * Hc + cc * 8];
      #pragma unroll
      for (int e = 0; e < 8; ++e) cacc[e] = iu[e] + cn[e] + bf2f(cp8[e]);
    } else {
      #pragma unroll
      for (int e = 0; e < 8; ++e) cacc[e] = iu[e] + cn[e];
    }
    float hv[8];
    #pragma unroll
    for (int e = 0; e < 8; ++e) hv[e] = ovv[e] * ftanh(cacc[e]);

    if (MODE == 0) {
      if (spos < S) {
        us8 h8, c8, cn16;
        #pragma unroll
        for (int e = 0; e < 8; ++e) {
          h8[e] = f2bf(hv[e]); c8[e] = f2bf(cacc[e]); cn16[e] = f2bf(cn[e]);
        }
        *(us8*)&H16x[(size_t)(M + spos) * Hc + cc * 8] = h8;
        *(us8*)&C16x[(size_t)(M + spos) * Hc + cc * 8] = c8;
        *(us8*)&hsumNS[(size_t)spos * Hc + cc * 8] = *(const us8*)&zs[r * HSP + cc * 8];
        *(us8*)&cpartNS[(size_t)spos * Hc + cc * 8] = cn16;
      }
    } else {
      if (ms >= 0) {
        float* dh = dstH + (size_t)ms * Hc + cc * 8;
        float* dc = dstC + (size_t)ms * Hc + cc * 8;
        *(float4*)&dh[0] = *(float4*)&hv[0];
        *(float4*)&dh[4] = *(float4*)&hv[4];
        *(float4*)&dc[0] = *(float4*)&cacc[0];
        *(float4*)&dc[4] = *(float4*)&cacc[4];
      }
    }
  }
}

// ---------------- node readout (MFMA, unchanged) ----------------
__global__ __launch_bounds__(256) void node_readout_mfma(
    const float* __restrict__ fnode, const int* __restrict__ agraph,
    const int* __restrict__ subnode, const float* __restrict__ hfull,
    const ushortT* __restrict__ packWn, const float* __restrict__ bn,
    float* __restrict__ node_buf, int Nsub)
{
  __shared__ __align__(16) ushortT z2[16 * ZP2];
  __shared__ int orow[16];
  __shared__ const float* aptr[16][Kc];

  const int t = threadIdx.x;
  const int row0 = blockIdx.x * 16;

  if (t < 16) orow[t] = (row0 + t < Nsub) ? subnode[row0 + t] : -1;
  if (t >= 64 && t < 64 + 128) {
    int i = t - 64, r = i >> 3, k = i & 7;
    int v = row0 + r;
    aptr[r][k] = (v < Nsub) ? hfull + (size_t)agraph[(size_t)v * Kc + k] * Hc : nullptr;
  }
  {
    int r = t >> 4, cp = t & 15;
    int v = row0 + r;
    const float4* fr = (v < Nsub) ? (const float4*)(fnode + (size_t)v * Hc) : nullptr;
    float4 v0, v1; v0.x = v0.y = v0.z = v0.w = 0.f; v1 = v0;
    if (fr) { v0 = fr[cp]; v1 = fr[cp + 16]; }
    *(us4*)&z2[r * ZP2 + cp * 4] = f2bf4(v0);
    *(us4*)&z2[r * ZP2 + 64 + cp * 4] = f2bf4(v1);
  }
  __syncthreads();
  {
    int r = t >> 4, cp = t & 15;
    float4 s0, s1; s0.x = s0.y = s0.z = s0.w = 0.f; s1 = s0;
    #pragma unroll
    for (int k = 0; k < Kc; ++k) {
      const float* p = aptr[r][k];
      if (p) {
        float4 v0 = ((const float4*)p)[cp], v1 = ((const float4*)p)[cp + 16];
        s0.x += v0.x; s0.y += v0.y; s0.z += v0.z; s0.w += v0.w;
        s1.x += v1.x; s1.y += v1.y; s1.z += v1.z; s1.w += v1.w;
      }
    }
    *(us4*)&z2[r * ZP2 + Hc + cp * 4] = f2bf4(s0);
    *(us4*)&z2[r * ZP2 + Hc + 64 + cp * 4] = f2bf4(s1);
  }
  __syncthreads();

  const int w = t >> 6, lane = t & 63;
  const int lg = lane >> 4, cl = lane & 15;

  f32x4 acc0 = (f32x4){0.f,0.f,0.f,0.f};
  f32x4 acc1 = (f32x4){0.f,0.f,0.f,0.f};
  const ushortT* zr = &z2[cl * ZP2 + lg * 8];
  #pragma unroll
  for (int kt = 0; kt < 8; ++kt) {
    bf16x8 a = *(const bf16x8*)&zr[kt * 32];
    bf16x8 b0 = *(const bf16x8*)&packWn[(size_t)(((w * 2 + 0) * 8 + kt) * 64 + lane) * 8];
    bf16x8 b1 = *(const bf16x8*)&packWn[(size_t)(((w * 2 + 1) * 8 + kt) * 64 + lane) * 8];
    acc0 = __builtin_amdgcn_mfma_f32_16x16x32_bf16(a, b0, acc0, 0, 0, 0);
    acc1 = __builtin_amdgcn_mfma_f32_16x16x32_bf16(a, b1, acc1, 0, 0, 0);
  }
  #pragma unroll
  for (int half = 0; half < 2; ++half) {
    int col = (w * 2 + half) * 16 + cl;
    float bnv = bn[col];
    f32x4 a_ = half ? acc1 : acc0;
    #pragma unroll
    for (int reg = 0; reg < 4; ++reg) {
      int row = lg * 4 + reg;
      int o = orow[row];
      if (o >= 0) node_buf[(size_t)o * Hc + col] = fmaxf(a_[reg] + bnv, 0.f);
    }
  }
}

// ---------------- launch ----------------
extern "C" void kernel_launch(void* const* d_in, const int* in_sizes, int n_in,
                              void* d_out, int out_size, void* d_ws, size_t ws_size,
                              hipStream_t stream) {
  const float* fnode   = (const float*)d_in[0];
  const float* fmess   = (const float*)d_in[1];
  const int*   agraph  = (const int*)d_in[2];
  const int*   bgraph  = (const int*)d_in[3];
  const float* h_in    = (const float*)d_in[4];
  const float* c_in    = (const float*)d_in[5];
  const int*   submess = (const int*)d_in[6];
  const int*   subnode = (const int*)d_in[7];
  const float* Wi = (const float*)d_in[9];
  const float* bi = (const float*)d_in[10];
  const float* Wo = (const float*)d_in[11];
  const float* bo = (const float*)d_in[12];
  const float* Wf = (const float*)d_in[13];
  const float* bf_ = (const float*)d_in[14];
  const float* Wu = (const float*)d_in[15];
  const float* bu = (const float*)d_in[16];
  const float* Wn = (const float*)d_in[17];
  const float* bn = (const float*)d_in[18];

  const int S    = in_sizes[6];
  const int Nsub = in_sizes[2] / Kc;
  const int M    = in_sizes[4] / Hc;
  const int num_nodes = out_size / Hc - 2 * M;

  float* node_buf = (float*)d_out;
  float* h_out = node_buf + (size_t)num_nodes * Hc;
  float* c_out = h_out + (size_t)M * Hc;

  const int lblocks = (S + 15) / 16;

  // ws layout: mark[M] | pack | Hf16x | C16x | H16x  (each (M+S+1) rows bf16) | Xg
  // partials (hsumNS, cpartNS: S rows bf16 each) live in node_buf region
  // (free until zero_f4 after iter1).
  int* mark = (int*)d_ws;
  size_t off = (((size_t)M * sizeof(int)) + 255) & ~(size_t)255;
  ushortT* pack = (ushortT*)((char*)d_ws + off);
  off += (((size_t)(GATE_FRAGS + WN_FRAGS) * 8 * sizeof(ushortT)) + 255) & ~(size_t)255;
  size_t shadow_bytes = (((size_t)(M + S + 1) * Hc * sizeof(ushortT)) + 255) & ~(size_t)255;
  ushortT* Hf16x = (ushortT*)((char*)d_ws + off); off += shadow_bytes;
  ushortT* C16x  = (ushortT*)((char*)d_ws + off); off += shadow_bytes;
  ushortT* H16x  = (ushortT*)((char*)d_ws + off); off += shadow_bytes;
  ushortT* Xg    = (ushortT*)((char*)d_ws + off);
  ushortT* packWn = pack + (size_t)GATE_FRAGS * 8;
  ushortT* cpartNS = (ushortT*)node_buf;            // S*128 bf16
  ushortT* hsumNS  = cpartNS + (size_t)S * Hc;

  // 1. mark + weight repack
  hipLaunchKernelGGL(mark_init, dim3((M + 255) / 256), dim3(256), 0, stream, mark, M);
  hipLaunchKernelGGL(mark_set,  dim3((S + 255) / 256), dim3(256), 0, stream, mark, submess, S);
  hipLaunchKernelGGL(repack_weights, dim3((GATE_FRAGS + WN_FRAGS + 255) / 256), dim3(256), 0, stream,
                     Wi, Wo, Wu, Wf, Wn, pack);

  // 2. streaming stage (passthrough + masked shadows + dummy-row zero)
  {
    long units = (long)M * 16;
    long gb = (units + 255) / 256; if (gb > 2048) gb = 2048;
    hipLaunchKernelGGL(stage_hc, dim3((int)gb), dim3(256), 0, stream,
                       h_in, c_in, mark, h_out, c_out, H16x, C16x, Hf16x, M, S);
  }
  // 3. Hf over rows [0,M)
  hipLaunchKernelGGL(hf_rows, dim3((M + 15) / 16), dim3(256), 0, stream,
                     H16x, pack, Hf16x, 0, M);
  // 4. Xg (independent)
  hipLaunchKernelGGL(xg_gemm, dim3(lblocks), dim3(256), 0, stream,
                     fmess, submess, pack, bi, bo, bu, bf_, Xg, S);

  // 5. iter 0: writes shadows M+spos and non-sub partials
  hipLaunchKernelGGL(lstm_step7<0>, dim3(lblocks), dim3(256), 0, stream,
      submess, bgraph, mark, H16x, C16x, Hf16x, Xg, pack,
      hsumNS, cpartNS, h_out, c_out, S, M);
  // 6. Hf over new sub rows [M, M+S)
  hipLaunchKernelGGL(hf_rows, dim3(lblocks), dim3(256), 0, stream,
                     H16x, pack, Hf16x, M, S);
  // 7. iter 1: sub-only gathers + partial reuse; final f32 writes
  hipLaunchKernelGGL(lstm_step7<1>, dim3(lblocks), dim3(256), 0, stream,
      submess, bgraph, mark, H16x, C16x, Hf16x, Xg, pack,
      hsumNS, cpartNS, h_out, c_out, S, M);

  // 8. zero node_buf (erases partials), then node readout
  long nn4 = (long)num_nodes * Hc / 4;
  long zb = (nn4 + 255) / 256; if (zb > 8192) zb = 8192;
  hipLaunchKernelGGL(zero_f4, dim3((int)zb), dim3(256), 0, stream, (float4*)node_buf, nn4);

  const int nblocks = (Nsub + 15) / 16;
  hipLaunchKernelGGL(node_readout_mfma, dim3(nblocks), dim3(256), 0, stream,
      fnode, agraph, subnode, h_out, packWn, bn, node_buf, S);
}

// Round 10
// 288.825 us; speedup vs baseline: 2.1582x; 1.2242x over previous
//
#include <hip/hip_runtime.h>
#include <cstdint>
#include <cstddef>

#define Hc   128
#define INc  256
#define Kc   8
#define HP   136          // hf_rows staging row pad (ushorts)
#define HSP  136          // lstm h_sum/h_new staging row pad (ushorts)
#define EPH  136          // lstm gate-partial arrays row pad (ushorts)
#define ZP2  264          // node/x staging row pad (ushorts)

typedef unsigned short ushortT;
typedef __attribute__((ext_vector_type(8))) short bf16x8;
typedef __attribute__((ext_vector_type(4))) float f32x4;
typedef __attribute__((ext_vector_type(4))) unsigned short us4;
typedef __attribute__((ext_vector_type(8))) unsigned short us8;

__device__ __forceinline__ float fsig(float x) {
  return __builtin_amdgcn_rcpf(1.f + __expf(-x));
}
__device__ __forceinline__ float ftanh(float x) {
  float e = __expf(2.f * fminf(x, 15.f));
  return (e - 1.f) * __builtin_amdgcn_rcpf(e + 1.f);
}
__device__ __forceinline__ ushortT f2bf(float f) {
  unsigned u = __builtin_bit_cast(unsigned, f);
  unsigned r = (u + 0x7fffu + ((u >> 16) & 1u)) >> 16;
  return (ushortT)r;
}
__device__ __forceinline__ us4 f2bf4(float4 v) {
  us4 o; o[0] = f2bf(v.x); o[1] = f2bf(v.y); o[2] = f2bf(v.z); o[3] = f2bf(v.w);
  return o;
}
__device__ __forceinline__ float bf2f(ushortT u) {
  return __builtin_bit_cast(float, (unsigned)u << 16);
}

#define GATE_FRAGS (4*8*12*64)
#define WN_FRAGS   (8*8*64)

// ---------------- kernel 1: init marks ----------------
__global__ void marks_init(int* __restrict__ mark, int M, int* __restrict__ nmark, int NN) {
  int i = blockIdx.x * blockDim.x + threadIdx.x;
  if (i < M) mark[i] = -1;
  if (i < NN) nmark[i] = -1;
}

// ---------------- kernel 2: set marks || repack weights ----------------
__global__ void set_repack(const int* __restrict__ submess, const int* __restrict__ subnode,
                           int S, int* __restrict__ mark, int* __restrict__ nmark,
                           const float* __restrict__ Wi, const float* __restrict__ Wo,
                           const float* __restrict__ Wu, const float* __restrict__ Wf,
                           const float* __restrict__ Wn, ushortT* __restrict__ pack, int SB) {
  if ((int)blockIdx.x < SB) {
    int i = blockIdx.x * 256 + threadIdx.x;
    if (i < S) { mark[submess[i]] = i; nmark[subnode[i]] = i; }
    return;
  }
  int idx = (blockIdx.x - SB) * 256 + threadIdx.x;
  if (idx < GATE_FRAGS) {
    int lane = idx & 63;
    int kt = (idx >> 6) % 12;
    int gc = idx / (64 * 12);
    int c = gc & 7, g = gc >> 3;
    const float* W = (g == 0) ? Wi : (g == 1) ? Wo : (g == 2) ? Wu : Wf;
    int k0 = kt * 32 + (lane >> 4) * 8;
    int col = c * 16 + (lane & 15);
    ushortT* dst = pack + (size_t)idx * 8;
    #pragma unroll
    for (int j = 0; j < 8; ++j) dst[j] = f2bf(W[(size_t)(k0 + j) * Hc + col]);
  } else if (idx < GATE_FRAGS + WN_FRAGS) {
    int i2 = idx - GATE_FRAGS;
    int lane = i2 & 63;
    int kt = (i2 >> 6) & 7;
    int c = i2 >> 9;
    int k0 = kt * 32 + (lane >> 4) * 8;
    int col = c * 16 + (lane & 15);
    ushortT* dst = pack + (size_t)GATE_FRAGS * 8 + (size_t)i2 * 8;
    #pragma unroll
    for (int j = 0; j < 8; ++j) dst[j] = f2bf(Wn[(size_t)(k0 + j) * Hc + col]);
  }
}

// W*2 B-fragment (h-part rows 256..383 of gate g => kt slots 8..11)
__device__ __forceinline__ const bf16x8* wh_frag(const ushortT* pack, int g, int cw, int kf, int lane) {
  return (const bf16x8*)&pack[(size_t)(((g * 8 + cw) * 12 + (8 + kf)) * 64 + lane) * 8];
}

// ---------------- kernel 3: stage (non-sub only) || xg_gemm ----------------
__global__ __launch_bounds__(256) void stage_xg(
    const float* __restrict__ h_in, const float* __restrict__ c_in,
    const int* __restrict__ mark,
    float* __restrict__ h_out, float* __restrict__ c_out,
    ushortT* __restrict__ H16x, ushortT* __restrict__ C16x, ushortT* __restrict__ Hf16x,
    const float* __restrict__ fmess, const int* __restrict__ submess,
    const ushortT* __restrict__ pack,
    const float* __restrict__ bi, const float* __restrict__ bo,
    const float* __restrict__ bu, const float* __restrict__ bfb,
    ushortT* __restrict__ Xg, int M, int S, int stageBlocks)
{
  __shared__ __align__(16) ushortT xs[16 * ZP2];
  __shared__ int msr[16];
  const int t = threadIdx.x;

  if ((int)blockIdx.x < stageBlocks) {
    // --- stage part: non-sub rows only; also zero DUMMY row (M+S) ---
    if (blockIdx.x == 0 && t < 48) {
      int arr = t >> 4, cp = t & 15;
      ushortT* dst = (arr == 0) ? H16x : (arr == 1) ? C16x : Hf16x;
      us8 z;
      #pragma unroll
      for (int e = 0; e < 8; ++e) z[e] = 0;
      *(us8*)&dst[(size_t)(M + S) * Hc + cp * 8] = z;
    }
    long total = (long)M * 16;
    for (long idx = (long)blockIdx.x * 256 + t; idx < total; idx += (long)stageBlocks * 256) {
      long j = idx >> 4;
      int cp = (int)(idx & 15);
      if (mark[j] >= 0) continue;      // sub rows: never read downstream
      const float4* h4 = (const float4*)(h_in + (size_t)j * Hc);
      const float4* c4 = (const float4*)(c_in + (size_t)j * Hc);
      float4 a0 = h4[cp * 2], a1 = h4[cp * 2 + 1];
      float4 b0 = c4[cp * 2], b1 = c4[cp * 2 + 1];
      ((float4*)(h_out + (size_t)j * Hc))[cp * 2] = a0;
      ((float4*)(h_out + (size_t)j * Hc))[cp * 2 + 1] = a1;
      ((float4*)(c_out + (size_t)j * Hc))[cp * 2] = b0;
      ((float4*)(c_out + (size_t)j * Hc))[cp * 2 + 1] = b1;
      *(us4*)&H16x[(size_t)j * Hc + cp * 8]     = f2bf4(a0);
      *(us4*)&H16x[(size_t)j * Hc + cp * 8 + 4] = f2bf4(a1);
      *(us4*)&C16x[(size_t)j * Hc + cp * 8]     = f2bf4(b0);
      *(us4*)&C16x[(size_t)j * Hc + cp * 8 + 4] = f2bf4(b1);
    }
    return;
  }

  // --- xg part ---
  const int row0 = (blockIdx.x - stageBlocks) * 16;
  if (t < 16) msr[t] = (row0 + t < S) ? submess[row0 + t] : -1;
  __syncthreads();
  {
    int r = t >> 4, cp = t & 15;
    int ms = msr[r];
    const float4* xr = (ms >= 0) ? (const float4*)(fmess + (size_t)ms * INc) : nullptr;
    #pragma unroll
    for (int q = 0; q < 4; ++q) {
      int slot = cp + q * 16;
      float4 v;
      if (xr) v = xr[slot]; else { v.x = v.y = v.z = v.w = 0.f; }
      *(us4*)&xs[r * ZP2 + slot * 4] = f2bf4(v);
    }
  }
  __syncthreads();

  const int w = t >> 6, lane = t & 63, lg = lane >> 4, cl = lane & 15;
  f32x4 acc[8];
  #pragma unroll
  for (int i = 0; i < 8; ++i) acc[i] = (f32x4){0.f, 0.f, 0.f, 0.f};
  const ushortT* zr = &xs[cl * ZP2 + lg * 8];
  #pragma unroll
  for (int kt = 0; kt < 8; ++kt) {
    bf16x8 a = *(const bf16x8*)&zr[kt * 32];
    #pragma unroll
    for (int c = 0; c < 8; ++c) {
      bf16x8 b = *(const bf16x8*)&pack[(size_t)(((w * 8 + c) * 12 + kt) * 64 + lane) * 8];
      acc[c] = __builtin_amdgcn_mfma_f32_16x16x32_bf16(a, b, acc[c], 0, 0, 0);
    }
  }
  const float* bias = (w == 0) ? bi : (w == 1) ? bo : (w == 2) ? bu : bfb;
  #pragma unroll
  for (int c = 0; c < 8; ++c) {
    int col = c * 16 + cl;
    float bv = bias[col];
    #pragma unroll
    for (int reg = 0; reg < 4; ++reg) {
      int s = row0 + lg * 4 + reg;
      if (s < S) Xg[(size_t)s * 512 + w * 128 + col] = f2bf(acc[c][reg] + bv);
    }
  }
}

// ---------------- kernel 4: Hf over non-sub rows [0,M) ----------------
__global__ __launch_bounds__(256) void hf_rows0(
    const ushortT* __restrict__ H16x, const int* __restrict__ mark,
    const ushortT* __restrict__ pack, ushortT* __restrict__ Hf16x, int M)
{
  __shared__ __align__(16) ushortT zh[16 * HP];
  __shared__ int mk[16];
  const int t = threadIdx.x;
  const int row0 = blockIdx.x * 16;

  if (t < 16) mk[t] = (row0 + t < M) ? mark[row0 + t] : 0;   // >=0 => skip
  __syncthreads();
  {
    int r = t >> 4, cp = t & 15;
    us8 v;
    #pragma unroll
    for (int e = 0; e < 8; ++e) v[e] = 0;
    if (mk[r] < 0) v = *(const us8*)&H16x[(size_t)(row0 + r) * Hc + cp * 8];
    *(us8*)&zh[r * HP + cp * 8] = v;
  }
  __syncthreads();

  const int w = t >> 6, lane = t & 63, lg = lane >> 4, cl = lane & 15;
  f32x4 acc0 = (f32x4){0.f,0.f,0.f,0.f}, acc1 = acc0;
  const ushortT* zr = &zh[cl * HP + lg * 8];
  #pragma unroll
  for (int kf = 0; kf < 4; ++kf) {
    bf16x8 a = *(const bf16x8*)&zr[kf * 32];
    acc0 = __builtin_amdgcn_mfma_f32_16x16x32_bf16(a, *wh_frag(pack, 3, w*2+0, kf, lane), acc0, 0, 0, 0);
    acc1 = __builtin_amdgcn_mfma_f32_16x16x32_bf16(a, *wh_frag(pack, 3, w*2+1, kf, lane), acc1, 0, 0, 0);
  }
  #pragma unroll
  for (int half = 0; half < 2; ++half) {
    int col = (w * 2 + half) * 16 + cl;
    f32x4 a_ = half ? acc1 : acc0;
    #pragma unroll
    for (int reg = 0; reg < 4; ++reg) {
      int row = lg * 4 + reg;
      if (mk[row] < 0) Hf16x[(size_t)(row0 + row) * Hc + col] = f2bf(a_[reg]);
    }
  }
}

// ---- kernels 5/6: LSTM step with redirect + partial reuse ----
// MODE 0: sub neighbors -> DUMMY (zero rows). Writes h/c shadows M+spos,
//         hsumNS (at gather phase), cpartNS; fused Hf tail -> Hf16x[M+spos].
// MODE 1: sub -> M+mark, non-sub -> DUMMY; seeds with saved partials;
//         writes final f32 h_out/c_out.
template<int MODE>
__global__ __launch_bounds__(256) void lstm8(
    const int* __restrict__ submess, const int* __restrict__ bgraph,
    const int* __restrict__ mark,
    ushortT* H16x, ushortT* C16x, ushortT* Hf16x,
    const ushortT* __restrict__ Xg, const ushortT* __restrict__ pack,
    ushortT* hsumNS, ushortT* cpartNS,
    float* __restrict__ dstH, float* __restrict__ dstC, int S, int M)
{
  __shared__ __align__(16) ushortT zs[16 * HSP];    // h_sum; reused for h_new (MODE 0)
  __shared__ __align__(16) ushortT pih[16 * EPH];
  __shared__ __align__(16) ushortT poh[16 * EPH];
  __shared__ __align__(16) ushortT puh[16 * EPH];
  __shared__ int nbj[16][Kc];
  __shared__ int msrow[16];

  const int t = threadIdx.x;
  const int row0 = blockIdx.x * 16;
  const int DUMMY = M + S;

  if (t < 128) {
    int r = t >> 3, k = t & 7;
    int s = row0 + r;
    int ms = (s < S) ? submess[s] : -1;
    if (k == 0) msrow[r] = ms;
    int j = DUMMY;
    if (ms >= 0) {
      int jj = bgraph[(size_t)ms * Kc + k];
      int m = mark[jj];
      j = (MODE == 0) ? (m >= 0 ? DUMMY : jj) : (m >= 0 ? M + m : DUMMY);
    }
    nbj[r][k] = j;
  }
  __syncthreads();

  // ---- h_sum gather -> zs (MODE 1 seeded; MODE 0 saves hsumNS here) ----
  {
    int r = t >> 4, cp = t & 15;
    int spos = row0 + r;
    float sum[8] = {0.f,0.f,0.f,0.f,0.f,0.f,0.f,0.f};
    if (MODE == 1 && spos < S) {
      us8 hs = *(const us8*)&hsumNS[(size_t)spos * Hc + cp * 8];
      #pragma unroll
      for (int e = 0; e < 8; ++e) sum[e] = bf2f(hs[e]);
    }
    #pragma unroll
    for (int k = 0; k < Kc; ++k) {
      int j = nbj[r][k];
      us8 v = *(const us8*)&H16x[(size_t)j * Hc + cp * 8];
      #pragma unroll
      for (int e = 0; e < 8; ++e) sum[e] += bf2f(v[e]);
    }
    us4 o0, o1;
    #pragma unroll
    for (int e = 0; e < 4; ++e) { o0[e] = f2bf(sum[e]); o1[e] = f2bf(sum[4 + e]); }
    *(us4*)&zs[r * HSP + cp * 8] = o0;
    *(us4*)&zs[r * HSP + cp * 8 + 4] = o1;
    if (MODE == 0 && spos < S) {
      *(us4*)&hsumNS[(size_t)spos * Hc + cp * 8] = o0;
      *(us4*)&hsumNS[(size_t)spos * Hc + cp * 8 + 4] = o1;
    }
  }
  __syncthreads();

  const int w = t >> 6, lane = t & 63, lg = lane >> 4, cl = lane & 15;

  // ---- gate h-part K-loop: 24 MFMAs/wave ----
  f32x4 acc[6];
  #pragma unroll
  for (int i = 0; i < 6; ++i) acc[i] = (f32x4){0.f, 0.f, 0.f, 0.f};
  const ushortT* zrow = &zs[cl * HSP + lg * 8];
  #pragma unroll
  for (int kf = 0; kf < 4; ++kf) {
    bf16x8 a = *(const bf16x8*)&zrow[kf * 32];
    #pragma unroll
    for (int g = 0; g < 3; ++g)
      #pragma unroll
      for (int half = 0; half < 2; ++half)
        acc[g * 2 + half] = __builtin_amdgcn_mfma_f32_16x16x32_bf16(
            a, *wh_frag(pack, g, w * 2 + half, kf, lane), acc[g * 2 + half], 0, 0, 0);
  }

  #pragma unroll
  for (int half = 0; half < 2; ++half) {
    int col = (w * 2 + half) * 16 + cl;
    #pragma unroll
    for (int reg = 0; reg < 4; ++reg) {
      int row = lg * 4 + reg;
      pih[row * EPH + col] = f2bf(acc[0 + half][reg]);
      poh[row * EPH + col] = f2bf(acc[2 + half][reg]);
      puh[row * EPH + col] = f2bf(acc[4 + half][reg]);
    }
  }
  __syncthreads();

  // ---- epilogue: (row, 8-col chunk) ----
  {
    int r = t >> 4, cc = t & 15;
    int ms = msrow[r];
    int spos = row0 + r;
    const ushortT* xgr = Xg + (size_t)spos * 512 + cc * 8;
    us8 xi8 = *(const us8*)&xgr[0];
    us8 xo8 = *(const us8*)&xgr[128];
    us8 xu8 = *(const us8*)&xgr[256];
    us8 xf8 = *(const us8*)&xgr[384];
    us8 pi8 = *(const us8*)&pih[r * EPH + cc * 8];
    us8 po8 = *(const us8*)&poh[r * EPH + cc * 8];
    us8 pu8 = *(const us8*)&puh[r * EPH + cc * 8];
    float fx[8], ovv[8], iu[8], cn[8];
    #pragma unroll
    for (int e = 0; e < 8; ++e) {
      float iv = fsig(bf2f(xi8[e]) + bf2f(pi8[e]));
      float uv = ftanh(bf2f(xu8[e]) + bf2f(pu8[e]));
      ovv[e] = fsig(bf2f(xo8[e]) + bf2f(po8[e]));
      fx[e] = bf2f(xf8[e]);
      iu[e] = iv * uv;
      cn[e] = 0.f;
    }
    #pragma unroll
    for (int k = 0; k < Kc; ++k) {
      int j = nbj[r][k];
      us8 hf8 = *(const us8*)&Hf16x[(size_t)j * Hc + cc * 8];
      us8 cn8 = *(const us8*)&C16x[(size_t)j * Hc + cc * 8];
      #pragma unroll
      for (int e = 0; e < 8; ++e)
        cn[e] = fmaf(fsig(fx[e] + bf2f(hf8[e])), bf2f(cn8[e]), cn[e]);
    }
    float cacc[8];
    if (MODE == 1 && spos < S) {
      us8 cp8 = *(const us8*)&cpartNS[(size_t)spos * Hc + cc * 8];
      #pragma unroll
      for (int e = 0; e < 8; ++e) cacc[e] = iu[e] + cn[e] + bf2f(cp8[e]);
    } else {
      #pragma unroll
      for (int e = 0; e < 8; ++e) cacc[e] = iu[e] + cn[e];
    }
    float hv[8];
    #pragma unroll
    for (int e = 0; e < 8; ++e) hv[e] = ovv[e] * ftanh(cacc[e]);

    if (MODE == 0) {
      us8 h8, c8, cn16;
      #pragma unroll
      for (int e = 0; e < 8; ++e) {
        h8[e] = (spos < S) ? f2bf(hv[e]) : (ushortT)0;
        c8[e] = f2bf(cacc[e]);
        cn16[e] = f2bf(cn[e]);
      }
      if (spos < S) {
        *(us8*)&H16x[(size_t)(M + spos) * Hc + cc * 8] = h8;
        *(us8*)&C16x[(size_t)(M + spos) * Hc + cc * 8] = c8;
        *(us8*)&cpartNS[(size_t)spos * Hc + cc * 8] = cn16;
      }
      // stage h_new for fused Hf tail
      *(us4*)&zs[r * HSP + cc * 8]     = (us4){h8[0], h8[1], h8[2], h8[3]};
      *(us4*)&zs[r * HSP + cc * 8 + 4] = (us4){h8[4], h8[5], h8[6], h8[7]};
    } else {
      if (ms >= 0) {
        float* dh = dstH + (size_t)ms * Hc + cc * 8;
        float* dc = dstC + (size_t)ms * Hc + cc * 8;
        *(float4*)&dh[0] = *(float4*)&hv[0];
        *(float4*)&dh[4] = *(float4*)&hv[4];
        *(float4*)&dc[0] = *(float4*)&cacc[0];
        *(float4*)&dc[4] = *(float4*)&cacc[4];
      }
    }
  }

  if (MODE == 0) {
    // ---- fused Hf tail: Hf16x[M+spos] = h_new @ Wf2 ----
    __syncthreads();
    f32x4 a0 = (f32x4){0.f,0.f,0.f,0.f}, a1 = a0;
    const ushortT* zr2 = &zs[cl * HSP + lg * 8];
    #pragma unroll
    for (int kf = 0; kf < 4; ++kf) {
      bf16x8 a = *(const bf16x8*)&zr2[kf * 32];
      a0 = __builtin_amdgcn_mfma_f32_16x16x32_bf16(a, *wh_frag(pack, 3, w*2+0, kf, lane), a0, 0, 0, 0);
      a1 = __builtin_amdgcn_mfma_f32_16x16x32_bf16(a, *wh_frag(pack, 3, w*2+1, kf, lane), a1, 0, 0, 0);
    }
    #pragma unroll
    for (int half = 0; half < 2; ++half) {
      int col = (w * 2 + half) * 16 + cl;
      f32x4 a_ = half ? a1 : a0;
      #pragma unroll
      for (int reg = 0; reg < 4; ++reg) {
        int sp = row0 + lg * 4 + reg;
        if (sp < S) Hf16x[(size_t)(M + sp) * Hc + col] = f2bf(a_[reg]);
      }
    }
  }
}

// ---------------- kernel 7: node readout || zero non-sub node rows ----------------
__global__ __launch_bounds__(256) void readout_zero(
    const float* __restrict__ fnode, const int* __restrict__ agraph,
    const int* __restrict__ subnode, const float* __restrict__ h_out,
    const ushortT* __restrict__ H16x, const int* __restrict__ mark,
    const int* __restrict__ nmark,
    const ushortT* __restrict__ packWn, const float* __restrict__ bn,
    float* __restrict__ node_buf, int Nsub, int num_nodes, int NB, int ZB)
{
  __shared__ __align__(16) ushortT z2[16 * ZP2];
  __shared__ int orow[16];
  __shared__ int jn[16][Kc];   // sub neighbors encoded as ~j (negative)

  const int t = threadIdx.x;

  if ((int)blockIdx.x >= NB) {
    // --- zero part: rows with nmark < 0 ---
    long total = (long)num_nodes * 16;
    float4 z; z.x = z.y = z.z = z.w = 0.f;
    for (long idx = (long)(blockIdx.x - NB) * 256 + t; idx < total; idx += (long)ZB * 256) {
      long v = idx >> 4;
      int cp = (int)(idx & 15);
      if (nmark[v] < 0) {
        ((float4*)(node_buf + (size_t)v * Hc))[cp * 2] = z;
        ((float4*)(node_buf + (size_t)v * Hc))[cp * 2 + 1] = z;
      }
    }
    return;
  }

  const int row0 = blockIdx.x * 16;
  if (t < 16) orow[t] = (row0 + t < Nsub) ? subnode[row0 + t] : -1;
  if (t >= 64 && t < 64 + 128) {
    int i = t - 64, r = i >> 3, k = i & 7;
    int v = row0 + r;
    int j = 0;
    if (v < Nsub) {
      j = agraph[(size_t)v * Kc + k];
      if (mark[j] >= 0) j = ~j;        // sub message: gather f32 from h_out
    }
    jn[r][k] = j;
  }
  {
    int r = t >> 4, cp = t & 15;
    int v = row0 + r;
    const float4* fr = (v < Nsub) ? (const float4*)(fnode + (size_t)v * Hc) : nullptr;
    float4 v0, v1; v0.x = v0.y = v0.z = v0.w = 0.f; v1 = v0;
    if (fr) { v0 = fr[cp]; v1 = fr[cp + 16]; }
    *(us4*)&z2[r * ZP2 + cp * 4] = f2bf4(v0);
    *(us4*)&z2[r * ZP2 + 64 + cp * 4] = f2bf4(v1);
  }
  __syncthreads();
  {
    int r = t >> 4, cp = t & 15;
    float sum[8] = {0.f,0.f,0.f,0.f,0.f,0.f,0.f,0.f};
    #pragma unroll
    for (int k = 0; k < Kc; ++k) {
      int je = jn[r][k];
      if (je < 0) {
        int j = ~je;
        float4 p0 = ((const float4*)(h_out + (size_t)j * Hc))[cp * 2];
        float4 p1 = ((const float4*)(h_out + (size_t)j * Hc))[cp * 2 + 1];
        sum[0] += p0.x; sum[1] += p0.y; sum[2] += p0.z; sum[3] += p0.w;
        sum[4] += p1.x; sum[5] += p1.y; sum[6] += p1.z; sum[7] += p1.w;
      } else {
        us8 v = *(const us8*)&H16x[(size_t)je * Hc + cp * 8];
        #pragma unroll
        for (int e = 0; e < 8; ++e) sum[e] += bf2f(v[e]);
      }
    }
    us4 o0, o1;
    #pragma unroll
    for (int e = 0; e < 4; ++e) { o0[e] = f2bf(sum[e]); o1[e] = f2bf(sum[4 + e]); }
    *(us4*)&z2[r * ZP2 + Hc + cp * 8] = o0;
    *(us4*)&z2[r * ZP2 + Hc + cp * 8 + 4] = o1;
  }
  __syncthreads();

  const int w = t >> 6, lane = t & 63;
  const int lg = lane >> 4, cl = lane & 15;

  f32x4 acc0 = (f32x4){0.f,0.f,0.f,0.f};
  f32x4 acc1 = (f32x4){0.f,0.f,0.f,0.f};
  const ushortT* zr = &z2[cl * ZP2 + lg * 8];
  #pragma unroll
  for (int kt = 0; kt < 8; ++kt) {
    bf16x8 a = *(const bf16x8*)&zr[kt * 32];
    bf16x8 b0 = *(const bf16x8*)&packWn[(size_t)(((w * 2 + 0) * 8 + kt) * 64 + lane) * 8];
    bf16x8 b1 = *(const bf16x8*)&packWn[(size_t)(((w * 2 + 1) * 8 + kt) * 64 + lane) * 8];
    acc0 = __builtin_amdgcn_mfma_f32_16x16x32_bf16(a, b0, acc0, 0, 0, 0);
    acc1 = __builtin_amdgcn_mfma_f32_16x16x32_bf16(a, b1, acc1, 0, 0, 0);
  }
  #pragma unroll
  for (int half = 0; half < 2; ++half) {
    int col = (w * 2 + half) * 16 + cl;
    float bnv = bn[col];
    f32x4 a_ = half ? acc1 : acc0;
    #pragma unroll
    for (int reg = 0; reg < 4; ++reg) {
      int row = lg * 4 + reg;
      int o = orow[row];
      if (o >= 0) node_buf[(size_t)o * Hc + col] = fmaxf(a_[reg] + bnv, 0.f);
    }
  }
}

// ---------------- launch ----------------
extern "C" void kernel_launch(void* const* d_in, const int* in_sizes, int n_in,
                              void* d_out, int out_size, void* d_ws, size_t ws_size,
                              hipStream_t stream) {
  const float* fnode   = (const float*)d_in[0];
  const float* fmess   = (const float*)d_in[1];
  const int*   agraph  = (const int*)d_in[2];
  const int*   bgraph  = (const int*)d_in[3];
  const float* h_in    = (const float*)d_in[4];
  const float* c_in    = (const float*)d_in[5];
  const int*   submess = (const int*)d_in[6];
  const int*   subnode = (const int*)d_in[7];
  const float* Wi = (const float*)d_in[9];
  const float* bi = (const float*)d_in[10];
  const float* Wo = (const float*)d_in[11];
  const float* bo = (const float*)d_in[12];
  const float* Wf = (const float*)d_in[13];
  const float* bf_ = (const float*)d_in[14];
  const float* Wu = (const float*)d_in[15];
  const float* bu = (const float*)d_in[16];
  const float* Wn = (const float*)d_in[17];
  const float* bn = (const float*)d_in[18];

  const int S    = in_sizes[6];
  const int Nsub = in_sizes[2] / Kc;
  const int M    = in_sizes[4] / Hc;
  const int num_nodes = out_size / Hc - 2 * M;

  float* node_buf = (float*)d_out;
  float* h_out = node_buf + (size_t)num_nodes * Hc;
  float* c_out = h_out + (size_t)M * Hc;

  const int lblocks = (S + 15) / 16;

  // ws: mark[M] | nmark[num_nodes] | pack | Hf16x | C16x | H16x (each M+S+1 rows) | Xg
  // partials (hsumNS, cpartNS) in node_buf region (dead after lstm8<1>).
  int* mark = (int*)d_ws;
  size_t off = (((size_t)M * sizeof(int)) + 255) & ~(size_t)255;
  int* nmark = (int*)((char*)d_ws + off);
  off += (((size_t)num_nodes * sizeof(int)) + 255) & ~(size_t)255;
  ushortT* pack = (ushortT*)((char*)d_ws + off);
  off += (((size_t)(GATE_FRAGS + WN_FRAGS) * 8 * sizeof(ushortT)) + 255) & ~(size_t)255;
  size_t shadow_bytes = (((size_t)(M + S + 1) * Hc * sizeof(ushortT)) + 255) & ~(size_t)255;
  ushortT* Hf16x = (ushortT*)((char*)d_ws + off); off += shadow_bytes;
  ushortT* C16x  = (ushortT*)((char*)d_ws + off); off += shadow_bytes;
  ushortT* H16x  = (ushortT*)((char*)d_ws + off); off += shadow_bytes;
  ushortT* Xg    = (ushortT*)((char*)d_ws + off);
  ushortT* packWn = pack + (size_t)GATE_FRAGS * 8;
  ushortT* cpartNS = (ushortT*)node_buf;
  ushortT* hsumNS  = cpartNS + (size_t)S * Hc;

  // 1. init marks
  int initN = (M > num_nodes) ? M : num_nodes;
  hipLaunchKernelGGL(marks_init, dim3((initN + 255) / 256), dim3(256), 0, stream,
                     mark, M, nmark, num_nodes);
  // 2. set marks || repack
  {
    int SB = (S + 255) / 256;
    int RB = (GATE_FRAGS + WN_FRAGS + 255) / 256;
    hipLaunchKernelGGL(set_repack, dim3(SB + RB), dim3(256), 0, stream,
                       submess, subnode, S, mark, nmark, Wi, Wo, Wu, Wf, Wn, pack, SB);
  }
  // 3. stage (non-sub) || xg
  {
    int stageBlocks = 1024;
    hipLaunchKernelGGL(stage_xg, dim3(stageBlocks + lblocks), dim3(256), 0, stream,
                       h_in, c_in, mark, h_out, c_out, H16x, C16x, Hf16x,
                       fmess, submess, pack, bi, bo, bu, bf_, Xg, M, S, stageBlocks);
  }
  // 4. Hf over non-sub rows [0,M)
  hipLaunchKernelGGL(hf_rows0, dim3((M + 15) / 16), dim3(256), 0, stream,
                     H16x, mark, pack, Hf16x, M);
  // 5. iter 0 (fused Hf tail)
  hipLaunchKernelGGL(lstm8<0>, dim3(lblocks), dim3(256), 0, stream,
      submess, bgraph, mark, H16x, C16x, Hf16x, Xg, pack,
      hsumNS, cpartNS, h_out, c_out, S, M);
  // 6. iter 1
  hipLaunchKernelGGL(lstm8<1>, dim3(lblocks), dim3(256), 0, stream,
      submess, bgraph, mark, H16x, C16x, Hf16x, Xg, pack,
      hsumNS, cpartNS, h_out, c_out, S, M);
  // 7. readout || zero non-sub node rows
  {
    int NB = (Nsub + 15) / 16;
    int ZB = 512;
    hipLaunchKernelGGL(readout_zero, dim3(NB + ZB), dim3(256), 0, stream,
        fnode, agraph, subnode, h_out, H16x, mark, nmark, packWn, bn,
        node_buf, Nsub, num_nodes, NB, ZB);
  }
}

// Round 11
// 285.444 us; speedup vs baseline: 2.1838x; 1.0118x over previous
//
#include <hip/hip_runtime.h>
#include <cstdint>
#include <cstddef>

#define Hc   128
#define INc  256
#define Kc   8
#define HP   136          // stage/hf staging row pad (ushorts)
#define HSP  136          // lstm h_sum/h_new staging row pad (ushorts)
#define EPH  136          // lstm gate-partial arrays row pad (ushorts)
#define ZP2  264          // node/x staging row pad (ushorts)

typedef unsigned short ushortT;
typedef __attribute__((ext_vector_type(8))) short bf16x8;
typedef __attribute__((ext_vector_type(4))) float f32x4;
typedef __attribute__((ext_vector_type(4))) unsigned short us4;
typedef __attribute__((ext_vector_type(8))) unsigned short us8;

__device__ __forceinline__ float fsig(float x) {
  return __builtin_amdgcn_rcpf(1.f + __expf(-x));
}
__device__ __forceinline__ float ftanh(float x) {
  float e = __expf(2.f * fminf(x, 15.f));
  return (e - 1.f) * __builtin_amdgcn_rcpf(e + 1.f);
}
__device__ __forceinline__ ushortT f2bf(float f) {
  unsigned u = __builtin_bit_cast(unsigned, f);
  unsigned r = (u + 0x7fffu + ((u >> 16) & 1u)) >> 16;
  return (ushortT)r;
}
__device__ __forceinline__ us4 f2bf4(float4 v) {
  us4 o; o[0] = f2bf(v.x); o[1] = f2bf(v.y); o[2] = f2bf(v.z); o[3] = f2bf(v.w);
  return o;
}
__device__ __forceinline__ us8 f2bf8(float4 a, float4 b) {
  us8 o;
  o[0] = f2bf(a.x); o[1] = f2bf(a.y); o[2] = f2bf(a.z); o[3] = f2bf(a.w);
  o[4] = f2bf(b.x); o[5] = f2bf(b.y); o[6] = f2bf(b.z); o[7] = f2bf(b.w);
  return o;
}
__device__ __forceinline__ float bf2f(ushortT u) {
  return __builtin_bit_cast(float, (unsigned)u << 16);
}

#define GATE_FRAGS (4*8*12*64)
#define WN_FRAGS   (8*8*64)

// ---------------- kernel 1: init marks ----------------
__global__ void marks_init(int* __restrict__ mark, int M, int* __restrict__ nmark, int NN) {
  int i = blockIdx.x * blockDim.x + threadIdx.x;
  if (i < M) mark[i] = -1;
  if (i < NN) nmark[i] = -1;
}

// ---------------- kernel 2: set marks || repack weights ----------------
__global__ void set_repack(const int* __restrict__ submess, const int* __restrict__ subnode,
                           int S, int* __restrict__ mark, int* __restrict__ nmark,
                           const float* __restrict__ Wi, const float* __restrict__ Wo,
                           const float* __restrict__ Wu, const float* __restrict__ Wf,
                           const float* __restrict__ Wn, ushortT* __restrict__ pack, int SB) {
  if ((int)blockIdx.x < SB) {
    int i = blockIdx.x * 256 + threadIdx.x;
    if (i < S) { mark[submess[i]] = i; nmark[subnode[i]] = i; }
    return;
  }
  int idx = (blockIdx.x - SB) * 256 + threadIdx.x;
  if (idx < GATE_FRAGS) {
    int lane = idx & 63;
    int kt = (idx >> 6) % 12;
    int gc = idx / (64 * 12);
    int c = gc & 7, g = gc >> 3;
    const float* W = (g == 0) ? Wi : (g == 1) ? Wo : (g == 2) ? Wu : Wf;
    int k0 = kt * 32 + (lane >> 4) * 8;
    int col = c * 16 + (lane & 15);
    ushortT* dst = pack + (size_t)idx * 8;
    #pragma unroll
    for (int j = 0; j < 8; ++j) dst[j] = f2bf(W[(size_t)(k0 + j) * Hc + col]);
  } else if (idx < GATE_FRAGS + WN_FRAGS) {
    int i2 = idx - GATE_FRAGS;
    int lane = i2 & 63;
    int kt = (i2 >> 6) & 7;
    int c = i2 >> 9;
    int k0 = kt * 32 + (lane >> 4) * 8;
    int col = c * 16 + (lane & 15);
    ushortT* dst = pack + (size_t)GATE_FRAGS * 8 + (size_t)i2 * 8;
    #pragma unroll
    for (int j = 0; j < 8; ++j) dst[j] = f2bf(Wn[(size_t)(k0 + j) * Hc + col]);
  }
}

// W*2 B-fragment (h-part rows 256..383 of gate g => kt slots 8..11)
__device__ __forceinline__ const bf16x8* wh_frag(const ushortT* pack, int g, int cw, int kf, int lane) {
  return (const bf16x8*)&pack[(size_t)(((g * 8 + cw) * 12 + (8 + kf)) * 64 + lane) * 8];
}

// ---------------- kernel 3: xg_gemm (blocks [0,XB)) || stage+Hf tiles ----------------
// xg first (longest blocks first). stage tiles: 16 non-sub rows each —
// f32 passthrough + us8 bf16 shadows + fused Hf MFMA; one iteration/thread.
__global__ __launch_bounds__(256) void xg_stage_hf(
    const float* __restrict__ fmess, const int* __restrict__ submess,
    const ushortT* __restrict__ pack,
    const float* __restrict__ bi, const float* __restrict__ bo,
    const float* __restrict__ bu, const float* __restrict__ bfb,
    ushortT* __restrict__ Xg,
    const float* __restrict__ h_in, const float* __restrict__ c_in,
    const int* __restrict__ mark,
    float* __restrict__ h_out, float* __restrict__ c_out,
    ushortT* __restrict__ H16x, ushortT* __restrict__ C16x, ushortT* __restrict__ Hf16x,
    int M, int S, int XB)
{
  __shared__ __align__(16) unsigned char pool[16 * ZP2 * 2];   // 8448 B
  __shared__ int aux[16];
  const int t = threadIdx.x;
  const int w = t >> 6, lane = t & 63, lg = lane >> 4, cl = lane & 15;

  if ((int)blockIdx.x < XB) {
    // ---- xg part ----
    ushortT* xs = (ushortT*)pool;
    const int row0 = blockIdx.x * 16;
    if (t < 16) aux[t] = (row0 + t < S) ? submess[row0 + t] : -1;
    __syncthreads();
    {
      int r = t >> 4, cp = t & 15;
      int ms = aux[r];
      const float4* xr = (ms >= 0) ? (const float4*)(fmess + (size_t)ms * INc) : nullptr;
      #pragma unroll
      for (int q = 0; q < 4; ++q) {
        int slot = cp + q * 16;
        float4 v;
        if (xr) v = xr[slot]; else { v.x = v.y = v.z = v.w = 0.f; }
        *(us4*)&xs[r * ZP2 + slot * 4] = f2bf4(v);
      }
    }
    __syncthreads();

    f32x4 acc[8];
    #pragma unroll
    for (int i = 0; i < 8; ++i) acc[i] = (f32x4){0.f, 0.f, 0.f, 0.f};
    const ushortT* zr = &xs[cl * ZP2 + lg * 8];
    #pragma unroll
    for (int kt = 0; kt < 8; ++kt) {
      bf16x8 a = *(const bf16x8*)&zr[kt * 32];
      #pragma unroll
      for (int c = 0; c < 8; ++c) {
        bf16x8 b = *(const bf16x8*)&pack[(size_t)(((w * 8 + c) * 12 + kt) * 64 + lane) * 8];
        acc[c] = __builtin_amdgcn_mfma_f32_16x16x32_bf16(a, b, acc[c], 0, 0, 0);
      }
    }
    const float* bias = (w == 0) ? bi : (w == 1) ? bo : (w == 2) ? bu : bfb;
    #pragma unroll
    for (int c = 0; c < 8; ++c) {
      int col = c * 16 + cl;
      float bv = bias[col];
      #pragma unroll
      for (int reg = 0; reg < 4; ++reg) {
        int s = row0 + lg * 4 + reg;
        if (s < S) Xg[(size_t)s * 512 + w * 128 + col] = f2bf(acc[c][reg] + bv);
      }
    }
    return;
  }

  // ---- stage + Hf tile part ----
  ushortT* zh = (ushortT*)pool;   // [16][HP]
  int* mk = aux;
  const int row0 = (blockIdx.x - XB) * 16;

  if (blockIdx.x == XB && t < 48) {    // zero DUMMY row M+S of all shadows
    int arr = t >> 4, cp = t & 15;
    ushortT* dst = (arr == 0) ? H16x : (arr == 1) ? C16x : Hf16x;
    us8 z;
    #pragma unroll
    for (int e = 0; e < 8; ++e) z[e] = 0;
    *(us8*)&dst[(size_t)(M + S) * Hc + cp * 8] = z;
  }
  if (t < 16) mk[t] = (row0 + t < M) ? mark[row0 + t] : 0;   // >=0 => skip
  __syncthreads();
  {
    int r = t >> 4, cp = t & 15;
    int j = row0 + r;
    us8 hz;
    #pragma unroll
    for (int e = 0; e < 8; ++e) hz[e] = 0;
    if (j < M && mk[r] < 0) {
      const float4* h4 = (const float4*)(h_in + (size_t)j * Hc);
      const float4* c4 = (const float4*)(c_in + (size_t)j * Hc);
      float4 a0 = h4[cp * 2], a1 = h4[cp * 2 + 1];
      float4 b0 = c4[cp * 2], b1 = c4[cp * 2 + 1];
      ((float4*)(h_out + (size_t)j * Hc))[cp * 2] = a0;
      ((float4*)(h_out + (size_t)j * Hc))[cp * 2 + 1] = a1;
      ((float4*)(c_out + (size_t)j * Hc))[cp * 2] = b0;
      ((float4*)(c_out + (size_t)j * Hc))[cp * 2 + 1] = b1;
      us8 h8 = f2bf8(a0, a1);
      *(us8*)&H16x[(size_t)j * Hc + cp * 8] = h8;
      *(us8*)&C16x[(size_t)j * Hc + cp * 8] = f2bf8(b0, b1);
      hz = h8;
    }
    *(us8*)&zh[r * HP + cp * 8] = hz;
  }
  __syncthreads();

  f32x4 acc0 = (f32x4){0.f,0.f,0.f,0.f}, acc1 = acc0;
  const ushortT* zr = &zh[cl * HP + lg * 8];
  #pragma unroll
  for (int kf = 0; kf < 4; ++kf) {
    bf16x8 a = *(const bf16x8*)&zr[kf * 32];
    acc0 = __builtin_amdgcn_mfma_f32_16x16x32_bf16(a, *wh_frag(pack, 3, w*2+0, kf, lane), acc0, 0, 0, 0);
    acc1 = __builtin_amdgcn_mfma_f32_16x16x32_bf16(a, *wh_frag(pack, 3, w*2+1, kf, lane), acc1, 0, 0, 0);
  }
  #pragma unroll
  for (int half = 0; half < 2; ++half) {
    int col = (w * 2 + half) * 16 + cl;
    f32x4 a_ = half ? acc1 : acc0;
    #pragma unroll
    for (int reg = 0; reg < 4; ++reg) {
      int row = lg * 4 + reg;
      if (row0 + row < M && mk[row] < 0)
        Hf16x[(size_t)(row0 + row) * Hc + col] = f2bf(a_[reg]);
    }
  }
}

// ---- kernels 4/5: LSTM step with redirect + partial reuse (unchanged R10) ----
template<int MODE>
__global__ __launch_bounds__(256) void lstm8(
    const int* __restrict__ submess, const int* __restrict__ bgraph,
    const int* __restrict__ mark,
    ushortT* H16x, ushortT* C16x, ushortT* Hf16x,
    const ushortT* __restrict__ Xg, const ushortT* __restrict__ pack,
    ushortT* hsumNS, ushortT* cpartNS,
    float* __restrict__ dstH, float* __restrict__ dstC, int S, int M)
{
  __shared__ __align__(16) ushortT zs[16 * HSP];
  __shared__ __align__(16) ushortT pih[16 * EPH];
  __shared__ __align__(16) ushortT poh[16 * EPH];
  __shared__ __align__(16) ushortT puh[16 * EPH];
  __shared__ int nbj[16][Kc];
  __shared__ int msrow[16];

  const int t = threadIdx.x;
  const int row0 = blockIdx.x * 16;
  const int DUMMY = M + S;

  if (t < 128) {
    int r = t >> 3, k = t & 7;
    int s = row0 + r;
    int ms = (s < S) ? submess[s] : -1;
    if (k == 0) msrow[r] = ms;
    int j = DUMMY;
    if (ms >= 0) {
      int jj = bgraph[(size_t)ms * Kc + k];
      int m = mark[jj];
      j = (MODE == 0) ? (m >= 0 ? DUMMY : jj) : (m >= 0 ? M + m : DUMMY);
    }
    nbj[r][k] = j;
  }
  __syncthreads();

  {
    int r = t >> 4, cp = t & 15;
    int spos = row0 + r;
    float sum[8] = {0.f,0.f,0.f,0.f,0.f,0.f,0.f,0.f};
    if (MODE == 1 && spos < S) {
      us8 hs = *(const us8*)&hsumNS[(size_t)spos * Hc + cp * 8];
      #pragma unroll
      for (int e = 0; e < 8; ++e) sum[e] = bf2f(hs[e]);
    }
    #pragma unroll
    for (int k = 0; k < Kc; ++k) {
      int j = nbj[r][k];
      us8 v = *(const us8*)&H16x[(size_t)j * Hc + cp * 8];
      #pragma unroll
      for (int e = 0; e < 8; ++e) sum[e] += bf2f(v[e]);
    }
    us8 o8;
    #pragma unroll
    for (int e = 0; e < 8; ++e) o8[e] = f2bf(sum[e]);
    *(us8*)&zs[r * HSP + cp * 8] = o8;
    if (MODE == 0 && spos < S)
      *(us8*)&hsumNS[(size_t)spos * Hc + cp * 8] = o8;
  }
  __syncthreads();

  const int w = t >> 6, lane = t & 63, lg = lane >> 4, cl = lane & 15;

  f32x4 acc[6];
  #pragma unroll
  for (int i = 0; i < 6; ++i) acc[i] = (f32x4){0.f, 0.f, 0.f, 0.f};
  const ushortT* zrow = &zs[cl * HSP + lg * 8];
  #pragma unroll
  for (int kf = 0; kf < 4; ++kf) {
    bf16x8 a = *(const bf16x8*)&zrow[kf * 32];
    #pragma unroll
    for (int g = 0; g < 3; ++g)
      #pragma unroll
      for (int half = 0; half < 2; ++half)
        acc[g * 2 + half] = __builtin_amdgcn_mfma_f32_16x16x32_bf16(
            a, *wh_frag(pack, g, w * 2 + half, kf, lane), acc[g * 2 + half], 0, 0, 0);
  }

  #pragma unroll
  for (int half = 0; half < 2; ++half) {
    int col = (w * 2 + half) * 16 + cl;
    #pragma unroll
    for (int reg = 0; reg < 4; ++reg) {
      int row = lg * 4 + reg;
      pih[row * EPH + col] = f2bf(acc[0 + half][reg]);
      poh[row * EPH + col] = f2bf(acc[2 + half][reg]);
      puh[row * EPH + col] = f2bf(acc[4 + half][reg]);
    }
  }
  __syncthreads();

  {
    int r = t >> 4, cc = t & 15;
    int ms = msrow[r];
    int spos = row0 + r;
    const ushortT* xgr = Xg + (size_t)spos * 512 + cc * 8;
    us8 xi8 = *(const us8*)&xgr[0];
    us8 xo8 = *(const us8*)&xgr[128];
    us8 xu8 = *(const us8*)&xgr[256];
    us8 xf8 = *(const us8*)&xgr[384];
    us8 pi8 = *(const us8*)&pih[r * EPH + cc * 8];
    us8 po8 = *(const us8*)&poh[r * EPH + cc * 8];
    us8 pu8 = *(const us8*)&puh[r * EPH + cc * 8];
    float fx[8], ovv[8], iu[8], cn[8];
    #pragma unroll
    for (int e = 0; e < 8; ++e) {
      float iv = fsig(bf2f(xi8[e]) + bf2f(pi8[e]));
      float uv = ftanh(bf2f(xu8[e]) + bf2f(pu8[e]));
      ovv[e] = fsig(bf2f(xo8[e]) + bf2f(po8[e]));
      fx[e] = bf2f(xf8[e]);
      iu[e] = iv * uv;
      cn[e] = 0.f;
    }
    #pragma unroll
    for (int k = 0; k < Kc; ++k) {
      int j = nbj[r][k];
      us8 hf8 = *(const us8*)&Hf16x[(size_t)j * Hc + cc * 8];
      us8 cn8 = *(const us8*)&C16x[(size_t)j * Hc + cc * 8];
      #pragma unroll
      for (int e = 0; e < 8; ++e)
        cn[e] = fmaf(fsig(fx[e] + bf2f(hf8[e])), bf2f(cn8[e]), cn[e]);
    }
    float cacc[8];
    if (MODE == 1 && spos < S) {
      us8 cp8 = *(const us8*)&cpartNS[(size_t)spos * Hc + cc * 8];
      #pragma unroll
      for (int e = 0; e < 8; ++e) cacc[e] = iu[e] + cn[e] + bf2f(cp8[e]);
    } else {
      #pragma unroll
      for (int e = 0; e < 8; ++e) cacc[e] = iu[e] + cn[e];
    }
    float hv[8];
    #pragma unroll
    for (int e = 0; e < 8; ++e) hv[e] = ovv[e] * ftanh(cacc[e]);

    if (MODE == 0) {
      us8 h8, c8, cn16;
      #pragma unroll
      for (int e = 0; e < 8; ++e) {
        h8[e] = (spos < S) ? f2bf(hv[e]) : (ushortT)0;
        c8[e] = f2bf(cacc[e]);
        cn16[e] = f2bf(cn[e]);
      }
      if (spos < S) {
        *(us8*)&H16x[(size_t)(M + spos) * Hc + cc * 8] = h8;
        *(us8*)&C16x[(size_t)(M + spos) * Hc + cc * 8] = c8;
        *(us8*)&cpartNS[(size_t)spos * Hc + cc * 8] = cn16;
      }
      *(us8*)&zs[r * HSP + cc * 8] = h8;
    } else {
      if (ms >= 0) {
        float* dh = dstH + (size_t)ms * Hc + cc * 8;
        float* dc = dstC + (size_t)ms * Hc + cc * 8;
        *(float4*)&dh[0] = *(float4*)&hv[0];
        *(float4*)&dh[4] = *(float4*)&hv[4];
        *(float4*)&dc[0] = *(float4*)&cacc[0];
        *(float4*)&dc[4] = *(float4*)&cacc[4];
      }
    }
  }

  if (MODE == 0) {
    __syncthreads();
    f32x4 a0 = (f32x4){0.f,0.f,0.f,0.f}, a1 = a0;
    const ushortT* zr2 = &zs[cl * HSP + lg * 8];
    #pragma unroll
    for (int kf = 0; kf < 4; ++kf) {
      bf16x8 a = *(const bf16x8*)&zr2[kf * 32];
      a0 = __builtin_amdgcn_mfma_f32_16x16x32_bf16(a, *wh_frag(pack, 3, w*2+0, kf, lane), a0, 0, 0, 0);
      a1 = __builtin_amdgcn_mfma_f32_16x16x32_bf16(a, *wh_frag(pack, 3, w*2+1, kf, lane), a1, 0, 0, 0);
    }
    #pragma unroll
    for (int half = 0; half < 2; ++half) {
      int col = (w * 2 + half) * 16 + cl;
      f32x4 a_ = half ? a1 : a0;
      #pragma unroll
      for (int reg = 0; reg < 4; ++reg) {
        int sp = row0 + lg * 4 + reg;
        if (sp < S) Hf16x[(size_t)(M + sp) * Hc + col] = f2bf(a_[reg]);
      }
    }
  }
}

// ---------------- kernel 6: node readout || zero non-sub node rows ----------------
__global__ __launch_bounds__(256) void readout_zero(
    const float* __restrict__ fnode, const int* __restrict__ agraph,
    const int* __restrict__ subnode, const float* __restrict__ h_out,
    const ushortT* __restrict__ H16x, const int* __restrict__ mark,
    const int* __restrict__ nmark,
    const ushortT* __restrict__ packWn, const float* __restrict__ bn,
    float* __restrict__ node_buf, int Nsub, int num_nodes, int NB, int ZB)
{
  __shared__ __align__(16) ushortT z2[16 * ZP2];
  __shared__ int orow[16];
  __shared__ int jn[16][Kc];

  const int t = threadIdx.x;

  if ((int)blockIdx.x >= NB) {
    long total = (long)num_nodes * 16;
    float4 z; z.x = z.y = z.z = z.w = 0.f;
    for (long idx = (long)(blockIdx.x - NB) * 256 + t; idx < total; idx += (long)ZB * 256) {
      long v = idx >> 4;
      int cp = (int)(idx & 15);
      if (nmark[v] < 0) {
        ((float4*)(node_buf + (size_t)v * Hc))[cp * 2] = z;
        ((float4*)(node_buf + (size_t)v * Hc))[cp * 2 + 1] = z;
      }
    }
    return;
  }

  const int row0 = blockIdx.x * 16;
  if (t < 16) orow[t] = (row0 + t < Nsub) ? subnode[row0 + t] : -1;
  if (t >= 64 && t < 64 + 128) {
    int i = t - 64, r = i >> 3, k = i & 7;
    int v = row0 + r;
    int j = 0;
    if (v < Nsub) {
      j = agraph[(size_t)v * Kc + k];
      if (mark[j] >= 0) j = ~j;
    }
    jn[r][k] = j;
  }
  {
    int r = t >> 4, cp = t & 15;
    int v = row0 + r;
    const float4* fr = (v < Nsub) ? (const float4*)(fnode + (size_t)v * Hc) : nullptr;
    float4 v0, v1; v0.x = v0.y = v0.z = v0.w = 0.f; v1 = v0;
    if (fr) { v0 = fr[cp]; v1 = fr[cp + 16]; }
    *(us4*)&z2[r * ZP2 + cp * 4] = f2bf4(v0);
    *(us4*)&z2[r * ZP2 + 64 + cp * 4] = f2bf4(v1);
  }
  __syncthreads();
  {
    int r = t >> 4, cp = t & 15;
    float sum[8] = {0.f,0.f,0.f,0.f,0.f,0.f,0.f,0.f};
    #pragma unroll
    for (int k = 0; k < Kc; ++k) {
      int je = jn[r][k];
      if (je < 0) {
        int j = ~je;
        float4 p0 = ((const float4*)(h_out + (size_t)j * Hc))[cp * 2];
        float4 p1 = ((const float4*)(h_out + (size_t)j * Hc))[cp * 2 + 1];
        sum[0] += p0.x; sum[1] += p0.y; sum[2] += p0.z; sum[3] += p0.w;
        sum[4] += p1.x; sum[5] += p1.y; sum[6] += p1.z; sum[7] += p1.w;
      } else {
        us8 v = *(const us8*)&H16x[(size_t)je * Hc + cp * 8];
        #pragma unroll
        for (int e = 0; e < 8; ++e) sum[e] += bf2f(v[e]);
      }
    }
    us8 o8;
    #pragma unroll
    for (int e = 0; e < 8; ++e) o8[e] = f2bf(sum[e]);
    *(us8*)&z2[r * ZP2 + Hc + cp * 8] = o8;
  }
  __syncthreads();

  const int w = t >> 6, lane = t & 63;
  const int lg = lane >> 4, cl = lane & 15;

  f32x4 acc0 = (f32x4){0.f,0.f,0.f,0.f};
  f32x4 acc1 = (f32x4){0.f,0.f,0.f,0.f};
  const ushortT* zr = &z2[cl * ZP2 + lg * 8];
  #pragma unroll
  for (int kt = 0; kt < 8; ++kt) {
    bf16x8 a = *(const bf16x8*)&zr[kt * 32];
    bf16x8 b0 = *(const bf16x8*)&packWn[(size_t)(((w * 2 + 0) * 8 + kt) * 64 + lane) * 8];
    bf16x8 b1 = *(const bf16x8*)&packWn[(size_t)(((w * 2 + 1) * 8 + kt) * 64 + lane) * 8];
    acc0 = __builtin_amdgcn_mfma_f32_16x16x32_bf16(a, b0, acc0, 0, 0, 0);
    acc1 = __builtin_amdgcn_mfma_f32_16x16x32_bf16(a, b1, acc1, 0, 0, 0);
  }
  #pragma unroll
  for (int half = 0; half < 2; ++half) {
    int col = (w * 2 + half) * 16 + cl;
    float bnv = bn[col];
    f32x4 a_ = half ? acc1 : acc0;
    #pragma unroll
    for (int reg = 0; reg < 4; ++reg) {
      int row = lg * 4 + reg;
      int o = orow[row];
      if (o >= 0) node_buf[(size_t)o * Hc + col] = fmaxf(a_[reg] + bnv, 0.f);
    }
  }
}

// ---------------- launch ----------------
extern "C" void kernel_launch(void* const* d_in, const int* in_sizes, int n_in,
                              void* d_out, int out_size, void* d_ws, size_t ws_size,
                              hipStream_t stream) {
  const float* fnode   = (const float*)d_in[0];
  const float* fmess   = (const float*)d_in[1];
  const int*   agraph  = (const int*)d_in[2];
  const int*   bgraph  = (const int*)d_in[3];
  const float* h_in    = (const float*)d_in[4];
  const float* c_in    = (const float*)d_in[5];
  const int*   submess = (const int*)d_in[6];
  const int*   subnode = (const int*)d_in[7];
  const float* Wi = (const float*)d_in[9];
  const float* bi = (const float*)d_in[10];
  const float* Wo = (const float*)d_in[11];
  const float* bo = (const float*)d_in[12];
  const float* Wf = (const float*)d_in[13];
  const float* bf_ = (const float*)d_in[14];
  const float* Wu = (const float*)d_in[15];
  const float* bu = (const float*)d_in[16];
  const float* Wn = (const float*)d_in[17];
  const float* bn = (const float*)d_in[18];

  const int S    = in_sizes[6];
  const int Nsub = in_sizes[2] / Kc;
  const int M    = in_sizes[4] / Hc;
  const int num_nodes = out_size / Hc - 2 * M;

  float* node_buf = (float*)d_out;
  float* h_out = node_buf + (size_t)num_nodes * Hc;
  float* c_out = h_out + (size_t)M * Hc;

  const int lblocks = (S + 15) / 16;

  // ws: mark[M] | nmark[num_nodes] | pack | Hf16x | C16x | H16x (each M+S+1 rows) | Xg
  int* mark = (int*)d_ws;
  size_t off = (((size_t)M * sizeof(int)) + 255) & ~(size_t)255;
  int* nmark = (int*)((char*)d_ws + off);
  off += (((size_t)num_nodes * sizeof(int)) + 255) & ~(size_t)255;
  ushortT* pack = (ushortT*)((char*)d_ws + off);
  off += (((size_t)(GATE_FRAGS + WN_FRAGS) * 8 * sizeof(ushortT)) + 255) & ~(size_t)255;
  size_t shadow_bytes = (((size_t)(M + S + 1) * Hc * sizeof(ushortT)) + 255) & ~(size_t)255;
  ushortT* Hf16x = (ushortT*)((char*)d_ws + off); off += shadow_bytes;
  ushortT* C16x  = (ushortT*)((char*)d_ws + off); off += shadow_bytes;
  ushortT* H16x  = (ushortT*)((char*)d_ws + off); off += shadow_bytes;
  ushortT* Xg    = (ushortT*)((char*)d_ws + off);
  ushortT* packWn = pack + (size_t)GATE_FRAGS * 8;
  ushortT* cpartNS = (ushortT*)node_buf;
  ushortT* hsumNS  = cpartNS + (size_t)S * Hc;

  // 1. init marks
  int initN = (M > num_nodes) ? M : num_nodes;
  hipLaunchKernelGGL(marks_init, dim3((initN + 255) / 256), dim3(256), 0, stream,
                     mark, M, nmark, num_nodes);
  // 2. set marks || repack
  {
    int SB = (S + 255) / 256;
    int RB = (GATE_FRAGS + WN_FRAGS + 255) / 256;
    hipLaunchKernelGGL(set_repack, dim3(SB + RB), dim3(256), 0, stream,
                       submess, subnode, S, mark, nmark, Wi, Wo, Wu, Wf, Wn, pack, SB);
  }
  // 3. xg || stage+Hf tiles (xg blocks first: LPT scheduling)
  {
    int XB = lblocks;
    int SB2 = (M + 15) / 16;
    hipLaunchKernelGGL(xg_stage_hf, dim3(XB + SB2), dim3(256), 0, stream,
                       fmess, submess, pack, bi, bo, bu, bf_, Xg,
                       h_in, c_in, mark, h_out, c_out, H16x, C16x, Hf16x,
                       M, S, XB);
  }
  // 4. iter 0 (fused Hf tail)
  hipLaunchKernelGGL(lstm8<0>, dim3(lblocks), dim3(256), 0, stream,
      submess, bgraph, mark, H16x, C16x, Hf16x, Xg, pack,
      hsumNS, cpartNS, h_out, c_out, S, M);
  // 5. iter 1
  hipLaunchKernelGGL(lstm8<1>, dim3(lblocks), dim3(256), 0, stream,
      submess, bgraph, mark, H16x, C16x, Hf16x, Xg, pack,
      hsumNS, cpartNS, h_out, c_out, S, M);
  // 6. readout || zero non-sub node rows
  {
    int NB = (Nsub + 15) / 16;
    int ZB = 512;
    hipLaunchKernelGGL(readout_zero, dim3(NB + ZB), dim3(256), 0, stream,
        fnode, agraph, subnode, h_out, H16x, mark, nmark, packWn, bn,
        node_buf, Nsub, num_nodes, NB, ZB);
  }
}

// Round 12
// 278.600 us; speedup vs baseline: 2.2374x; 1.0246x over previous
//
#include <hip/hip_runtime.h>
#include <cstdint>
#include <cstddef>

#define Hc   128
#define INc  256
#define Kc   8
#define HP   136          // stage/hf staging row pad (ushorts)
#define HSP  136          // lstm h_sum/h_new staging row pad (ushorts)
#define EPH  136          // lstm gate-partial arrays row pad (ushorts)
#define ZP2  264          // node/x staging row pad (ushorts)
#define XOP  520          // xg output LDS row pad (ushorts)

typedef unsigned short ushortT;
typedef __attribute__((ext_vector_type(8))) short bf16x8;
typedef __attribute__((ext_vector_type(4))) float f32x4;
typedef __attribute__((ext_vector_type(4))) unsigned short us4;
typedef __attribute__((ext_vector_type(8))) unsigned short us8;

__device__ __forceinline__ float fsig(float x) {
  return __builtin_amdgcn_rcpf(1.f + __expf(-x));
}
__device__ __forceinline__ float ftanh(float x) {
  float e = __expf(2.f * fminf(x, 15.f));
  return (e - 1.f) * __builtin_amdgcn_rcpf(e + 1.f);
}
__device__ __forceinline__ ushortT f2bf(float f) {
  unsigned u = __builtin_bit_cast(unsigned, f);
  unsigned r = (u + 0x7fffu + ((u >> 16) & 1u)) >> 16;
  return (ushortT)r;
}
__device__ __forceinline__ us4 f2bf4(float4 v) {
  us4 o; o[0] = f2bf(v.x); o[1] = f2bf(v.y); o[2] = f2bf(v.z); o[3] = f2bf(v.w);
  return o;
}
__device__ __forceinline__ us8 f2bf8(float4 a, float4 b) {
  us8 o;
  o[0] = f2bf(a.x); o[1] = f2bf(a.y); o[2] = f2bf(a.z); o[3] = f2bf(a.w);
  o[4] = f2bf(b.x); o[5] = f2bf(b.y); o[6] = f2bf(b.z); o[7] = f2bf(b.w);
  return o;
}
__device__ __forceinline__ float bf2f(ushortT u) {
  return __builtin_bit_cast(float, (unsigned)u << 16);
}

#define GATE_FRAGS (4*8*12*64)
#define WN_FRAGS   (8*8*64)

// ---------------- kernel 1: init marks ----------------
__global__ void marks_init(int* __restrict__ mark, int M, int* __restrict__ nmark, int NN) {
  int i = blockIdx.x * blockDim.x + threadIdx.x;
  if (i < M) mark[i] = -1;
  if (i < NN) nmark[i] = -1;
}

// ---------------- kernel 2: set marks || repack weights ----------------
__global__ void set_repack(const int* __restrict__ submess, const int* __restrict__ subnode,
                           int S, int* __restrict__ mark, int* __restrict__ nmark,
                           const float* __restrict__ Wi, const float* __restrict__ Wo,
                           const float* __restrict__ Wu, const float* __restrict__ Wf,
                           const float* __restrict__ Wn, ushortT* __restrict__ pack, int SB) {
  if ((int)blockIdx.x < SB) {
    int i = blockIdx.x * 256 + threadIdx.x;
    if (i < S) { mark[submess[i]] = i; nmark[subnode[i]] = i; }
    return;
  }
  int idx = (blockIdx.x - SB) * 256 + threadIdx.x;
  if (idx < GATE_FRAGS) {
    int lane = idx & 63;
    int kt = (idx >> 6) % 12;
    int gc = idx / (64 * 12);
    int c = gc & 7, g = gc >> 3;
    const float* W = (g == 0) ? Wi : (g == 1) ? Wo : (g == 2) ? Wu : Wf;
    int k0 = kt * 32 + (lane >> 4) * 8;
    int col = c * 16 + (lane & 15);
    ushortT* dst = pack + (size_t)idx * 8;
    #pragma unroll
    for (int j = 0; j < 8; ++j) dst[j] = f2bf(W[(size_t)(k0 + j) * Hc + col]);
  } else if (idx < GATE_FRAGS + WN_FRAGS) {
    int i2 = idx - GATE_FRAGS;
    int lane = i2 & 63;
    int kt = (i2 >> 6) & 7;
    int c = i2 >> 9;
    int k0 = kt * 32 + (lane >> 4) * 8;
    int col = c * 16 + (lane & 15);
    ushortT* dst = pack + (size_t)GATE_FRAGS * 8 + (size_t)i2 * 8;
    #pragma unroll
    for (int j = 0; j < 8; ++j) dst[j] = f2bf(Wn[(size_t)(k0 + j) * Hc + col]);
  }
}

// W*2 B-fragment (h-part rows 256..383 of gate g => kt slots 8..11)
__device__ __forceinline__ const bf16x8* wh_frag(const ushortT* pack, int g, int cw, int kf, int lane) {
  return (const bf16x8*)&pack[(size_t)(((g * 8 + cw) * 12 + (8 + kf)) * 64 + lane) * 8];
}

// ---------------- kernel 3: xg_gemm (blocks [0,XB)) || stage+Hf tiles ----------------
// All MFMA epilogues store via LDS roundtrip -> coalesced us8 stores.
__global__ __launch_bounds__(256) void xg_stage_hf(
    const float* __restrict__ fmess, const int* __restrict__ submess,
    const ushortT* __restrict__ pack,
    const float* __restrict__ bi, const float* __restrict__ bo,
    const float* __restrict__ bu, const float* __restrict__ bfb,
    ushortT* __restrict__ Xg,
    const float* __restrict__ h_in, const float* __restrict__ c_in,
    const int* __restrict__ mark,
    float* __restrict__ h_out, float* __restrict__ c_out,
    ushortT* __restrict__ H16x, ushortT* __restrict__ C16x, ushortT* __restrict__ Hf16x,
    int M, int S, int XB)
{
  __shared__ __align__(16) unsigned char pool[16 * XOP * 2];   // 16640 B
  __shared__ int aux[16];
  const int t = threadIdx.x;
  const int w = t >> 6, lane = t & 63, lg = lane >> 4, cl = lane & 15;

  if ((int)blockIdx.x < XB) {
    // ---- xg part ----
    ushortT* xs = (ushortT*)pool;                 // input staging, stride ZP2
    ushortT* xo = (ushortT*)pool;                 // output staging, stride XOP
    const int row0 = blockIdx.x * 16;
    if (t < 16) aux[t] = (row0 + t < S) ? submess[row0 + t] : -1;
    __syncthreads();
    {
      int r = t >> 4, cp = t & 15;
      int ms = aux[r];
      const float4* xr = (ms >= 0) ? (const float4*)(fmess + (size_t)ms * INc) : nullptr;
      #pragma unroll
      for (int q = 0; q < 4; ++q) {
        int slot = cp + q * 16;
        float4 v;
        if (xr) v = xr[slot]; else { v.x = v.y = v.z = v.w = 0.f; }
        *(us4*)&xs[r * ZP2 + slot * 4] = f2bf4(v);
      }
    }
    __syncthreads();

    f32x4 acc[8];
    #pragma unroll
    for (int i = 0; i < 8; ++i) acc[i] = (f32x4){0.f, 0.f, 0.f, 0.f};
    const ushortT* zr = &xs[cl * ZP2 + lg * 8];
    #pragma unroll
    for (int kt = 0; kt < 8; ++kt) {
      bf16x8 a = *(const bf16x8*)&zr[kt * 32];
      #pragma unroll
      for (int c = 0; c < 8; ++c) {
        bf16x8 b = *(const bf16x8*)&pack[(size_t)(((w * 8 + c) * 12 + kt) * 64 + lane) * 8];
        acc[c] = __builtin_amdgcn_mfma_f32_16x16x32_bf16(a, b, acc[c], 0, 0, 0);
      }
    }
    __syncthreads();   // xs reads done; pool becomes output buffer
    const float* bias = (w == 0) ? bi : (w == 1) ? bo : (w == 2) ? bu : bfb;
    #pragma unroll
    for (int c = 0; c < 8; ++c) {
      int col = c * 16 + cl;
      float bv = bias[col];
      #pragma unroll
      for (int reg = 0; reg < 4; ++reg)
        xo[(lg * 4 + reg) * XOP + w * 128 + col] = f2bf(acc[c][reg] + bv);
    }
    __syncthreads();
    {
      int r = t >> 4, cc = t & 15;
      int s = row0 + r;
      if (s < S) {
        const ushortT* src = &xo[r * XOP + cc * 32];
        ushortT* dst = &Xg[(size_t)s * 512 + cc * 32];
        *(us8*)&dst[0]  = *(const us8*)&src[0];
        *(us8*)&dst[8]  = *(const us8*)&src[8];
        *(us8*)&dst[16] = *(const us8*)&src[16];
        *(us8*)&dst[24] = *(const us8*)&src[24];
      }
    }
    return;
  }

  // ---- stage + Hf tile part ----
  ushortT* zh = (ushortT*)pool;   // [16][HP]
  int* mk = aux;
  const int row0 = (blockIdx.x - XB) * 16;

  if (blockIdx.x == XB && t < 48) {    // zero DUMMY row M+S of all shadows
    int arr = t >> 4, cp = t & 15;
    ushortT* dst = (arr == 0) ? H16x : (arr == 1) ? C16x : Hf16x;
    us8 z;
    #pragma unroll
    for (int e = 0; e < 8; ++e) z[e] = 0;
    *(us8*)&dst[(size_t)(M + S) * Hc + cp * 8] = z;
  }
  if (t < 16) mk[t] = (row0 + t < M) ? mark[row0 + t] : 0;   // >=0 => skip
  __syncthreads();
  {
    int r = t >> 4, cp = t & 15;
    int j = row0 + r;
    us8 hz;
    #pragma unroll
    for (int e = 0; e < 8; ++e) hz[e] = 0;
    if (j < M && mk[r] < 0) {
      const float4* h4 = (const float4*)(h_in + (size_t)j * Hc);
      const float4* c4 = (const float4*)(c_in + (size_t)j * Hc);
      float4 a0 = h4[cp * 2], a1 = h4[cp * 2 + 1];
      float4 b0 = c4[cp * 2], b1 = c4[cp * 2 + 1];
      ((float4*)(h_out + (size_t)j * Hc))[cp * 2] = a0;
      ((float4*)(h_out + (size_t)j * Hc))[cp * 2 + 1] = a1;
      ((float4*)(c_out + (size_t)j * Hc))[cp * 2] = b0;
      ((float4*)(c_out + (size_t)j * Hc))[cp * 2 + 1] = b1;
      us8 h8 = f2bf8(a0, a1);
      *(us8*)&H16x[(size_t)j * Hc + cp * 8] = h8;
      *(us8*)&C16x[(size_t)j * Hc + cp * 8] = f2bf8(b0, b1);
      hz = h8;
    }
    *(us8*)&zh[r * HP + cp * 8] = hz;
  }
  __syncthreads();

  f32x4 acc0 = (f32x4){0.f,0.f,0.f,0.f}, acc1 = acc0;
  const ushortT* zr = &zh[cl * HP + lg * 8];
  #pragma unroll
  for (int kf = 0; kf < 4; ++kf) {
    bf16x8 a = *(const bf16x8*)&zr[kf * 32];
    acc0 = __builtin_amdgcn_mfma_f32_16x16x32_bf16(a, *wh_frag(pack, 3, w*2+0, kf, lane), acc0, 0, 0, 0);
    acc1 = __builtin_amdgcn_mfma_f32_16x16x32_bf16(a, *wh_frag(pack, 3, w*2+1, kf, lane), acc1, 0, 0, 0);
  }
  __syncthreads();   // zh A-frag reads done; reuse zh for Hf roundtrip
  #pragma unroll
  for (int half = 0; half < 2; ++half) {
    int col = (w * 2 + half) * 16 + cl;
    f32x4 a_ = half ? acc1 : acc0;
    #pragma unroll
    for (int reg = 0; reg < 4; ++reg)
      zh[(lg * 4 + reg) * HP + col] = f2bf(a_[reg]);
  }
  __syncthreads();
  {
    int r = t >> 4, cp = t & 15;
    if (row0 + r < M && mk[r] < 0)
      *(us8*)&Hf16x[(size_t)(row0 + r) * Hc + cp * 8] = *(const us8*)&zh[r * HP + cp * 8];
  }
}

// ---- kernels 4/5: LSTM step with redirect + partial reuse ----
template<int MODE>
__global__ __launch_bounds__(256) void lstm8(
    const int* __restrict__ submess, const int* __restrict__ bgraph,
    const int* __restrict__ mark,
    ushortT* H16x, ushortT* C16x, ushortT* Hf16x,
    const ushortT* __restrict__ Xg, const ushortT* __restrict__ pack,
    ushortT* hsumNS, ushortT* cpartNS,
    float* __restrict__ dstH, float* __restrict__ dstC, int S, int M)
{
  __shared__ __align__(16) ushortT zs[16 * HSP];
  __shared__ __align__(16) ushortT pih[16 * EPH];
  __shared__ __align__(16) ushortT poh[16 * EPH];
  __shared__ __align__(16) ushortT puh[16 * EPH];
  __shared__ int nbj[16][Kc];
  __shared__ int msrow[16];

  const int t = threadIdx.x;
  const int row0 = blockIdx.x * 16;
  const int DUMMY = M + S;

  if (t < 128) {
    int r = t >> 3, k = t & 7;
    int s = row0 + r;
    int ms = (s < S) ? submess[s] : -1;
    if (k == 0) msrow[r] = ms;
    int j = DUMMY;
    if (ms >= 0) {
      int jj = bgraph[(size_t)ms * Kc + k];
      int m = mark[jj];
      j = (MODE == 0) ? (m >= 0 ? DUMMY : jj) : (m >= 0 ? M + m : DUMMY);
    }
    nbj[r][k] = j;
  }
  __syncthreads();

  {
    int r = t >> 4, cp = t & 15;
    int spos = row0 + r;
    float sum[8] = {0.f,0.f,0.f,0.f,0.f,0.f,0.f,0.f};
    if (MODE == 1 && spos < S) {
      us8 hs = *(const us8*)&hsumNS[(size_t)spos * Hc + cp * 8];
      #pragma unroll
      for (int e = 0; e < 8; ++e) sum[e] = bf2f(hs[e]);
    }
    #pragma unroll
    for (int k = 0; k < Kc; ++k) {
      int j = nbj[r][k];
      us8 v = *(const us8*)&H16x[(size_t)j * Hc + cp * 8];
      #pragma unroll
      for (int e = 0; e < 8; ++e) sum[e] += bf2f(v[e]);
    }
    us8 o8;
    #pragma unroll
    for (int e = 0; e < 8; ++e) o8[e] = f2bf(sum[e]);
    *(us8*)&zs[r * HSP + cp * 8] = o8;
    if (MODE == 0 && spos < S)
      *(us8*)&hsumNS[(size_t)spos * Hc + cp * 8] = o8;
  }
  __syncthreads();

  const int w = t >> 6, lane = t & 63, lg = lane >> 4, cl = lane & 15;

  f32x4 acc[6];
  #pragma unroll
  for (int i = 0; i < 6; ++i) acc[i] = (f32x4){0.f, 0.f, 0.f, 0.f};
  const ushortT* zrow = &zs[cl * HSP + lg * 8];
  #pragma unroll
  for (int kf = 0; kf < 4; ++kf) {
    bf16x8 a = *(const bf16x8*)&zrow[kf * 32];
    #pragma unroll
    for (int g = 0; g < 3; ++g)
      #pragma unroll
      for (int half = 0; half < 2; ++half)
        acc[g * 2 + half] = __builtin_amdgcn_mfma_f32_16x16x32_bf16(
            a, *wh_frag(pack, g, w * 2 + half, kf, lane), acc[g * 2 + half], 0, 0, 0);
  }

  #pragma unroll
  for (int half = 0; half < 2; ++half) {
    int col = (w * 2 + half) * 16 + cl;
    #pragma unroll
    for (int reg = 0; reg < 4; ++reg) {
      int row = lg * 4 + reg;
      pih[row * EPH + col] = f2bf(acc[0 + half][reg]);
      poh[row * EPH + col] = f2bf(acc[2 + half][reg]);
      puh[row * EPH + col] = f2bf(acc[4 + half][reg]);
    }
  }
  __syncthreads();

  {
    int r = t >> 4, cc = t & 15;
    int ms = msrow[r];
    int spos = row0 + r;
    const ushortT* xgr = Xg + (size_t)spos * 512 + cc * 8;
    us8 xi8 = *(const us8*)&xgr[0];
    us8 xo8 = *(const us8*)&xgr[128];
    us8 xu8 = *(const us8*)&xgr[256];
    us8 xf8 = *(const us8*)&xgr[384];
    us8 pi8 = *(const us8*)&pih[r * EPH + cc * 8];
    us8 po8 = *(const us8*)&poh[r * EPH + cc * 8];
    us8 pu8 = *(const us8*)&puh[r * EPH + cc * 8];
    float fx[8], ovv[8], iu[8], cn[8];
    #pragma unroll
    for (int e = 0; e < 8; ++e) {
      float iv = fsig(bf2f(xi8[e]) + bf2f(pi8[e]));
      float uv = ftanh(bf2f(xu8[e]) + bf2f(pu8[e]));
      ovv[e] = fsig(bf2f(xo8[e]) + bf2f(po8[e]));
      fx[e] = bf2f(xf8[e]);
      iu[e] = iv * uv;
      cn[e] = 0.f;
    }
    #pragma unroll
    for (int k = 0; k < Kc; ++k) {
      int j = nbj[r][k];
      us8 hf8 = *(const us8*)&Hf16x[(size_t)j * Hc + cc * 8];
      us8 cn8 = *(const us8*)&C16x[(size_t)j * Hc + cc * 8];
      #pragma unroll
      for (int e = 0; e < 8; ++e)
        cn[e] = fmaf(fsig(fx[e] + bf2f(hf8[e])), bf2f(cn8[e]), cn[e]);
    }
    float cacc[8];
    if (MODE == 1 && spos < S) {
      us8 cp8 = *(const us8*)&cpartNS[(size_t)spos * Hc + cc * 8];
      #pragma unroll
      for (int e = 0; e < 8; ++e) cacc[e] = iu[e] + cn[e] + bf2f(cp8[e]);
    } else {
      #pragma unroll
      for (int e = 0; e < 8; ++e) cacc[e] = iu[e] + cn[e];
    }
    float hv[8];
    #pragma unroll
    for (int e = 0; e < 8; ++e) hv[e] = ovv[e] * ftanh(cacc[e]);

    if (MODE == 0) {
      us8 h8, c8, cn16;
      #pragma unroll
      for (int e = 0; e < 8; ++e) {
        h8[e] = (spos < S) ? f2bf(hv[e]) : (ushortT)0;
        c8[e] = f2bf(cacc[e]);
        cn16[e] = f2bf(cn[e]);
      }
      if (spos < S) {
        *(us8*)&H16x[(size_t)(M + spos) * Hc + cc * 8] = h8;
        *(us8*)&C16x[(size_t)(M + spos) * Hc + cc * 8] = c8;
        *(us8*)&cpartNS[(size_t)spos * Hc + cc * 8] = cn16;
      }
      *(us8*)&zs[r * HSP + cc * 8] = h8;
    } else {
      if (ms >= 0) {
        float* dh = dstH + (size_t)ms * Hc + cc * 8;
        float* dc = dstC + (size_t)ms * Hc + cc * 8;
        *(float4*)&dh[0] = *(float4*)&hv[0];
        *(float4*)&dh[4] = *(float4*)&hv[4];
        *(float4*)&dc[0] = *(float4*)&cacc[0];
        *(float4*)&dc[4] = *(float4*)&cacc[4];
      }
    }
  }

  if (MODE == 0) {
    // ---- fused Hf tail; epilogue stores via pih roundtrip ----
    __syncthreads();
    f32x4 a0 = (f32x4){0.f,0.f,0.f,0.f}, a1 = a0;
    const ushortT* zr2 = &zs[cl * HSP + lg * 8];
    #pragma unroll
    for (int kf = 0; kf < 4; ++kf) {
      bf16x8 a = *(const bf16x8*)&zr2[kf * 32];
      a0 = __builtin_amdgcn_mfma_f32_16x16x32_bf16(a, *wh_frag(pack, 3, w*2+0, kf, lane), a0, 0, 0, 0);
      a1 = __builtin_amdgcn_mfma_f32_16x16x32_bf16(a, *wh_frag(pack, 3, w*2+1, kf, lane), a1, 0, 0, 0);
    }
    #pragma unroll
    for (int half = 0; half < 2; ++half) {
      int col = (w * 2 + half) * 16 + cl;
      f32x4 a_ = half ? a1 : a0;
      #pragma unroll
      for (int reg = 0; reg < 4; ++reg)
        pih[(lg * 4 + reg) * EPH + col] = f2bf(a_[reg]);
    }
    __syncthreads();
    {
      int r = t >> 4, cp = t & 15;
      int sp = row0 + r;
      if (sp < S)
        *(us8*)&Hf16x[(size_t)(M + sp) * Hc + cp * 8] = *(const us8*)&pih[r * EPH + cp * 8];
    }
  }
}

// ---------------- kernel 6: node readout || zero non-sub node rows ----------------
__global__ __launch_bounds__(256) void readout_zero(
    const float* __restrict__ fnode, const int* __restrict__ agraph,
    const int* __restrict__ subnode, const float* __restrict__ h_out,
    const ushortT* __restrict__ H16x, const int* __restrict__ mark,
    const int* __restrict__ nmark,
    const ushortT* __restrict__ packWn, const float* __restrict__ bn,
    float* __restrict__ node_buf, int Nsub, int num_nodes, int NB, int ZB)
{
  __shared__ __align__(16) ushortT z2[16 * ZP2];
  __shared__ int orow[16];
  __shared__ int jn[16][Kc];

  const int t = threadIdx.x;

  if ((int)blockIdx.x >= NB) {
    long total = (long)num_nodes * 16;
    float4 z; z.x = z.y = z.z = z.w = 0.f;
    for (long idx = (long)(blockIdx.x - NB) * 256 + t; idx < total; idx += (long)ZB * 256) {
      long v = idx >> 4;
      int cp = (int)(idx & 15);
      if (nmark[v] < 0) {
        ((float4*)(node_buf + (size_t)v * Hc))[cp * 2] = z;
        ((float4*)(node_buf + (size_t)v * Hc))[cp * 2 + 1] = z;
      }
    }
    return;
  }

  const int row0 = blockIdx.x * 16;
  if (t < 16) orow[t] = (row0 + t < Nsub) ? subnode[row0 + t] : -1;
  if (t >= 64 && t < 64 + 128) {
    int i = t - 64, r = i >> 3, k = i & 7;
    int v = row0 + r;
    int j = 0;
    if (v < Nsub) {
      j = agraph[(size_t)v * Kc + k];
      if (mark[j] >= 0) j = ~j;
    }
    jn[r][k] = j;
  }
  {
    int r = t >> 4, cp = t & 15;
    int v = row0 + r;
    const float4* fr = (v < Nsub) ? (const float4*)(fnode + (size_t)v * Hc) : nullptr;
    float4 v0, v1; v0.x = v0.y = v0.z = v0.w = 0.f; v1 = v0;
    if (fr) { v0 = fr[cp]; v1 = fr[cp + 16]; }
    *(us4*)&z2[r * ZP2 + cp * 4] = f2bf4(v0);
    *(us4*)&z2[r * ZP2 + 64 + cp * 4] = f2bf4(v1);
  }
  __syncthreads();
  {
    int r = t >> 4, cp = t & 15;
    float sum[8] = {0.f,0.f,0.f,0.f,0.f,0.f,0.f,0.f};
    #pragma unroll
    for (int k = 0; k < Kc; ++k) {
      int je = jn[r][k];
      if (je < 0) {
        int j = ~je;
        float4 p0 = ((const float4*)(h_out + (size_t)j * Hc))[cp * 2];
        float4 p1 = ((const float4*)(h_out + (size_t)j * Hc))[cp * 2 + 1];
        sum[0] += p0.x; sum[1] += p0.y; sum[2] += p0.z; sum[3] += p0.w;
        sum[4] += p1.x; sum[5] += p1.y; sum[6] += p1.z; sum[7] += p1.w;
      } else {
        us8 v = *(const us8*)&H16x[(size_t)je * Hc + cp * 8];
        #pragma unroll
        for (int e = 0; e < 8; ++e) sum[e] += bf2f(v[e]);
      }
    }
    us8 o8;
    #pragma unroll
    for (int e = 0; e < 8; ++e) o8[e] = f2bf(sum[e]);
    *(us8*)&z2[r * ZP2 + Hc + cp * 8] = o8;
  }
  __syncthreads();

  const int w = t >> 6, lane = t & 63;
  const int lg = lane >> 4, cl = lane & 15;

  f32x4 acc0 = (f32x4){0.f,0.f,0.f,0.f};
  f32x4 acc1 = (f32x4){0.f,0.f,0.f,0.f};
  const ushortT* zr = &z2[cl * ZP2 + lg * 8];
  #pragma unroll
  for (int kt = 0; kt < 8; ++kt) {
    bf16x8 a = *(const bf16x8*)&zr[kt * 32];
    bf16x8 b0 = *(const bf16x8*)&packWn[(size_t)(((w * 2 + 0) * 8 + kt) * 64 + lane) * 8];
    bf16x8 b1 = *(const bf16x8*)&packWn[(size_t)(((w * 2 + 1) * 8 + kt) * 64 + lane) * 8];
    acc0 = __builtin_amdgcn_mfma_f32_16x16x32_bf16(a, b0, acc0, 0, 0, 0);
    acc1 = __builtin_amdgcn_mfma_f32_16x16x32_bf16(a, b1, acc1, 0, 0, 0);
  }
  __syncthreads();   // z2 A-frag reads done; reuse as f32 output buffer
  float* zf = (float*)z2;   // [16][132] f32 = 8448 B
  #pragma unroll
  for (int half = 0; half < 2; ++half) {
    int col = (w * 2 + half) * 16 + cl;
    float bnv = bn[col];
    f32x4 a_ = half ? acc1 : acc0;
    #pragma unroll
    for (int reg = 0; reg < 4; ++reg)
      zf[(lg * 4 + reg) * 132 + col] = fmaxf(a_[reg] + bnv, 0.f);
  }
  __syncthreads();
  {
    int r = t >> 4, cc = t & 15;
    int o = orow[r];
    if (o >= 0) {
      float* dst = node_buf + (size_t)o * Hc + cc * 8;
      *(float4*)&dst[0] = *(const float4*)&zf[r * 132 + cc * 8];
      *(float4*)&dst[4] = *(const float4*)&zf[r * 132 + cc * 8 + 4];
    }
  }
}

// ---------------- launch ----------------
extern "C" void kernel_launch(void* const* d_in, const int* in_sizes, int n_in,
                              void* d_out, int out_size, void* d_ws, size_t ws_size,
                              hipStream_t stream) {
  const float* fnode   = (const float*)d_in[0];
  const float* fmess   = (const float*)d_in[1];
  const int*   agraph  = (const int*)d_in[2];
  const int*   bgraph  = (const int*)d_in[3];
  const float* h_in    = (const float*)d_in[4];
  const float* c_in    = (const float*)d_in[5];
  const int*   submess = (const int*)d_in[6];
  const int*   subnode = (const int*)d_in[7];
  const float* Wi = (const float*)d_in[9];
  const float* bi = (const float*)d_in[10];
  const float* Wo = (const float*)d_in[11];
  const float* bo = (const float*)d_in[12];
  const float* Wf = (const float*)d_in[13];
  const float* bf_ = (const float*)d_in[14];
  const float* Wu = (const float*)d_in[15];
  const float* bu = (const float*)d_in[16];
  const float* Wn = (const float*)d_in[17];
  const float* bn = (const float*)d_in[18];

  const int S    = in_sizes[6];
  const int Nsub = in_sizes[2] / Kc;
  const int M    = in_sizes[4] / Hc;
  const int num_nodes = out_size / Hc - 2 * M;

  float* node_buf = (float*)d_out;
  float* h_out = node_buf + (size_t)num_nodes * Hc;
  float* c_out = h_out + (size_t)M * Hc;

  const int lblocks = (S + 15) / 16;

  // ws: mark[M] | nmark[num_nodes] | pack | Hf16x | C16x | H16x (each M+S+1 rows) | Xg
  int* mark = (int*)d_ws;
  size_t off = (((size_t)M * sizeof(int)) + 255) & ~(size_t)255;
  int* nmark = (int*)((char*)d_ws + off);
  off += (((size_t)num_nodes * sizeof(int)) + 255) & ~(size_t)255;
  ushortT* pack = (ushortT*)((char*)d_ws + off);
  off += (((size_t)(GATE_FRAGS + WN_FRAGS) * 8 * sizeof(ushortT)) + 255) & ~(size_t)255;
  size_t shadow_bytes = (((size_t)(M + S + 1) * Hc * sizeof(ushortT)) + 255) & ~(size_t)255;
  ushortT* Hf16x = (ushortT*)((char*)d_ws + off); off += shadow_bytes;
  ushortT* C16x  = (ushortT*)((char*)d_ws + off); off += shadow_bytes;
  ushortT* H16x  = (ushortT*)((char*)d_ws + off); off += shadow_bytes;
  ushortT* Xg    = (ushortT*)((char*)d_ws + off);
  ushortT* packWn = pack + (size_t)GATE_FRAGS * 8;
  ushortT* cpartNS = (ushortT*)node_buf;
  ushortT* hsumNS  = cpartNS + (size_t)S * Hc;

  // 1. init marks
  int initN = (M > num_nodes) ? M : num_nodes;
  hipLaunchKernelGGL(marks_init, dim3((initN + 255) / 256), dim3(256), 0, stream,
                     mark, M, nmark, num_nodes);
  // 2. set marks || repack
  {
    int SB = (S + 255) / 256;
    int RB = (GATE_FRAGS + WN_FRAGS + 255) / 256;
    hipLaunchKernelGGL(set_repack, dim3(SB + RB), dim3(256), 0, stream,
                       submess, subnode, S, mark, nmark, Wi, Wo, Wu, Wf, Wn, pack, SB);
  }
  // 3. xg || stage+Hf tiles (xg blocks first: LPT scheduling)
  {
    int XB = lblocks;
    int SB2 = (M + 15) / 16;
    hipLaunchKernelGGL(xg_stage_hf, dim3(XB + SB2), dim3(256), 0, stream,
                       fmess, submess, pack, bi, bo, bu, bf_, Xg,
                       h_in, c_in, mark, h_out, c_out, H16x, C16x, Hf16x,
                       M, S, XB);
  }
  // 4. iter 0 (fused Hf tail)
  hipLaunchKernelGGL(lstm8<0>, dim3(lblocks), dim3(256), 0, stream,
      submess, bgraph, mark, H16x, C16x, Hf16x, Xg, pack,
      hsumNS, cpartNS, h_out, c_out, S, M);
  // 5. iter 1
  hipLaunchKernelGGL(lstm8<1>, dim3(lblocks), dim3(256), 0, stream,
      submess, bgraph, mark, H16x, C16x, Hf16x, Xg, pack,
      hsumNS, cpartNS, h_out, c_out, S, M);
  // 6. readout || zero non-sub node rows
  {
    int NB = (Nsub + 15) / 16;
    int ZB = 512;
    hipLaunchKernelGGL(readout_zero, dim3(NB + ZB), dim3(256), 0, stream,
        fnode, agraph, subnode, h_out, H16x, mark, nmark, packWn, bn,
        node_buf, Nsub, num_nodes, NB, ZB);
  }
}

// Round 13
// 276.644 us; speedup vs baseline: 2.2532x; 1.0071x over previous
//
#include <hip/hip_runtime.h>
#include <cstdint>
#include <cstddef>

#define Hc   128
#define INc  256
#define Kc   8
#define HP   136          // stage/hf staging row pad (ushorts)
#define HSP  136          // lstm h_sum/h_new staging row pad (ushorts)
#define EPH  136          // lstm gate-partial arrays row pad (ushorts)
#define ZP2  264          // node/x staging row pad (ushorts)
#define XOP  520          // xg output LDS row pad (ushorts)
#define HCS  384          // HCF interleaved row stride (ushorts): [H|C|F]

typedef unsigned short ushortT;
typedef __attribute__((ext_vector_type(8))) short bf16x8;
typedef __attribute__((ext_vector_type(4))) float f32x4;
typedef __attribute__((ext_vector_type(4))) unsigned short us4;
typedef __attribute__((ext_vector_type(8))) unsigned short us8;

__device__ __forceinline__ float fsig(float x) {
  return __builtin_amdgcn_rcpf(1.f + __expf(-x));
}
__device__ __forceinline__ float ftanh(float x) {
  float e = __expf(2.f * fminf(x, 15.f));
  return (e - 1.f) * __builtin_amdgcn_rcpf(e + 1.f);
}
__device__ __forceinline__ ushortT f2bf(float f) {
  unsigned u = __builtin_bit_cast(unsigned, f);
  unsigned r = (u + 0x7fffu + ((u >> 16) & 1u)) >> 16;
  return (ushortT)r;
}
__device__ __forceinline__ us4 f2bf4(float4 v) {
  us4 o; o[0] = f2bf(v.x); o[1] = f2bf(v.y); o[2] = f2bf(v.z); o[3] = f2bf(v.w);
  return o;
}
__device__ __forceinline__ us8 f2bf8(float4 a, float4 b) {
  us8 o;
  o[0] = f2bf(a.x); o[1] = f2bf(a.y); o[2] = f2bf(a.z); o[3] = f2bf(a.w);
  o[4] = f2bf(b.x); o[5] = f2bf(b.y); o[6] = f2bf(b.z); o[7] = f2bf(b.w);
  return o;
}
__device__ __forceinline__ float bf2f(ushortT u) {
  return __builtin_bit_cast(float, (unsigned)u << 16);
}

#define GATE_FRAGS (4*8*12*64)
#define WN_FRAGS   (8*8*64)

// ---------------- kernel 1: init marks ----------------
__global__ void marks_init(int* __restrict__ mark, int M, int* __restrict__ nmark, int NN) {
  int i = blockIdx.x * blockDim.x + threadIdx.x;
  if (i < M) mark[i] = -1;
  if (i < NN) nmark[i] = -1;
}

// ---------------- kernel 2: set marks || repack weights ----------------
__global__ void set_repack(const int* __restrict__ submess, const int* __restrict__ subnode,
                           int S, int* __restrict__ mark, int* __restrict__ nmark,
                           const float* __restrict__ Wi, const float* __restrict__ Wo,
                           const float* __restrict__ Wu, const float* __restrict__ Wf,
                           const float* __restrict__ Wn, ushortT* __restrict__ pack, int SB) {
  if ((int)blockIdx.x < SB) {
    int i = blockIdx.x * 256 + threadIdx.x;
    if (i < S) { mark[submess[i]] = i; nmark[subnode[i]] = i; }
    return;
  }
  int idx = (blockIdx.x - SB) * 256 + threadIdx.x;
  if (idx < GATE_FRAGS) {
    int lane = idx & 63;
    int kt = (idx >> 6) % 12;
    int gc = idx / (64 * 12);
    int c = gc & 7, g = gc >> 3;
    const float* W = (g == 0) ? Wi : (g == 1) ? Wo : (g == 2) ? Wu : Wf;
    int k0 = kt * 32 + (lane >> 4) * 8;
    int col = c * 16 + (lane & 15);
    ushortT* dst = pack + (size_t)idx * 8;
    #pragma unroll
    for (int j = 0; j < 8; ++j) dst[j] = f2bf(W[(size_t)(k0 + j) * Hc + col]);
  } else if (idx < GATE_FRAGS + WN_FRAGS) {
    int i2 = idx - GATE_FRAGS;
    int lane = i2 & 63;
    int kt = (i2 >> 6) & 7;
    int c = i2 >> 9;
    int k0 = kt * 32 + (lane >> 4) * 8;
    int col = c * 16 + (lane & 15);
    ushortT* dst = pack + (size_t)GATE_FRAGS * 8 + (size_t)i2 * 8;
    #pragma unroll
    for (int j = 0; j < 8; ++j) dst[j] = f2bf(Wn[(size_t)(k0 + j) * Hc + col]);
  }
}

// W*2 B-fragment (h-part rows 256..383 of gate g => kt slots 8..11)
__device__ __forceinline__ const bf16x8* wh_frag(const ushortT* pack, int g, int cw, int kf, int lane) {
  return (const bf16x8*)&pack[(size_t)(((g * 8 + cw) * 12 + (8 + kf)) * 64 + lane) * 8];
}

// ---------------- kernel 3: xg_gemm (32-row tiles, blocks [0,XB)) || stage+Hf ----
__global__ __launch_bounds__(256) void xg_stage_hf(
    const float* __restrict__ fmess, const int* __restrict__ submess,
    const ushortT* __restrict__ pack,
    const float* __restrict__ bi, const float* __restrict__ bo,
    const float* __restrict__ bu, const float* __restrict__ bfb,
    ushortT* __restrict__ Xg,
    const float* __restrict__ h_in, const float* __restrict__ c_in,
    const int* __restrict__ mark,
    float* __restrict__ h_out, float* __restrict__ c_out,
    ushortT* __restrict__ HCF,
    int M, int S, int XB)
{
  __shared__ __align__(16) ushortT xs[32 * ZP2];   // 16896 B; reused for outputs
  __shared__ int aux[32];
  const int t = threadIdx.x;
  const int w = t >> 6, lane = t & 63, lg = lane >> 4, cl = lane & 15;

  if ((int)blockIdx.x < XB) {
    // ---- xg part: 32 rows, 2 M-subtiles per wave (B-frag reuse x2) ----
    const int row0 = blockIdx.x * 32;
    if (t < 32) aux[t] = (row0 + t < S) ? submess[row0 + t] : -1;
    __syncthreads();
    #pragma unroll
    for (int rr = 0; rr < 2; ++rr) {
      int r = (t >> 4) + rr * 16, cp = t & 15;
      int ms = aux[r];
      const float4* xr = (ms >= 0) ? (const float4*)(fmess + (size_t)ms * INc) : nullptr;
      #pragma unroll
      for (int q = 0; q < 4; ++q) {
        int slot = cp + q * 16;
        float4 v;
        if (xr) v = xr[slot]; else { v.x = v.y = v.z = v.w = 0.f; }
        *(us4*)&xs[r * ZP2 + slot * 4] = f2bf4(v);
      }
    }
    __syncthreads();

    f32x4 acc0[8], acc1[8];
    #pragma unroll
    for (int i = 0; i < 8; ++i) {
      acc0[i] = (f32x4){0.f, 0.f, 0.f, 0.f};
      acc1[i] = (f32x4){0.f, 0.f, 0.f, 0.f};
    }
    const ushortT* zrA = &xs[cl * ZP2 + lg * 8];
    const ushortT* zrB = &xs[(16 + cl) * ZP2 + lg * 8];
    #pragma unroll
    for (int kt = 0; kt < 8; ++kt) {
      bf16x8 a0 = *(const bf16x8*)&zrA[kt * 32];
      bf16x8 a1 = *(const bf16x8*)&zrB[kt * 32];
      #pragma unroll
      for (int c = 0; c < 8; ++c) {
        bf16x8 b = *(const bf16x8*)&pack[(size_t)(((w * 8 + c) * 12 + kt) * 64 + lane) * 8];
        acc0[c] = __builtin_amdgcn_mfma_f32_16x16x32_bf16(a0, b, acc0[c], 0, 0, 0);
        acc1[c] = __builtin_amdgcn_mfma_f32_16x16x32_bf16(a1, b, acc1[c], 0, 0, 0);
      }
    }
    __syncthreads();   // xs input reads done; reuse as output staging [16][XOP]
    const float* bias = (w == 0) ? bi : (w == 1) ? bo : (w == 2) ? bu : bfb;
    #pragma unroll
    for (int mt = 0; mt < 2; ++mt) {
      #pragma unroll
      for (int c = 0; c < 8; ++c) {
        int col = c * 16 + cl;
        float bv = bias[col];
        #pragma unroll
        for (int reg = 0; reg < 4; ++reg) {
          float v = (mt ? acc1[c][reg] : acc0[c][reg]) + bv;
          xs[(lg * 4 + reg) * XOP + w * 128 + col] = f2bf(v);
        }
      }
      __syncthreads();
      {
        int r = t >> 4, cc = t & 15;
        int s = row0 + mt * 16 + r;
        if (s < S) {
          const ushortT* src = &xs[r * XOP + cc * 32];
          ushortT* dst = &Xg[(size_t)s * 512 + cc * 32];
          *(us8*)&dst[0]  = *(const us8*)&src[0];
          *(us8*)&dst[8]  = *(const us8*)&src[8];
          *(us8*)&dst[16] = *(const us8*)&src[16];
          *(us8*)&dst[24] = *(const us8*)&src[24];
        }
      }
      __syncthreads();
    }
    return;
  }

  // ---- stage + Hf tile part: 16 rows; writes interleaved HCF ----
  ushortT* zh = xs;   // [16][HP]
  int* mk = aux;
  const int row0 = (blockIdx.x - XB) * 16;

  if (blockIdx.x == XB && t < 48) {    // zero DUMMY row (M+S): 384 ushorts = 48 us8
    us8 z;
    #pragma unroll
    for (int e = 0; e < 8; ++e) z[e] = 0;
    *(us8*)&HCF[(size_t)(M + S) * HCS + t * 8] = z;
  }
  if (t < 16) mk[t] = (row0 + t < M) ? mark[row0 + t] : 0;   // >=0 => skip
  __syncthreads();
  {
    int r = t >> 4, cp = t & 15;
    int j = row0 + r;
    us8 hz;
    #pragma unroll
    for (int e = 0; e < 8; ++e) hz[e] = 0;
    if (j < M && mk[r] < 0) {
      const float4* h4 = (const float4*)(h_in + (size_t)j * Hc);
      const float4* c4 = (const float4*)(c_in + (size_t)j * Hc);
      float4 a0 = h4[cp * 2], a1 = h4[cp * 2 + 1];
      float4 b0 = c4[cp * 2], b1 = c4[cp * 2 + 1];
      ((float4*)(h_out + (size_t)j * Hc))[cp * 2] = a0;
      ((float4*)(h_out + (size_t)j * Hc))[cp * 2 + 1] = a1;
      ((float4*)(c_out + (size_t)j * Hc))[cp * 2] = b0;
      ((float4*)(c_out + (size_t)j * Hc))[cp * 2 + 1] = b1;
      us8 h8 = f2bf8(a0, a1);
      *(us8*)&HCF[(size_t)j * HCS + cp * 8] = h8;
      *(us8*)&HCF[(size_t)j * HCS + 128 + cp * 8] = f2bf8(b0, b1);
      hz = h8;
    }
    *(us8*)&zh[r * HP + cp * 8] = hz;
  }
  __syncthreads();

  f32x4 acc0 = (f32x4){0.f,0.f,0.f,0.f}, acc1 = acc0;
  const ushortT* zr = &zh[cl * HP + lg * 8];
  #pragma unroll
  for (int kf = 0; kf < 4; ++kf) {
    bf16x8 a = *(const bf16x8*)&zr[kf * 32];
    acc0 = __builtin_amdgcn_mfma_f32_16x16x32_bf16(a, *wh_frag(pack, 3, w*2+0, kf, lane), acc0, 0, 0, 0);
    acc1 = __builtin_amdgcn_mfma_f32_16x16x32_bf16(a, *wh_frag(pack, 3, w*2+1, kf, lane), acc1, 0, 0, 0);
  }
  __syncthreads();   // zh A-frag reads done; reuse for Hf roundtrip
  #pragma unroll
  for (int half = 0; half < 2; ++half) {
    int col = (w * 2 + half) * 16 + cl;
    f32x4 a_ = half ? acc1 : acc0;
    #pragma unroll
    for (int reg = 0; reg < 4; ++reg)
      zh[(lg * 4 + reg) * HP + col] = f2bf(a_[reg]);
  }
  __syncthreads();
  {
    int r = t >> 4, cp = t & 15;
    if (row0 + r < M && mk[r] < 0)
      *(us8*)&HCF[(size_t)(row0 + r) * HCS + 256 + cp * 8] = *(const us8*)&zh[r * HP + cp * 8];
  }
}

// ---- kernels 4/5: LSTM step over interleaved HCF shadows ----
// MODE 0: sub neighbors -> DUMMY zero row. Writes HCF[M+spos] H/C, partials,
//         fused Hf tail -> HCF[M+spos].F.
// MODE 1: sub -> M+mark, non-sub -> DUMMY; seeds with saved partials;
//         writes final f32 h_out/c_out.
template<int MODE>
__global__ __launch_bounds__(256) void lstm8(
    const int* __restrict__ submess, const int* __restrict__ bgraph,
    const int* __restrict__ mark,
    ushortT* HCF,
    const ushortT* __restrict__ Xg, const ushortT* __restrict__ pack,
    ushortT* hsumNS, ushortT* cpartNS,
    float* __restrict__ dstH, float* __restrict__ dstC, int S, int M)
{
  __shared__ __align__(16) ushortT zs[16 * HSP];
  __shared__ __align__(16) ushortT pih[16 * EPH];
  __shared__ __align__(16) ushortT poh[16 * EPH];
  __shared__ __align__(16) ushortT puh[16 * EPH];
  __shared__ int nbj[16][Kc];
  __shared__ int msrow[16];

  const int t = threadIdx.x;
  const int row0 = blockIdx.x * 16;
  const int DUMMY = M + S;

  if (t < 128) {
    int r = t >> 3, k = t & 7;
    int s = row0 + r;
    int ms = (s < S) ? submess[s] : -1;
    if (k == 0) msrow[r] = ms;
    int j = DUMMY;
    if (ms >= 0) {
      int jj = bgraph[(size_t)ms * Kc + k];
      int m = mark[jj];
      j = (MODE == 0) ? (m >= 0 ? DUMMY : jj) : (m >= 0 ? M + m : DUMMY);
    }
    nbj[r][k] = j;
  }
  __syncthreads();

  {
    int r = t >> 4, cp = t & 15;
    int spos = row0 + r;
    float sum[8] = {0.f,0.f,0.f,0.f,0.f,0.f,0.f,0.f};
    if (MODE == 1 && spos < S) {
      us8 hs = *(const us8*)&hsumNS[(size_t)spos * Hc + cp * 8];
      #pragma unroll
      for (int e = 0; e < 8; ++e) sum[e] = bf2f(hs[e]);
    }
    #pragma unroll
    for (int k = 0; k < Kc; ++k) {
      int j = nbj[r][k];
      us8 v = *(const us8*)&HCF[(size_t)j * HCS + cp * 8];
      #pragma unroll
      for (int e = 0; e < 8; ++e) sum[e] += bf2f(v[e]);
    }
    us8 o8;
    #pragma unroll
    for (int e = 0; e < 8; ++e) o8[e] = f2bf(sum[e]);
    *(us8*)&zs[r * HSP + cp * 8] = o8;
    if (MODE == 0 && spos < S)
      *(us8*)&hsumNS[(size_t)spos * Hc + cp * 8] = o8;
  }
  __syncthreads();

  const int w = t >> 6, lane = t & 63, lg = lane >> 4, cl = lane & 15;

  f32x4 acc[6];
  #pragma unroll
  for (int i = 0; i < 6; ++i) acc[i] = (f32x4){0.f, 0.f, 0.f, 0.f};
  const ushortT* zrow = &zs[cl * HSP + lg * 8];
  #pragma unroll
  for (int kf = 0; kf < 4; ++kf) {
    bf16x8 a = *(const bf16x8*)&zrow[kf * 32];
    #pragma unroll
    for (int g = 0; g < 3; ++g)
      #pragma unroll
      for (int half = 0; half < 2; ++half)
        acc[g * 2 + half] = __builtin_amdgcn_mfma_f32_16x16x32_bf16(
            a, *wh_frag(pack, g, w * 2 + half, kf, lane), acc[g * 2 + half], 0, 0, 0);
  }

  #pragma unroll
  for (int half = 0; half < 2; ++half) {
    int col = (w * 2 + half) * 16 + cl;
    #pragma unroll
    for (int reg = 0; reg < 4; ++reg) {
      int row = lg * 4 + reg;
      pih[row * EPH + col] = f2bf(acc[0 + half][reg]);
      poh[row * EPH + col] = f2bf(acc[2 + half][reg]);
      puh[row * EPH + col] = f2bf(acc[4 + half][reg]);
    }
  }
  __syncthreads();

  {
    int r = t >> 4, cc = t & 15;
    int ms = msrow[r];
    int spos = row0 + r;
    const ushortT* xgr = Xg + (size_t)spos * 512 + cc * 8;
    us8 xi8 = *(const us8*)&xgr[0];
    us8 xo8 = *(const us8*)&xgr[128];
    us8 xu8 = *(const us8*)&xgr[256];
    us8 xf8 = *(const us8*)&xgr[384];
    us8 pi8 = *(const us8*)&pih[r * EPH + cc * 8];
    us8 po8 = *(const us8*)&poh[r * EPH + cc * 8];
    us8 pu8 = *(const us8*)&puh[r * EPH + cc * 8];
    float fx[8], ovv[8], iu[8], cn[8];
    #pragma unroll
    for (int e = 0; e < 8; ++e) {
      float iv = fsig(bf2f(xi8[e]) + bf2f(pi8[e]));
      float uv = ftanh(bf2f(xu8[e]) + bf2f(pu8[e]));
      ovv[e] = fsig(bf2f(xo8[e]) + bf2f(po8[e]));
      fx[e] = bf2f(xf8[e]);
      iu[e] = iv * uv;
      cn[e] = 0.f;
    }
    #pragma unroll
    for (int k = 0; k < Kc; ++k) {
      int j = nbj[r][k];
      us8 hf8 = *(const us8*)&HCF[(size_t)j * HCS + 256 + cc * 8];
      us8 cn8 = *(const us8*)&HCF[(size_t)j * HCS + 128 + cc * 8];
      #pragma unroll
      for (int e = 0; e < 8; ++e)
        cn[e] = fmaf(fsig(fx[e] + bf2f(hf8[e])), bf2f(cn8[e]), cn[e]);
    }
    float cacc[8];
    if (MODE == 1 && spos < S) {
      us8 cp8 = *(const us8*)&cpartNS[(size_t)spos * Hc + cc * 8];
      #pragma unroll
      for (int e = 0; e < 8; ++e) cacc[e] = iu[e] + cn[e] + bf2f(cp8[e]);
    } else {
      #pragma unroll
      for (int e = 0; e < 8; ++e) cacc[e] = iu[e] + cn[e];
    }
    float hv[8];
    #pragma unroll
    for (int e = 0; e < 8; ++e) hv[e] = ovv[e] * ftanh(cacc[e]);

    if (MODE == 0) {
      us8 h8, c8, cn16;
      #pragma unroll
      for (int e = 0; e < 8; ++e) {
        h8[e] = (spos < S) ? f2bf(hv[e]) : (ushortT)0;
        c8[e] = f2bf(cacc[e]);
        cn16[e] = f2bf(cn[e]);
      }
      if (spos < S) {
        *(us8*)&HCF[(size_t)(M + spos) * HCS + cc * 8] = h8;
        *(us8*)&HCF[(size_t)(M + spos) * HCS + 128 + cc * 8] = c8;
        *(us8*)&cpartNS[(size_t)spos * Hc + cc * 8] = cn16;
      }
      *(us8*)&zs[r * HSP + cc * 8] = h8;
    } else {
      if (ms >= 0) {
        float* dh = dstH + (size_t)ms * Hc + cc * 8;
        float* dc = dstC + (size_t)ms * Hc + cc * 8;
        *(float4*)&dh[0] = *(float4*)&hv[0];
        *(float4*)&dh[4] = *(float4*)&hv[4];
        *(float4*)&dc[0] = *(float4*)&cacc[0];
        *(float4*)&dc[4] = *(float4*)&cacc[4];
      }
    }
  }

  if (MODE == 0) {
    // ---- fused Hf tail; stores via pih roundtrip -> HCF[M+sp].F ----
    __syncthreads();
    f32x4 a0 = (f32x4){0.f,0.f,0.f,0.f}, a1 = a0;
    const ushortT* zr2 = &zs[cl * HSP + lg * 8];
    #pragma unroll
    for (int kf = 0; kf < 4; ++kf) {
      bf16x8 a = *(const bf16x8*)&zr2[kf * 32];
      a0 = __builtin_amdgcn_mfma_f32_16x16x32_bf16(a, *wh_frag(pack, 3, w*2+0, kf, lane), a0, 0, 0, 0);
      a1 = __builtin_amdgcn_mfma_f32_16x16x32_bf16(a, *wh_frag(pack, 3, w*2+1, kf, lane), a1, 0, 0, 0);
    }
    #pragma unroll
    for (int half = 0; half < 2; ++half) {
      int col = (w * 2 + half) * 16 + cl;
      f32x4 a_ = half ? a1 : a0;
      #pragma unroll
      for (int reg = 0; reg < 4; ++reg)
        pih[(lg * 4 + reg) * EPH + col] = f2bf(a_[reg]);
    }
    __syncthreads();
    {
      int r = t >> 4, cp = t & 15;
      int sp = row0 + r;
      if (sp < S)
        *(us8*)&HCF[(size_t)(M + sp) * HCS + 256 + cp * 8] = *(const us8*)&pih[r * EPH + cp * 8];
    }
  }
}

// ---------------- kernel 6: node readout || zero non-sub node rows ----------------
__global__ __launch_bounds__(256) void readout_zero(
    const float* __restrict__ fnode, const int* __restrict__ agraph,
    const int* __restrict__ subnode, const float* __restrict__ h_out,
    const ushortT* __restrict__ HCF, const int* __restrict__ mark,
    const int* __restrict__ nmark,
    const ushortT* __restrict__ packWn, const float* __restrict__ bn,
    float* __restrict__ node_buf, int Nsub, int num_nodes, int NB, int ZB)
{
  __shared__ __align__(16) ushortT z2[16 * ZP2];
  __shared__ int orow[16];
  __shared__ int jn[16][Kc];

  const int t = threadIdx.x;

  if ((int)blockIdx.x >= NB) {
    long total = (long)num_nodes * 16;
    float4 z; z.x = z.y = z.z = z.w = 0.f;
    for (long idx = (long)(blockIdx.x - NB) * 256 + t; idx < total; idx += (long)ZB * 256) {
      long v = idx >> 4;
      int cp = (int)(idx & 15);
      if (nmark[v] < 0) {
        ((float4*)(node_buf + (size_t)v * Hc))[cp * 2] = z;
        ((float4*)(node_buf + (size_t)v * Hc))[cp * 2 + 1] = z;
      }
    }
    return;
  }

  const int row0 = blockIdx.x * 16;
  if (t < 16) orow[t] = (row0 + t < Nsub) ? subnode[row0 + t] : -1;
  if (t >= 64 && t < 64 + 128) {
    int i = t - 64, r = i >> 3, k = i & 7;
    int v = row0 + r;
    int j = 0;
    if (v < Nsub) {
      j = agraph[(size_t)v * Kc + k];
      if (mark[j] >= 0) j = ~j;   // sub message: gather f32 from h_out
    }
    jn[r][k] = j;
  }
  {
    int r = t >> 4, cp = t & 15;
    int v = row0 + r;
    const float4* fr = (v < Nsub) ? (const float4*)(fnode + (size_t)v * Hc) : nullptr;
    float4 v0, v1; v0.x = v0.y = v0.z = v0.w = 0.f; v1 = v0;
    if (fr) { v0 = fr[cp]; v1 = fr[cp + 16]; }
    *(us4*)&z2[r * ZP2 + cp * 4] = f2bf4(v0);
    *(us4*)&z2[r * ZP2 + 64 + cp * 4] = f2bf4(v1);
  }
  __syncthreads();
  {
    int r = t >> 4, cp = t & 15;
    float sum[8] = {0.f,0.f,0.f,0.f,0.f,0.f,0.f,0.f};
    #pragma unroll
    for (int k = 0; k < Kc; ++k) {
      int je = jn[r][k];
      if (je < 0) {
        int j = ~je;
        float4 p0 = ((const float4*)(h_out + (size_t)j * Hc))[cp * 2];
        float4 p1 = ((const float4*)(h_out + (size_t)j * Hc))[cp * 2 + 1];
        sum[0] += p0.x; sum[1] += p0.y; sum[2] += p0.z; sum[3] += p0.w;
        sum[4] += p1.x; sum[5] += p1.y; sum[6] += p1.z; sum[7] += p1.w;
      } else {
        us8 v = *(const us8*)&HCF[(size_t)je * HCS + cp * 8];
        #pragma unroll
        for (int e = 0; e < 8; ++e) sum[e] += bf2f(v[e]);
      }
    }
    us8 o8;
    #pragma unroll
    for (int e = 0; e < 8; ++e) o8[e] = f2bf(sum[e]);
    *(us8*)&z2[r * ZP2 + Hc + cp * 8] = o8;
  }
  __syncthreads();

  const int w = t >> 6, lane = t & 63;
  const int lg = lane >> 4, cl = lane & 15;

  f32x4 acc0 = (f32x4){0.f,0.f,0.f,0.f};
  f32x4 acc1 = (f32x4){0.f,0.f,0.f,0.f};
  const ushortT* zr = &z2[cl * ZP2 + lg * 8];
  #pragma unroll
  for (int kt = 0; kt < 8; ++kt) {
    bf16x8 a = *(const bf16x8*)&zr[kt * 32];
    bf16x8 b0 = *(const bf16x8*)&packWn[(size_t)(((w * 2 + 0) * 8 + kt) * 64 + lane) * 8];
    bf16x8 b1 = *(const bf16x8*)&packWn[(size_t)(((w * 2 + 1) * 8 + kt) * 64 + lane) * 8];
    acc0 = __builtin_amdgcn_mfma_f32_16x16x32_bf16(a, b0, acc0, 0, 0, 0);
    acc1 = __builtin_amdgcn_mfma_f32_16x16x32_bf16(a, b1, acc1, 0, 0, 0);
  }
  __syncthreads();   // z2 A-frag reads done; reuse as f32 output buffer
  float* zf = (float*)z2;   // [16][132] f32
  #pragma unroll
  for (int half = 0; half < 2; ++half) {
    int col = (w * 2 + half) * 16 + cl;
    float bnv = bn[col];
    f32x4 a_ = half ? acc1 : acc0;
    #pragma unroll
    for (int reg = 0; reg < 4; ++reg)
      zf[(lg * 4 + reg) * 132 + col] = fmaxf(a_[reg] + bnv, 0.f);
  }
  __syncthreads();
  {
    int r = t >> 4, cc = t & 15;
    int o = orow[r];
    if (o >= 0) {
      float* dst = node_buf + (size_t)o * Hc + cc * 8;
      *(float4*)&dst[0] = *(const float4*)&zf[r * 132 + cc * 8];
      *(float4*)&dst[4] = *(const float4*)&zf[r * 132 + cc * 8 + 4];
    }
  }
}

// ---------------- launch ----------------
extern "C" void kernel_launch(void* const* d_in, const int* in_sizes, int n_in,
                              void* d_out, int out_size, void* d_ws, size_t ws_size,
                              hipStream_t stream) {
  const float* fnode   = (const float*)d_in[0];
  const float* fmess   = (const float*)d_in[1];
  const int*   agraph  = (const int*)d_in[2];
  const int*   bgraph  = (const int*)d_in[3];
  const float* h_in    = (const float*)d_in[4];
  const float* c_in    = (const float*)d_in[5];
  const int*   submess = (const int*)d_in[6];
  const int*   subnode = (const int*)d_in[7];
  const float* Wi = (const float*)d_in[9];
  const float* bi = (const float*)d_in[10];
  const float* Wo = (const float*)d_in[11];
  const float* bo = (const float*)d_in[12];
  const float* Wf = (const float*)d_in[13];
  const float* bf_ = (const float*)d_in[14];
  const float* Wu = (const float*)d_in[15];
  const float* bu = (const float*)d_in[16];
  const float* Wn = (const float*)d_in[17];
  const float* bn = (const float*)d_in[18];

  const int S    = in_sizes[6];
  const int Nsub = in_sizes[2] / Kc;
  const int M    = in_sizes[4] / Hc;
  const int num_nodes = out_size / Hc - 2 * M;

  float* node_buf = (float*)d_out;
  float* h_out = node_buf + (size_t)num_nodes * Hc;
  float* c_out = h_out + (size_t)M * Hc;

  const int lblocks = (S + 15) / 16;

  // ws: mark[M] | nmark[num_nodes] | pack | HCF[(M+S+1)*384] | Xg[S*512]
  int* mark = (int*)d_ws;
  size_t off = (((size_t)M * sizeof(int)) + 255) & ~(size_t)255;
  int* nmark = (int*)((char*)d_ws + off);
  off += (((size_t)num_nodes * sizeof(int)) + 255) & ~(size_t)255;
  ushortT* pack = (ushortT*)((char*)d_ws + off);
  off += (((size_t)(GATE_FRAGS + WN_FRAGS) * 8 * sizeof(ushortT)) + 255) & ~(size_t)255;
  ushortT* HCF = (ushortT*)((char*)d_ws + off);
  off += (((size_t)(M + S + 1) * HCS * sizeof(ushortT)) + 255) & ~(size_t)255;
  ushortT* Xg = (ushortT*)((char*)d_ws + off);
  ushortT* packWn = pack + (size_t)GATE_FRAGS * 8;
  ushortT* cpartNS = (ushortT*)node_buf;
  ushortT* hsumNS  = cpartNS + (size_t)S * Hc;

  // 1. init marks
  int initN = (M > num_nodes) ? M : num_nodes;
  hipLaunchKernelGGL(marks_init, dim3((initN + 255) / 256), dim3(256), 0, stream,
                     mark, M, nmark, num_nodes);
  // 2. set marks || repack
  {
    int SB = (S + 255) / 256;
    int RB = (GATE_FRAGS + WN_FRAGS + 255) / 256;
    hipLaunchKernelGGL(set_repack, dim3(SB + RB), dim3(256), 0, stream,
                       submess, subnode, S, mark, nmark, Wi, Wo, Wu, Wf, Wn, pack, SB);
  }
  // 3. xg (32-row tiles) || stage+Hf tiles
  {
    int XB = (S + 31) / 32;
    int SB2 = (M + 15) / 16;
    hipLaunchKernelGGL(xg_stage_hf, dim3(XB + SB2), dim3(256), 0, stream,
                       fmess, submess, pack, bi, bo, bu, bf_, Xg,
                       h_in, c_in, mark, h_out, c_out, HCF,
                       M, S, XB);
  }
  // 4. iter 0 (fused Hf tail)
  hipLaunchKernelGGL(lstm8<0>, dim3(lblocks), dim3(256), 0, stream,
      submess, bgraph, mark, HCF, Xg, pack,
      hsumNS, cpartNS, h_out, c_out, S, M);
  // 5. iter 1
  hipLaunchKernelGGL(lstm8<1>, dim3(lblocks), dim3(256), 0, stream,
      submess, bgraph, mark, HCF, Xg, pack,
      hsumNS, cpartNS, h_out, c_out, S, M);
  // 6. readout || zero non-sub node rows
  {
    int NB = (Nsub + 15) / 16;
    int ZB = 512;
    hipLaunchKernelGGL(readout_zero, dim3(NB + ZB), dim3(256), 0, stream,
        fnode, agraph, subnode, h_out, HCF, mark, nmark, packWn, bn,
        node_buf, Nsub, num_nodes, NB, ZB);
  }
}